// Round 1
// baseline (1240.393 us; speedup 1.0000x reference)
//
#include <hip/hip_runtime.h>

constexpr int CB = 2, CL = 1024, CD = 1024, CNH = 16, CHD = 64, CHDH = 128, CBN = CB * CNH;

__device__ __forceinline__ float sigf(float x) { return 1.0f / (1.0f + __expf(-x)); }

// ---------------------------------------------------------------------------
// Big GEMM: C[M,N] = A[M,K] * Bw[N,K]^T + bias[N], K = 1024 (=CD), tile 64x64.
// AMODE 0: A plain row-major (B*L, D). AMODE 1: A gathered from per-head z2s.
// CMODE 0: C plain row-major (stride CD). CMODE 1: C scattered to per-head.
// ---------------------------------------------------------------------------
template <int AMODE, int CMODE>
__global__ __launch_bounds__(256) void gemm_big(const float* __restrict__ A,
                                                const float* __restrict__ Bw,
                                                const float* __restrict__ bias,
                                                float* __restrict__ C) {
    __shared__ float As[16][68];
    __shared__ float Bs[16][68];
    const int t = threadIdx.x;
    const int r0 = blockIdx.y << 6;
    const int c0 = blockIdx.x << 6;
    const int lrow = t >> 2;
    const int lk4 = (t & 3) << 2;
    const int tr = t >> 4, tc = t & 15;
    float acc[4][4] = {};
    for (int kc = 0; kc < CD; kc += 16) {
        const int ar = r0 + lrow;
        const int ak = kc + lk4;
        float4 av;
        if (AMODE == 0) {
            av = *(const float4*)(A + (size_t)ar * CD + ak);
        } else {
            int b = ar >> 10, l = ar & 1023;
            int n = ak >> 6, d = ak & 63;
            av = *(const float4*)(A + ((((size_t)b * CNH + n) * CL + l) << 6) + d);
        }
        float4 bv = *(const float4*)(Bw + (size_t)(c0 + lrow) * CD + ak);
        As[lk4 + 0][lrow] = av.x; As[lk4 + 1][lrow] = av.y;
        As[lk4 + 2][lrow] = av.z; As[lk4 + 3][lrow] = av.w;
        Bs[lk4 + 0][lrow] = bv.x; Bs[lk4 + 1][lrow] = bv.y;
        Bs[lk4 + 2][lrow] = bv.z; Bs[lk4 + 3][lrow] = bv.w;
        __syncthreads();
#pragma unroll
        for (int kk = 0; kk < 16; ++kk) {
            float4 a4 = *(const float4*)(&As[kk][tr << 2]);
            float4 b4 = *(const float4*)(&Bs[kk][tc << 2]);
            float a[4] = {a4.x, a4.y, a4.z, a4.w};
            float b[4] = {b4.x, b4.y, b4.z, b4.w};
#pragma unroll
            for (int i = 0; i < 4; ++i)
#pragma unroll
                for (int j = 0; j < 4; ++j) acc[i][j] += a[i] * b[j];
        }
        __syncthreads();
    }
#pragma unroll
    for (int i = 0; i < 4; ++i) {
        const int r = r0 + tr * 4 + i;
        const int c = c0 + tc * 4;
        float4 o;
        o.x = acc[i][0] + bias[c + 0];
        o.y = acc[i][1] + bias[c + 1];
        o.z = acc[i][2] + bias[c + 2];
        o.w = acc[i][3] + bias[c + 3];
        if (CMODE == 0) {
            *(float4*)(C + (size_t)r * CD + c) = o;
        } else {
            int b = r >> 10, l = r & 1023;
            int n = c >> 6, d = c & 63;
            *(float4*)(C + ((((size_t)b * CNH + n) * CL + l) << 6) + d) = o;
        }
    }
}

// ---------------------------------------------------------------------------
// lr / log_wd projections: one wave per token row.
// ---------------------------------------------------------------------------
__global__ __launch_bounds__(64) void lrwd_kernel(
    const float* __restrict__ x, const float* __restrict__ lblr,
    const float* __restrict__ fclr_w, const float* __restrict__ fclr_b,
    const float* __restrict__ lbwd, const float* __restrict__ fcwd_w,
    const float* __restrict__ fcwd_b, float* __restrict__ lrp,
    float* __restrict__ logwd) {
    const int r = blockIdx.x;  // 0 .. B*L-1
    const int b = r >> 10, l = r & 1023;
    const int lane = threadIdx.x;
    float xv[16];
#pragma unroll
    for (int j = 0; j < 16; ++j) xv[j] = x[(size_t)r * CD + lane + 64 * j];
    for (int n = 0; n < CNH; ++n) {
        float d1 = 0.f, d2 = 0.f;
#pragma unroll
        for (int j = 0; j < 16; ++j) {
            d1 += xv[j] * fclr_w[(size_t)n * CD + lane + 64 * j];
            d2 += xv[j] * fcwd_w[(size_t)n * CD + lane + 64 * j];
        }
#pragma unroll
        for (int s = 32; s > 0; s >>= 1) {
            d1 += __shfl_down(d1, s);
            d2 += __shfl_down(d2, s);
        }
        if (lane == 0) {
            lrp[((size_t)b * CNH + n) * CL + l] = __expf(lblr[n]) * sigf(d1 + fclr_b[n]);
            logwd[((size_t)b * CNH + n) * CL + l] =
                log1pf(-__expf(lbwd[n]) * sigf(d2 + fcwd_b[n]));
        }
    }
}

// ---------------------------------------------------------------------------
// In-place inclusive prefix sum of log_wd -> cum, plus wdc = exp(cum).
// One wave per (b,n); lane holds 16 consecutive elements.
// ---------------------------------------------------------------------------
__global__ __launch_bounds__(64) void scan_kernel(float* __restrict__ cum,
                                                  float* __restrict__ wdc) {
    const int bn = blockIdx.x;
    const int lane = threadIdx.x;
    float* p = cum + (size_t)bn * CL;
    float v[16];
#pragma unroll
    for (int j = 0; j < 16; ++j) v[j] = p[lane * 16 + j];
#pragma unroll
    for (int j = 1; j < 16; ++j) v[j] += v[j - 1];
    float tot = v[15];
    float inc = tot;
#pragma unroll
    for (int s = 1; s < 64; s <<= 1) {
        float tv = __shfl_up(inc, s);
        if (lane >= s) inc += tv;
    }
    const float pre = inc - tot;
#pragma unroll
    for (int j = 0; j < 16; ++j) {
        float c = pre + v[j];
        p[lane * 16 + j] = c;
        wdc[(size_t)bn * CL + lane * 16 + j] = __expf(c);
    }
}

// ---------------------------------------------------------------------------
// Fused per-head MLP forward/backward over a 32-token tile.
//   Z1 = W1 K^T ; X2 = silu(Z1) ; Z2 = W2 X2 ; gZ2 = Z2 - V
//   gX2 = W2^T gZ2 ; gZ1 = silu'(Z1) * gX2
// ---------------------------------------------------------------------------
__global__ __launch_bounds__(256) void mlp_kernel(
    const float* __restrict__ kh, const float* __restrict__ vh,
    const float* __restrict__ W1, const float* __restrict__ W2,
    float* __restrict__ x2, float* __restrict__ gz1, float* __restrict__ gz2) {
    __shared__ float W1s[CHDH * CHD];  // [h][d]
    __shared__ float W2s[CHD * CHDH];  // [d][h]
    __shared__ float Ks[32][65];
    __shared__ float X2s[32][129];
    __shared__ float GZ2s[32][65];
    __shared__ float GZ1s[32][129];
    const int bn = blockIdx.y;
    const int l0 = blockIdx.x << 5;
    const int t = threadIdx.x;
    {
        const float4* w1g = (const float4*)(W1 + (size_t)bn * CHDH * CHD);
        const float4* w2g = (const float4*)(W2 + (size_t)bn * CHD * CHDH);
        float4* w1l = (float4*)W1s;
        float4* w2l = (float4*)W2s;
        for (int i = t; i < CHDH * CHD / 4; i += 256) {
            w1l[i] = w1g[i];
            w2l[i] = w2g[i];
        }
        const float4* kg = (const float4*)(kh + ((size_t)bn * CL + l0) * CHD);
        const float4* vg = (const float4*)(vh + ((size_t)bn * CL + l0) * CHD);
        for (int i = t; i < 32 * CHD / 4; i += 256) {
            int row = (i << 2) >> 6, col = (i << 2) & 63;
            float4 kv = kg[i];
            Ks[row][col] = kv.x; Ks[row][col + 1] = kv.y;
            Ks[row][col + 2] = kv.z; Ks[row][col + 3] = kv.w;
            float4 vv = vg[i];
            GZ2s[row][col] = vv.x; GZ2s[row][col + 1] = vv.y;
            GZ2s[row][col + 2] = vv.z; GZ2s[row][col + 3] = vv.w;
        }
    }
    __syncthreads();
    const int tt = t & 31;  // token
    const int ss = t >> 5;  // slot 0..7
    float z1v[16] = {};
    for (int d = 0; d < CHD; ++d) {
        float kv = Ks[tt][d];
#pragma unroll
        for (int j = 0; j < 16; ++j) z1v[j] += W1s[(ss * 16 + j) * CHD + d] * kv;
    }
#pragma unroll
    for (int j = 0; j < 16; ++j) {
        float a = z1v[j];
        X2s[tt][ss * 16 + j] = a * sigf(a);
    }
    __syncthreads();
    {
        float z2v[8] = {};
        for (int h = 0; h < CHDH; ++h) {
            float xv = X2s[tt][h];
#pragma unroll
            for (int j = 0; j < 8; ++j) z2v[j] += W2s[(ss * 8 + j) * CHDH + h] * xv;
        }
#pragma unroll
        for (int j = 0; j < 8; ++j) {
            int d = ss * 8 + j;
            float g = z2v[j] - GZ2s[tt][d];  // v staged there
            GZ2s[tt][d] = g;
        }
    }
    __syncthreads();
    {
        float gx[16] = {};
        for (int d = 0; d < CHD; ++d) {
            float gv = GZ2s[tt][d];
#pragma unroll
            for (int j = 0; j < 16; ++j) gx[j] += W2s[d * CHDH + ss * 16 + j] * gv;
        }
#pragma unroll
        for (int j = 0; j < 16; ++j) {
            float zz = z1v[j];
            float s = sigf(zz);
            float sil = zz * s;
            GZ1s[tt][ss * 16 + j] = (sil + s * (1.f - sil)) * gx[j];
        }
    }
    __syncthreads();
    {
        float4* xg = (float4*)(x2 + ((size_t)bn * CL + l0) * CHDH);
        float4* gg = (float4*)(gz1 + ((size_t)bn * CL + l0) * CHDH);
        for (int i = t; i < 32 * CHDH / 4; i += 256) {
            int row = (i << 2) >> 7, col = (i << 2) & 127;
            float4 v;
            v.x = X2s[row][col]; v.y = X2s[row][col + 1];
            v.z = X2s[row][col + 2]; v.w = X2s[row][col + 3];
            xg[i] = v;
            float4 g;
            g.x = GZ1s[row][col]; g.y = GZ1s[row][col + 1];
            g.z = GZ1s[row][col + 2]; g.w = GZ1s[row][col + 3];
            gg[i] = g;
        }
        float4* zg = (float4*)(gz2 + ((size_t)bn * CL + l0) * CHD);
        for (int i = t; i < 32 * CHD / 4; i += 256) {
            int row = (i << 2) >> 6, col = (i << 2) & 63;
            float4 v;
            v.x = GZ2s[row][col]; v.y = GZ2s[row][col + 1];
            v.z = GZ2s[row][col + 2]; v.w = GZ2s[row][col + 3];
            zg[i] = v;
        }
    }
}

// ---------------------------------------------------------------------------
// Layer-1 readout: X2_ = silu( wd_cross[m]*(W1 q_m) - sum_{l<=m} (k_l.q_m)
//                  * lr[l] * exp(cum[m]-cum[l]) * gz1[l,:] )
// One block per (b,n,m-tile of 64). acc: 64m x 128h, 32/thread.
// ---------------------------------------------------------------------------
__global__ __launch_bounds__(256) void attn1_kernel(
    const float* __restrict__ qh, const float* __restrict__ kh,
    const float* __restrict__ gz1, const float* __restrict__ W1,
    const float* __restrict__ lrp, const float* __restrict__ cump,
    const float* __restrict__ wdcp, float* __restrict__ x2q) {
    __shared__ float Qs[64][65];
    __shared__ float Ks[64][65];
    __shared__ float S[64][65];
    __shared__ float GZ1s[64 * CHDH];  // W1 staged first, then gz1 tiles
    __shared__ float lrl[64], cuml[64], cumm[64], wdcm[64];
    const int bn = blockIdx.y;
    const int mt = blockIdx.x;
    const int m0 = mt << 6;
    const int t = threadIdx.x;
    {
        const float4* qg = (const float4*)(qh + ((size_t)bn * CL + m0) * CHD);
        for (int i = t; i < 64 * CHD / 4; i += 256) {
            int row = (i << 2) >> 6, col = (i << 2) & 63;
            float4 v = qg[i];
            Qs[row][col] = v.x; Qs[row][col + 1] = v.y;
            Qs[row][col + 2] = v.z; Qs[row][col + 3] = v.w;
        }
        const float4* wg = (const float4*)(W1 + (size_t)bn * CHDH * CHD);
        float4* wl = (float4*)GZ1s;
        for (int i = t; i < CHDH * CHD / 4; i += 256) wl[i] = wg[i];
        if (t < 64) {
            cumm[t] = cump[(size_t)bn * CL + m0 + t];
            wdcm[t] = wdcp[(size_t)bn * CL + m0 + t];
        }
    }
    __syncthreads();
    const int tm = t & 15;  // m group
    const int th = t >> 4;  // h group
    float acc[4][8] = {};
    for (int d = 0; d < CHD; ++d) {
        float q4[4], w8[8];
#pragma unroll
        for (int i = 0; i < 4; ++i) q4[i] = Qs[tm * 4 + i][d];
#pragma unroll
        for (int j = 0; j < 8; ++j) w8[j] = GZ1s[(th * 8 + j) * CHD + d];
#pragma unroll
        for (int i = 0; i < 4; ++i)
#pragma unroll
            for (int j = 0; j < 8; ++j) acc[i][j] += q4[i] * w8[j];
    }
#pragma unroll
    for (int i = 0; i < 4; ++i) {
        float w = wdcm[tm * 4 + i];
#pragma unroll
        for (int j = 0; j < 8; ++j) acc[i][j] *= w;
    }
    __syncthreads();  // W1 staging in GZ1s no longer needed
    for (int lt = 0; lt <= mt; ++lt) {
        const int l0 = lt << 6;
        {
            const float4* kg = (const float4*)(kh + ((size_t)bn * CL + l0) * CHD);
            for (int i = t; i < 64 * CHD / 4; i += 256) {
                int row = (i << 2) >> 6, col = (i << 2) & 63;
                float4 v = kg[i];
                Ks[row][col] = v.x; Ks[row][col + 1] = v.y;
                Ks[row][col + 2] = v.z; Ks[row][col + 3] = v.w;
            }
            const float4* gg = (const float4*)(gz1 + ((size_t)bn * CL + l0) * CHDH);
            float4* gl = (float4*)GZ1s;
            for (int i = t; i < 64 * CHDH / 4; i += 256) gl[i] = gg[i];
            if (t < 64) {
                lrl[t] = lrp[(size_t)bn * CL + l0 + t];
                cuml[t] = cump[(size_t)bn * CL + l0 + t];
            }
        }
        __syncthreads();
        {
            float sv[4][4] = {};
            for (int d = 0; d < CHD; ++d) {
                float k4[4], q4[4];
#pragma unroll
                for (int i = 0; i < 4; ++i) k4[i] = Ks[tm * 4 + i][d];
#pragma unroll
                for (int j = 0; j < 4; ++j) q4[j] = Qs[th * 4 + j][d];
#pragma unroll
                for (int i = 0; i < 4; ++i)
#pragma unroll
                    for (int j = 0; j < 4; ++j) sv[i][j] += k4[i] * q4[j];
            }
#pragma unroll
            for (int i = 0; i < 4; ++i) {
                int li = tm * 4 + i;
#pragma unroll
                for (int j = 0; j < 4; ++j) {
                    int mj = th * 4 + j;
                    float s = (m0 + mj >= l0 + li)
                                  ? sv[i][j] * lrl[li] * __expf(cumm[mj] - cuml[li])
                                  : 0.f;
                    S[li][mj] = s;
                }
            }
        }
        __syncthreads();
        for (int l = 0; l < 64; ++l) {
            float gv[8];
#pragma unroll
            for (int j = 0; j < 8; ++j) gv[j] = GZ1s[l * CHDH + th * 8 + j];
#pragma unroll
            for (int i = 0; i < 4; ++i) {
                float svv = S[l][tm * 4 + i];
#pragma unroll
                for (int j = 0; j < 8; ++j) acc[i][j] -= svv * gv[j];
            }
        }
        __syncthreads();
    }
    // silu and store via LDS for coalescing
#pragma unroll
    for (int i = 0; i < 4; ++i) {
        int m = tm * 4 + i;
#pragma unroll
        for (int j = 0; j < 8; ++j) {
            int h = th * 8 + j;
            float a = acc[i][j];
            GZ1s[m * CHDH + h] = a * sigf(a);
        }
    }
    __syncthreads();
    {
        float4* og = (float4*)(x2q + ((size_t)bn * CL + m0) * CHDH);
        const float4* gl = (const float4*)GZ1s;
        for (int i = t; i < 64 * CHDH / 4; i += 256) og[i] = gl[i];
    }
}

// ---------------------------------------------------------------------------
// Layer-2 readout: Z2_ = wd_cross[m]*(W2 x2_[m]) - sum_{l<=m} (x2[l].x2_[m])
//                  * lr[l] * exp(cum[m]-cum[l]) * gz2[l,:]
// ---------------------------------------------------------------------------
__global__ __launch_bounds__(256) void attn2_kernel(
    const float* __restrict__ x2q, const float* __restrict__ x2,
    const float* __restrict__ gz2, const float* __restrict__ W2,
    const float* __restrict__ lrp, const float* __restrict__ cump,
    const float* __restrict__ wdcp, float* __restrict__ z2s) {
    __shared__ float Qs[64][129];   // x2_ tile (queries)
    __shared__ float Ks[64][129];   // x2 tile (keys)
    __shared__ float W2s[64][129];  // [d][h]
    __shared__ float S[64][65];
    __shared__ float GZ2s[64][65];
    __shared__ float lrl[64], cuml[64], cumm[64], wdcm[64];
    const int bn = blockIdx.y;
    const int mt = blockIdx.x;
    const int m0 = mt << 6;
    const int t = threadIdx.x;
    {
        const float4* qg = (const float4*)(x2q + ((size_t)bn * CL + m0) * CHDH);
        for (int i = t; i < 64 * CHDH / 4; i += 256) {
            int row = (i << 2) >> 7, col = (i << 2) & 127;
            float4 v = qg[i];
            Qs[row][col] = v.x; Qs[row][col + 1] = v.y;
            Qs[row][col + 2] = v.z; Qs[row][col + 3] = v.w;
        }
        const float4* wg = (const float4*)(W2 + (size_t)bn * CHD * CHDH);
        for (int i = t; i < CHD * CHDH / 4; i += 256) {
            int row = (i << 2) >> 7, col = (i << 2) & 127;
            float4 v = wg[i];
            W2s[row][col] = v.x; W2s[row][col + 1] = v.y;
            W2s[row][col + 2] = v.z; W2s[row][col + 3] = v.w;
        }
        if (t < 64) {
            cumm[t] = cump[(size_t)bn * CL + m0 + t];
            wdcm[t] = wdcp[(size_t)bn * CL + m0 + t];
        }
    }
    __syncthreads();
    const int tmq = t >> 4;  // m group
    const int td = t & 15;   // d group
    float acc[4][4] = {};
    for (int h = 0; h < CHDH; ++h) {
        float q4[4], w4[4];
#pragma unroll
        for (int i = 0; i < 4; ++i) q4[i] = Qs[tmq * 4 + i][h];
#pragma unroll
        for (int j = 0; j < 4; ++j) w4[j] = W2s[td * 4 + j][h];
#pragma unroll
        for (int i = 0; i < 4; ++i)
#pragma unroll
            for (int j = 0; j < 4; ++j) acc[i][j] += q4[i] * w4[j];
    }
#pragma unroll
    for (int i = 0; i < 4; ++i) {
        float w = wdcm[tmq * 4 + i];
#pragma unroll
        for (int j = 0; j < 4; ++j) acc[i][j] *= w;
    }
    for (int lt = 0; lt <= mt; ++lt) {
        const int l0 = lt << 6;
        __syncthreads();  // previous iteration readers done
        {
            const float4* kg = (const float4*)(x2 + ((size_t)bn * CL + l0) * CHDH);
            for (int i = t; i < 64 * CHDH / 4; i += 256) {
                int row = (i << 2) >> 7, col = (i << 2) & 127;
                float4 v = kg[i];
                Ks[row][col] = v.x; Ks[row][col + 1] = v.y;
                Ks[row][col + 2] = v.z; Ks[row][col + 3] = v.w;
            }
            const float4* gg = (const float4*)(gz2 + ((size_t)bn * CL + l0) * CHD);
            for (int i = t; i < 64 * CHD / 4; i += 256) {
                int row = (i << 2) >> 6, col = (i << 2) & 63;
                float4 v = gg[i];
                GZ2s[row][col] = v.x; GZ2s[row][col + 1] = v.y;
                GZ2s[row][col + 2] = v.z; GZ2s[row][col + 3] = v.w;
            }
            if (t < 64) {
                lrl[t] = lrp[(size_t)bn * CL + l0 + t];
                cuml[t] = cump[(size_t)bn * CL + l0 + t];
            }
        }
        __syncthreads();
        {
            float sv[4][4] = {};
            for (int h = 0; h < CHDH; ++h) {
                float k4[4], q4[4];
#pragma unroll
                for (int i = 0; i < 4; ++i) k4[i] = Ks[td * 4 + i][h];
#pragma unroll
                for (int j = 0; j < 4; ++j) q4[j] = Qs[tmq * 4 + j][h];
#pragma unroll
                for (int i = 0; i < 4; ++i)
#pragma unroll
                    for (int j = 0; j < 4; ++j) sv[i][j] += k4[i] * q4[j];
            }
#pragma unroll
            for (int i = 0; i < 4; ++i) {
                int li = td * 4 + i;
#pragma unroll
                for (int j = 0; j < 4; ++j) {
                    int mj = tmq * 4 + j;
                    float s = (m0 + mj >= l0 + li)
                                  ? sv[i][j] * lrl[li] * __expf(cumm[mj] - cuml[li])
                                  : 0.f;
                    S[li][mj] = s;
                }
            }
        }
        __syncthreads();
        for (int l = 0; l < 64; ++l) {
            float gv[4];
#pragma unroll
            for (int j = 0; j < 4; ++j) gv[j] = GZ2s[l][td * 4 + j];
#pragma unroll
            for (int i = 0; i < 4; ++i) {
                float svv = S[l][tmq * 4 + i];
#pragma unroll
                for (int j = 0; j < 4; ++j) acc[i][j] -= svv * gv[j];
            }
        }
    }
    __syncthreads();
#pragma unroll
    for (int i = 0; i < 4; ++i) {
        int m = tmq * 4 + i;
#pragma unroll
        for (int j = 0; j < 4; ++j) GZ2s[m][td * 4 + j] = acc[i][j];
    }
    __syncthreads();
    {
        float4* og = (float4*)(z2s + ((size_t)bn * CL + m0) * CHD);
        for (int i = t; i < 64 * CHD / 4; i += 256) {
            int row = (i << 2) >> 6, col = (i << 2) & 63;
            float4 v;
            v.x = GZ2s[row][col]; v.y = GZ2s[row][col + 1];
            v.z = GZ2s[row][col + 2]; v.w = GZ2s[row][col + 3];
            og[i] = v;
        }
    }
}

// ---------------------------------------------------------------------------
// W1_next[h,d] = wdc_last*W1[h,d] - sum_l lr[l]*exp(cum_last-cum[l])*gz1[l,h]*k[l,d]
// grid (half of h, bn)
// ---------------------------------------------------------------------------
__global__ __launch_bounds__(256) void w1next_kernel(
    const float* __restrict__ gz1, const float* __restrict__ kh,
    const float* __restrict__ W1, const float* __restrict__ lrp,
    const float* __restrict__ cump, float* __restrict__ outw) {
    __shared__ float Gs[64][65];
    __shared__ float Ks[64][65];
    __shared__ float coefs[64];
    const int bn = blockIdx.y;
    const int h0 = blockIdx.x << 6;
    const int t = threadIdx.x;
    const float cum_last = cump[(size_t)bn * CL + CL - 1];
    const float wdcl = __expf(cum_last);
    const int hi = t >> 4, di = t & 15;
    float acc[4][4] = {};
    for (int l0 = 0; l0 < CL; l0 += 64) {
        for (int i = t; i < 64 * 64 / 4; i += 256) {
            int row = (i << 2) >> 6, col = (i << 2) & 63;
            float4 g = *(const float4*)(gz1 + ((size_t)bn * CL + l0 + row) * CHDH + h0 + col);
            Gs[row][col] = g.x; Gs[row][col + 1] = g.y;
            Gs[row][col + 2] = g.z; Gs[row][col + 3] = g.w;
            float4 k = *(const float4*)(kh + ((size_t)bn * CL + l0 + row) * CHD + col);
            Ks[row][col] = k.x; Ks[row][col + 1] = k.y;
            Ks[row][col + 2] = k.z; Ks[row][col + 3] = k.w;
        }
        if (t < 64)
            coefs[t] = lrp[(size_t)bn * CL + l0 + t] *
                       __expf(cum_last - cump[(size_t)bn * CL + l0 + t]);
        __syncthreads();
        for (int l = 0; l < 64; ++l) {
            float c = coefs[l];
            float g4[4], k4[4];
#pragma unroll
            for (int i = 0; i < 4; ++i) g4[i] = Gs[l][hi * 4 + i] * c;
#pragma unroll
            for (int j = 0; j < 4; ++j) k4[j] = Ks[l][di * 4 + j];
#pragma unroll
            for (int i = 0; i < 4; ++i)
#pragma unroll
                for (int j = 0; j < 4; ++j) acc[i][j] += g4[i] * k4[j];
        }
        __syncthreads();
    }
    const float* w1g = W1 + (size_t)bn * CHDH * CHD;
#pragma unroll
    for (int i = 0; i < 4; ++i) {
        int h = h0 + hi * 4 + i;
        int d = di * 4;
        float4 o;
        o.x = wdcl * w1g[h * CHD + d + 0] - acc[i][0];
        o.y = wdcl * w1g[h * CHD + d + 1] - acc[i][1];
        o.z = wdcl * w1g[h * CHD + d + 2] - acc[i][2];
        o.w = wdcl * w1g[h * CHD + d + 3] - acc[i][3];
        *(float4*)(outw + (size_t)bn * CHDH * CHD + h * CHD + d) = o;
    }
}

// ---------------------------------------------------------------------------
// W2_next[d,h] = wdc_last*W2[d,h] - sum_l lr[l]*exp(cum_last-cum[l])*gz2[l,d]*x2[l,h]
// ---------------------------------------------------------------------------
__global__ __launch_bounds__(256) void w2next_kernel(
    const float* __restrict__ gz2, const float* __restrict__ x2,
    const float* __restrict__ W2, const float* __restrict__ lrp,
    const float* __restrict__ cump, float* __restrict__ outw) {
    __shared__ float Gs[64][65];  // gz2: l x d
    __shared__ float Xs[64][65];  // x2 half: l x h
    __shared__ float coefs[64];
    const int bn = blockIdx.y;
    const int h0 = blockIdx.x << 6;
    const int t = threadIdx.x;
    const float cum_last = cump[(size_t)bn * CL + CL - 1];
    const float wdcl = __expf(cum_last);
    const int di = t >> 4, hi = t & 15;
    float acc[4][4] = {};
    for (int l0 = 0; l0 < CL; l0 += 64) {
        for (int i = t; i < 64 * 64 / 4; i += 256) {
            int row = (i << 2) >> 6, col = (i << 2) & 63;
            float4 g = *(const float4*)(gz2 + ((size_t)bn * CL + l0 + row) * CHD + col);
            Gs[row][col] = g.x; Gs[row][col + 1] = g.y;
            Gs[row][col + 2] = g.z; Gs[row][col + 3] = g.w;
            float4 xv = *(const float4*)(x2 + ((size_t)bn * CL + l0 + row) * CHDH + h0 + col);
            Xs[row][col] = xv.x; Xs[row][col + 1] = xv.y;
            Xs[row][col + 2] = xv.z; Xs[row][col + 3] = xv.w;
        }
        if (t < 64)
            coefs[t] = lrp[(size_t)bn * CL + l0 + t] *
                       __expf(cum_last - cump[(size_t)bn * CL + l0 + t]);
        __syncthreads();
        for (int l = 0; l < 64; ++l) {
            float c = coefs[l];
            float g4[4], x4[4];
#pragma unroll
            for (int i = 0; i < 4; ++i) g4[i] = Gs[l][di * 4 + i] * c;
#pragma unroll
            for (int j = 0; j < 4; ++j) x4[j] = Xs[l][hi * 4 + j];
#pragma unroll
            for (int i = 0; i < 4; ++i)
#pragma unroll
                for (int j = 0; j < 4; ++j) acc[i][j] += g4[i] * x4[j];
        }
        __syncthreads();
    }
    const float* w2g = W2 + (size_t)bn * CHD * CHDH;
#pragma unroll
    for (int i = 0; i < 4; ++i) {
        int d = di * 4 + i;
        int h = h0 + hi * 4;
        float4 o;
        o.x = wdcl * w2g[d * CHDH + h + 0] - acc[i][0];
        o.y = wdcl * w2g[d * CHDH + h + 1] - acc[i][1];
        o.z = wdcl * w2g[d * CHDH + h + 2] - acc[i][2];
        o.w = wdcl * w2g[d * CHDH + h + 3] - acc[i][3];
        *(float4*)(outw + (size_t)bn * CHD * CHDH + d * CHDH + h) = o;
    }
}

// ---------------------------------------------------------------------------
extern "C" void kernel_launch(void* const* d_in, const int* in_sizes, int n_in,
                              void* d_out, int out_size, void* d_ws, size_t ws_size,
                              hipStream_t stream) {
    (void)in_sizes; (void)n_in; (void)out_size; (void)ws_size;
    const float* x      = (const float*)d_in[0];
    const float* W1     = (const float*)d_in[1];
    const float* W2     = (const float*)d_in[2];
    const float* lblr   = (const float*)d_in[3];
    const float* fclr_w = (const float*)d_in[4];
    const float* fclr_b = (const float*)d_in[5];
    const float* lbwd   = (const float*)d_in[6];
    const float* fcwd_w = (const float*)d_in[7];
    const float* fcwd_b = (const float*)d_in[8];
    const float* qw = (const float*)d_in[9];
    const float* qb = (const float*)d_in[10];
    const float* kw = (const float*)d_in[11];
    const float* kb = (const float*)d_in[12];
    const float* vw = (const float*)d_in[13];
    const float* vb = (const float*)d_in[14];
    const float* ow = (const float*)d_in[15];
    const float* ob = (const float*)d_in[16];

    float* ws = (float*)d_ws;
    const size_t SZ_HD = (size_t)CBN * CL * CHD;    // 2,097,152
    const size_t SZ_HDH = (size_t)CBN * CL * CHDH;  // 4,194,304
    float* qh   = ws;
    float* khb  = qh + SZ_HD;
    float* vhb  = khb + SZ_HD;
    float* gz2b = vhb + SZ_HD;
    float* z2sb = gz2b + SZ_HD;
    float* x2b  = z2sb + SZ_HD;
    float* gz1b = x2b + SZ_HDH;
    float* x2qb = gz1b + SZ_HDH;
    float* lrb  = x2qb + SZ_HDH;
    float* cumb = lrb + (size_t)CBN * CL;
    float* wdcb = cumb + (size_t)CBN * CL;

    float* outp = (float*)d_out;
    float* w1n = outp + (size_t)CB * CL * CD;
    float* w2n = w1n + (size_t)CBN * CHDH * CHD;

    dim3 gBig(CD / 64, (CB * CL) / 64);
    gemm_big<0, 1><<<gBig, 256, 0, stream>>>(x, qw, qb, qh);
    gemm_big<0, 1><<<gBig, 256, 0, stream>>>(x, kw, kb, khb);
    gemm_big<0, 1><<<gBig, 256, 0, stream>>>(x, vw, vb, vhb);
    lrwd_kernel<<<CB * CL, 64, 0, stream>>>(x, lblr, fclr_w, fclr_b, lbwd, fcwd_w,
                                            fcwd_b, lrb, cumb);
    scan_kernel<<<CBN, 64, 0, stream>>>(cumb, wdcb);
    mlp_kernel<<<dim3(CL / 32, CBN), 256, 0, stream>>>(khb, vhb, W1, W2, x2b, gz1b, gz2b);
    attn1_kernel<<<dim3(CL / 64, CBN), 256, 0, stream>>>(qh, khb, gz1b, W1, lrb, cumb,
                                                         wdcb, x2qb);
    attn2_kernel<<<dim3(CL / 64, CBN), 256, 0, stream>>>(x2qb, x2b, gz2b, W2, lrb, cumb,
                                                         wdcb, z2sb);
    w1next_kernel<<<dim3(2, CBN), 256, 0, stream>>>(gz1b, khb, W1, lrb, cumb, w1n);
    w2next_kernel<<<dim3(2, CBN), 256, 0, stream>>>(gz2b, x2b, W2, lrb, cumb, w2n);
    gemm_big<1, 0><<<gBig, 256, 0, stream>>>(z2sb, ow, ob, outp);
}

// Round 2
// 715.242 us; speedup vs baseline: 1.7342x; 1.7342x over previous
//
#include <hip/hip_runtime.h>

constexpr int CB = 2, CL = 1024, CD = 1024, CNH = 16, CHD = 64, CHDH = 128, CBN = CB * CNH;

__device__ __forceinline__ float sigf(float x) { return 1.0f / (1.0f + __expf(-x)); }

// round-to-nearest-even float -> bf16
__device__ __forceinline__ unsigned short f2bf(float x) {
    unsigned u = __float_as_uint(x);
    u += 0x7fffu + ((u >> 16) & 1u);
    return (unsigned short)(u >> 16);
}
__device__ __forceinline__ unsigned pk2(float a, float b) {
    return (unsigned)f2bf(a) | ((unsigned)f2bf(b) << 16);
}

typedef __attribute__((ext_vector_type(8))) short short8v;
typedef __attribute__((ext_vector_type(4))) float f32x4;
#define MFMA16(a, b, c) __builtin_amdgcn_mfma_f32_16x16x32_bf16(a, b, c, 0, 0, 0)

// ---------------------------------------------------------------------------
// Big GEMM: C[M,N] = A[M,K] * Bw[N,K]^T + bias[N], K = 1024 (=CD), tile 64x64.
// ---------------------------------------------------------------------------
template <int AMODE, int CMODE>
__global__ __launch_bounds__(256) void gemm_big(const float* __restrict__ A,
                                                const float* __restrict__ Bw,
                                                const float* __restrict__ bias,
                                                float* __restrict__ C) {
    __shared__ float As[16][68];
    __shared__ float Bs[16][68];
    const int t = threadIdx.x;
    const int r0 = blockIdx.y << 6;
    const int c0 = blockIdx.x << 6;
    const int lrow = t >> 2;
    const int lk4 = (t & 3) << 2;
    const int tr = t >> 4, tc = t & 15;
    float acc[4][4] = {};
    for (int kc = 0; kc < CD; kc += 16) {
        const int ar = r0 + lrow;
        const int ak = kc + lk4;
        float4 av;
        if (AMODE == 0) {
            av = *(const float4*)(A + (size_t)ar * CD + ak);
        } else {
            int b = ar >> 10, l = ar & 1023;
            int n = ak >> 6, d = ak & 63;
            av = *(const float4*)(A + ((((size_t)b * CNH + n) * CL + l) << 6) + d);
        }
        float4 bv = *(const float4*)(Bw + (size_t)(c0 + lrow) * CD + ak);
        As[lk4 + 0][lrow] = av.x; As[lk4 + 1][lrow] = av.y;
        As[lk4 + 2][lrow] = av.z; As[lk4 + 3][lrow] = av.w;
        Bs[lk4 + 0][lrow] = bv.x; Bs[lk4 + 1][lrow] = bv.y;
        Bs[lk4 + 2][lrow] = bv.z; Bs[lk4 + 3][lrow] = bv.w;
        __syncthreads();
#pragma unroll
        for (int kk = 0; kk < 16; ++kk) {
            float4 a4 = *(const float4*)(&As[kk][tr << 2]);
            float4 b4 = *(const float4*)(&Bs[kk][tc << 2]);
            float a[4] = {a4.x, a4.y, a4.z, a4.w};
            float b[4] = {b4.x, b4.y, b4.z, b4.w};
#pragma unroll
            for (int i = 0; i < 4; ++i)
#pragma unroll
                for (int j = 0; j < 4; ++j) acc[i][j] += a[i] * b[j];
        }
        __syncthreads();
    }
#pragma unroll
    for (int i = 0; i < 4; ++i) {
        const int r = r0 + tr * 4 + i;
        const int c = c0 + tc * 4;
        float4 o;
        o.x = acc[i][0] + bias[c + 0];
        o.y = acc[i][1] + bias[c + 1];
        o.z = acc[i][2] + bias[c + 2];
        o.w = acc[i][3] + bias[c + 3];
        if (CMODE == 0) {
            *(float4*)(C + (size_t)r * CD + c) = o;
        } else {
            int b = r >> 10, l = r & 1023;
            int n = c >> 6, d = c & 63;
            *(float4*)(C + ((((size_t)b * CNH + n) * CL + l) << 6) + d) = o;
        }
    }
}

// ---------------------------------------------------------------------------
// lr / log_wd projections: one wave per token row.
// ---------------------------------------------------------------------------
__global__ __launch_bounds__(64) void lrwd_kernel(
    const float* __restrict__ x, const float* __restrict__ lblr,
    const float* __restrict__ fclr_w, const float* __restrict__ fclr_b,
    const float* __restrict__ lbwd, const float* __restrict__ fcwd_w,
    const float* __restrict__ fcwd_b, float* __restrict__ lrp,
    float* __restrict__ logwd) {
    const int r = blockIdx.x;
    const int b = r >> 10, l = r & 1023;
    const int lane = threadIdx.x;
    float xv[16];
#pragma unroll
    for (int j = 0; j < 16; ++j) xv[j] = x[(size_t)r * CD + lane + 64 * j];
    for (int n = 0; n < CNH; ++n) {
        float d1 = 0.f, d2 = 0.f;
#pragma unroll
        for (int j = 0; j < 16; ++j) {
            d1 += xv[j] * fclr_w[(size_t)n * CD + lane + 64 * j];
            d2 += xv[j] * fcwd_w[(size_t)n * CD + lane + 64 * j];
        }
#pragma unroll
        for (int s = 32; s > 0; s >>= 1) {
            d1 += __shfl_down(d1, s);
            d2 += __shfl_down(d2, s);
        }
        if (lane == 0) {
            lrp[((size_t)b * CNH + n) * CL + l] = __expf(lblr[n]) * sigf(d1 + fclr_b[n]);
            logwd[((size_t)b * CNH + n) * CL + l] =
                log1pf(-__expf(lbwd[n]) * sigf(d2 + fcwd_b[n]));
        }
    }
}

// ---------------------------------------------------------------------------
// Inclusive prefix sum of log_wd -> cum, plus wdc = exp(cum).
// ---------------------------------------------------------------------------
__global__ __launch_bounds__(64) void scan_kernel(float* __restrict__ cum,
                                                  float* __restrict__ wdc) {
    const int bn = blockIdx.x;
    const int lane = threadIdx.x;
    float* p = cum + (size_t)bn * CL;
    float v[16];
#pragma unroll
    for (int j = 0; j < 16; ++j) v[j] = p[lane * 16 + j];
#pragma unroll
    for (int j = 1; j < 16; ++j) v[j] += v[j - 1];
    float tot = v[15];
    float inc = tot;
#pragma unroll
    for (int s = 1; s < 64; s <<= 1) {
        float tv = __shfl_up(inc, s);
        if (lane >= s) inc += tv;
    }
    const float pre = inc - tot;
#pragma unroll
    for (int j = 0; j < 16; ++j) {
        float c = pre + v[j];
        p[lane * 16 + j] = c;
        wdc[(size_t)bn * CL + lane * 16 + j] = __expf(c);
    }
}

// ---------------------------------------------------------------------------
// Fused per-head MLP forward/backward over a 32-token tile.
// ---------------------------------------------------------------------------
__global__ __launch_bounds__(256) void mlp_kernel(
    const float* __restrict__ kh, const float* __restrict__ vh,
    const float* __restrict__ W1, const float* __restrict__ W2,
    float* __restrict__ x2, float* __restrict__ gz1, float* __restrict__ gz2) {
    __shared__ float W1s[CHDH * CHD];
    __shared__ float W2s[CHD * CHDH];
    __shared__ float Ks[32][65];
    __shared__ float X2s[32][129];
    __shared__ float GZ2s[32][65];
    __shared__ float GZ1s[32][129];
    const int bn = blockIdx.y;
    const int l0 = blockIdx.x << 5;
    const int t = threadIdx.x;
    {
        const float4* w1g = (const float4*)(W1 + (size_t)bn * CHDH * CHD);
        const float4* w2g = (const float4*)(W2 + (size_t)bn * CHD * CHDH);
        float4* w1l = (float4*)W1s;
        float4* w2l = (float4*)W2s;
        for (int i = t; i < CHDH * CHD / 4; i += 256) {
            w1l[i] = w1g[i];
            w2l[i] = w2g[i];
        }
        const float4* kg = (const float4*)(kh + ((size_t)bn * CL + l0) * CHD);
        const float4* vg = (const float4*)(vh + ((size_t)bn * CL + l0) * CHD);
        for (int i = t; i < 32 * CHD / 4; i += 256) {
            int row = (i << 2) >> 6, col = (i << 2) & 63;
            float4 kv = kg[i];
            Ks[row][col] = kv.x; Ks[row][col + 1] = kv.y;
            Ks[row][col + 2] = kv.z; Ks[row][col + 3] = kv.w;
            float4 vv = vg[i];
            GZ2s[row][col] = vv.x; GZ2s[row][col + 1] = vv.y;
            GZ2s[row][col + 2] = vv.z; GZ2s[row][col + 3] = vv.w;
        }
    }
    __syncthreads();
    const int tt = t & 31;
    const int ss = t >> 5;
    float z1v[16] = {};
    for (int d = 0; d < CHD; ++d) {
        float kv = Ks[tt][d];
#pragma unroll
        for (int j = 0; j < 16; ++j) z1v[j] += W1s[(ss * 16 + j) * CHD + d] * kv;
    }
#pragma unroll
    for (int j = 0; j < 16; ++j) {
        float a = z1v[j];
        X2s[tt][ss * 16 + j] = a * sigf(a);
    }
    __syncthreads();
    {
        float z2v[8] = {};
        for (int h = 0; h < CHDH; ++h) {
            float xv = X2s[tt][h];
#pragma unroll
            for (int j = 0; j < 8; ++j) z2v[j] += W2s[(ss * 8 + j) * CHDH + h] * xv;
        }
#pragma unroll
        for (int j = 0; j < 8; ++j) {
            int d = ss * 8 + j;
            float g = z2v[j] - GZ2s[tt][d];
            GZ2s[tt][d] = g;
        }
    }
    __syncthreads();
    {
        float gx[16] = {};
        for (int d = 0; d < CHD; ++d) {
            float gv = GZ2s[tt][d];
#pragma unroll
            for (int j = 0; j < 16; ++j) gx[j] += W2s[d * CHDH + ss * 16 + j] * gv;
        }
#pragma unroll
        for (int j = 0; j < 16; ++j) {
            float zz = z1v[j];
            float s = sigf(zz);
            float sil = zz * s;
            GZ1s[tt][ss * 16 + j] = (sil + s * (1.f - sil)) * gx[j];
        }
    }
    __syncthreads();
    {
        float4* xg = (float4*)(x2 + ((size_t)bn * CL + l0) * CHDH);
        float4* gg = (float4*)(gz1 + ((size_t)bn * CL + l0) * CHDH);
        for (int i = t; i < 32 * CHDH / 4; i += 256) {
            int row = (i << 2) >> 7, col = (i << 2) & 127;
            float4 v;
            v.x = X2s[row][col]; v.y = X2s[row][col + 1];
            v.z = X2s[row][col + 2]; v.w = X2s[row][col + 3];
            xg[i] = v;
            float4 g;
            g.x = GZ1s[row][col]; g.y = GZ1s[row][col + 1];
            g.z = GZ1s[row][col + 2]; g.w = GZ1s[row][col + 3];
            gg[i] = g;
        }
        float4* zg = (float4*)(gz2 + ((size_t)bn * CL + l0) * CHD);
        for (int i = t; i < 32 * CHD / 4; i += 256) {
            int row = (i << 2) >> 6, col = (i << 2) & 63;
            float4 v;
            v.x = GZ2s[row][col]; v.y = GZ2s[row][col + 1];
            v.z = GZ2s[row][col + 2]; v.w = GZ2s[row][col + 3];
            zg[i] = v;
        }
    }
}

// ---------------------------------------------------------------------------
// attn1 (MFMA bf16): X2_[m,h] = silu( wdc[m]*(W1 q_m)[h]
//                      - sum_{l<=m} (k_l.q_m)*lr[l]*exp(cum[m]-cum[l])*gz1[l,h] )
// block: (m-tile 64, bn). 4 waves. Output x2q in bf16.
// ---------------------------------------------------------------------------
__global__ __launch_bounds__(256) void attn1_mfma(
    const float* __restrict__ qh, const float* __restrict__ kh,
    const float* __restrict__ gz1, const float* __restrict__ W1,
    const float* __restrict__ lrp, const float* __restrict__ cump,
    const float* __restrict__ wdcp, unsigned short* __restrict__ x2q) {
    __shared__ __align__(16) unsigned short Qb[64][72];   // q  [m][d]
    __shared__ __align__(16) unsigned short Wb[128][72];  // W1 [h][d]; reused as out stage
    __shared__ __align__(16) unsigned short Kb[64][72];   // k  [l][d]
    __shared__ __align__(16) unsigned short GT[128][72];  // gz1^T [h][l]
    __shared__ __align__(16) unsigned short Pm[64][72];   // P [m][l]
    __shared__ float lrl[64], cuml[64], cumm[64], wdcm[64];
    const int bn = blockIdx.y, mt = blockIdx.x, m0 = mt << 6;
    const int t = threadIdx.x;
    const int wv = t >> 6, lane = t & 63;
    const int lm = lane & 15, lg = lane >> 4;
    {
        const float4* qg = (const float4*)(qh + ((size_t)bn * CL + m0) * CHD);
        for (int i = t; i < 64 * 64 / 4; i += 256) {
            int r = i >> 4, c = (i & 15) << 2;
            float4 v = qg[i];
            *(uint2*)&Qb[r][c] = make_uint2(pk2(v.x, v.y), pk2(v.z, v.w));
        }
        const float4* wg = (const float4*)(W1 + (size_t)bn * CHDH * CHD);
        for (int i = t; i < 128 * 64 / 4; i += 256) {
            int r = i >> 4, c = (i & 15) << 2;
            float4 v = wg[i];
            *(uint2*)&Wb[r][c] = make_uint2(pk2(v.x, v.y), pk2(v.z, v.w));
        }
        if (t < 64) {
            cumm[t] = cump[(size_t)bn * CL + m0 + t];
            wdcm[t] = wdcp[(size_t)bn * CL + m0 + t];
        }
    }
    __syncthreads();
    // init term: acc[m16][hh], wave wv owns h16 = {2wv, 2wv+1}
    f32x4 acc[4][2];
#pragma unroll
    for (int i = 0; i < 4; ++i)
#pragma unroll
        for (int j = 0; j < 2; ++j) acc[i][j] = (f32x4){0.f, 0.f, 0.f, 0.f};
#pragma unroll
    for (int m16 = 0; m16 < 4; ++m16)
#pragma unroll
        for (int hh = 0; hh < 2; ++hh) {
            int h16 = wv * 2 + hh;
#pragma unroll
            for (int ks = 0; ks < 2; ++ks) {
                short8v a = *(const short8v*)&Qb[m16 * 16 + lm][ks * 32 + lg * 8];
                short8v b = *(const short8v*)&Wb[h16 * 16 + lm][ks * 32 + lg * 8];
                acc[m16][hh] = MFMA16(a, b, acc[m16][hh]);
            }
        }
#pragma unroll
    for (int m16 = 0; m16 < 4; ++m16) {
#pragma unroll
        for (int r = 0; r < 4; ++r) {
            float w = wdcm[m16 * 16 + lg * 4 + r];
            acc[m16][0][r] *= w;
            acc[m16][1][r] *= w;
        }
    }
    for (int lt = 0; lt <= mt; ++lt) {
        const int l0 = lt << 6;
        __syncthreads();  // previous apply done before restaging
        {
            const float4* kg = (const float4*)(kh + ((size_t)bn * CL + l0) * CHD);
            for (int i = t; i < 64 * 64 / 4; i += 256) {
                int r = i >> 4, c = (i & 15) << 2;
                float4 v = kg[i];
                *(uint2*)&Kb[r][c] = make_uint2(pk2(v.x, v.y), pk2(v.z, v.w));
            }
            const float4* gg = (const float4*)(gz1 + ((size_t)bn * CL + l0) * CHDH);
            for (int i = t; i < 64 * 128 / 4; i += 256) {
                int r = i >> 5, c = (i & 31) << 2;  // l row, h col
                float4 v = gg[i];
                GT[c + 0][r] = f2bf(v.x); GT[c + 1][r] = f2bf(v.y);
                GT[c + 2][r] = f2bf(v.z); GT[c + 3][r] = f2bf(v.w);
            }
            if (t < 64) {
                lrl[t] = lrp[(size_t)bn * CL + l0 + t];
                cuml[t] = cump[(size_t)bn * CL + l0 + t];
            }
        }
        __syncthreads();
        // scores: wave wv owns l16 = wv; D[l][m]
        {
            const int mabsb = m0 + lm;
#pragma unroll
            for (int m16 = 0; m16 < 4; ++m16) {
                f32x4 s = (f32x4){0.f, 0.f, 0.f, 0.f};
#pragma unroll
                for (int ks = 0; ks < 2; ++ks) {
                    short8v a = *(const short8v*)&Kb[wv * 16 + lm][ks * 32 + lg * 8];
                    short8v b = *(const short8v*)&Qb[m16 * 16 + lm][ks * 32 + lg * 8];
                    s = MFMA16(a, b, s);
                }
                int mloc = m16 * 16 + lm;
                int mabs = mabsb + m16 * 16;
                float cm = cumm[mloc];
                unsigned short pv[4];
#pragma unroll
                for (int r = 0; r < 4; ++r) {
                    int lloc = wv * 16 + lg * 4 + r;
                    float val = (mabs >= l0 + lloc)
                                    ? s[r] * lrl[lloc] * __expf(cm - cuml[lloc])
                                    : 0.f;
                    pv[r] = f2bf(val);
                }
                *(uint2*)&Pm[mloc][wv * 16 + lg * 4] =
                    make_uint2((unsigned)pv[0] | ((unsigned)pv[1] << 16),
                               (unsigned)pv[2] | ((unsigned)pv[3] << 16));
            }
        }
        __syncthreads();
        // apply: acc[m16][hh] -= P[m][l] * gz1[l][h]
#pragma unroll
        for (int m16 = 0; m16 < 4; ++m16)
#pragma unroll
            for (int hh = 0; hh < 2; ++hh) {
                int h16 = wv * 2 + hh;
                f32x4 p = (f32x4){0.f, 0.f, 0.f, 0.f};
#pragma unroll
                for (int ks = 0; ks < 2; ++ks) {
                    short8v a = *(const short8v*)&Pm[m16 * 16 + lm][ks * 32 + lg * 8];
                    short8v b = *(const short8v*)&GT[h16 * 16 + lm][ks * 32 + lg * 8];
                    p = MFMA16(a, b, p);
                }
#pragma unroll
                for (int r = 0; r < 4; ++r) acc[m16][hh][r] -= p[r];
            }
    }
    __syncthreads();
    // silu + store bf16 via LDS (reuse Wb as [64][136])
    {
        unsigned short(*Ob)[136] = (unsigned short(*)[136])Wb;
#pragma unroll
        for (int m16 = 0; m16 < 4; ++m16)
#pragma unroll
            for (int hh = 0; hh < 2; ++hh) {
                int h = (wv * 2 + hh) * 16 + lm;
#pragma unroll
                for (int r = 0; r < 4; ++r) {
                    int mloc = m16 * 16 + lg * 4 + r;
                    float a = acc[m16][hh][r];
                    Ob[mloc][h] = f2bf(a * sigf(a));
                }
            }
        __syncthreads();
        unsigned short* og = x2q + ((size_t)bn * CL + m0) * CHDH;
        for (int i = t; i < 64 * 128 / 8; i += 256) {
            int r = i >> 4, c = (i & 15) * 8;
            *(uint4*)(og + (size_t)r * CHDH + c) = *(const uint4*)&Ob[r][c];
        }
    }
}

// ---------------------------------------------------------------------------
// attn2 (MFMA bf16): Z2_[m,d] = wdc[m]*(W2 x2_[m])[d]
//          - sum_{l<=m} (x2[l].x2_[m])*lr[l]*exp(cum[m]-cum[l])*gz2[l,d]
// ---------------------------------------------------------------------------
__global__ __launch_bounds__(256) void attn2_mfma(
    const unsigned short* __restrict__ x2q, const float* __restrict__ x2,
    const float* __restrict__ gz2, const float* __restrict__ W2,
    const float* __restrict__ lrp, const float* __restrict__ cump,
    const float* __restrict__ wdcp, float* __restrict__ z2s) {
    __shared__ __align__(16) unsigned short X2qb[64][136];  // x2_ [m][h]
    __shared__ __align__(16) unsigned short W2b[64][136];   // W2 [d][h]; reused as f32 out stage
    __shared__ __align__(16) unsigned short X2l[64][136];   // x2 [l][h]
    __shared__ __align__(16) unsigned short GT2[64][72];    // gz2^T [d][l]
    __shared__ __align__(16) unsigned short Pm[64][72];     // P [m][l]
    __shared__ float lrl[64], cuml[64], cumm[64], wdcm[64];
    const int bn = blockIdx.y, mt = blockIdx.x, m0 = mt << 6;
    const int t = threadIdx.x;
    const int wv = t >> 6, lane = t & 63;
    const int lm = lane & 15, lg = lane >> 4;
    {
        const uint4* qg = (const uint4*)(x2q + ((size_t)bn * CL + m0) * CHDH);
        for (int i = t; i < 64 * 128 / 8; i += 256) {
            int r = i >> 4, c = (i & 15) * 8;
            *(uint4*)&X2qb[r][c] = qg[i];
        }
        const float4* wg = (const float4*)(W2 + (size_t)bn * CHD * CHDH);
        for (int i = t; i < 64 * 128 / 4; i += 256) {
            int r = i >> 5, c = (i & 31) << 2;
            float4 v = wg[i];
            *(uint2*)&W2b[r][c] = make_uint2(pk2(v.x, v.y), pk2(v.z, v.w));
        }
        if (t < 64) {
            cumm[t] = cump[(size_t)bn * CL + m0 + t];
            wdcm[t] = wdcp[(size_t)bn * CL + m0 + t];
        }
    }
    __syncthreads();
    // init: acc[m16], wave wv owns d16 = wv
    f32x4 acc[4];
#pragma unroll
    for (int i = 0; i < 4; ++i) acc[i] = (f32x4){0.f, 0.f, 0.f, 0.f};
#pragma unroll
    for (int m16 = 0; m16 < 4; ++m16)
#pragma unroll
        for (int ks = 0; ks < 4; ++ks) {
            short8v a = *(const short8v*)&X2qb[m16 * 16 + lm][ks * 32 + lg * 8];
            short8v b = *(const short8v*)&W2b[wv * 16 + lm][ks * 32 + lg * 8];
            acc[m16] = MFMA16(a, b, acc[m16]);
        }
#pragma unroll
    for (int m16 = 0; m16 < 4; ++m16)
#pragma unroll
        for (int r = 0; r < 4; ++r) acc[m16][r] *= wdcm[m16 * 16 + lg * 4 + r];
    for (int lt = 0; lt <= mt; ++lt) {
        const int l0 = lt << 6;
        __syncthreads();
        {
            const float4* kg = (const float4*)(x2 + ((size_t)bn * CL + l0) * CHDH);
            for (int i = t; i < 64 * 128 / 4; i += 256) {
                int r = i >> 5, c = (i & 31) << 2;
                float4 v = kg[i];
                *(uint2*)&X2l[r][c] = make_uint2(pk2(v.x, v.y), pk2(v.z, v.w));
            }
            const float4* gg = (const float4*)(gz2 + ((size_t)bn * CL + l0) * CHD);
            for (int i = t; i < 64 * 64 / 4; i += 256) {
                int r = i >> 4, c = (i & 15) << 2;  // l row, d col
                float4 v = gg[i];
                GT2[c + 0][r] = f2bf(v.x); GT2[c + 1][r] = f2bf(v.y);
                GT2[c + 2][r] = f2bf(v.z); GT2[c + 3][r] = f2bf(v.w);
            }
            if (t < 64) {
                lrl[t] = lrp[(size_t)bn * CL + l0 + t];
                cuml[t] = cump[(size_t)bn * CL + l0 + t];
            }
        }
        __syncthreads();
        {
            const int mabsb = m0 + lm;
#pragma unroll
            for (int m16 = 0; m16 < 4; ++m16) {
                f32x4 s = (f32x4){0.f, 0.f, 0.f, 0.f};
#pragma unroll
                for (int ks = 0; ks < 4; ++ks) {
                    short8v a = *(const short8v*)&X2l[wv * 16 + lm][ks * 32 + lg * 8];
                    short8v b = *(const short8v*)&X2qb[m16 * 16 + lm][ks * 32 + lg * 8];
                    s = MFMA16(a, b, s);
                }
                int mloc = m16 * 16 + lm;
                int mabs = mabsb + m16 * 16;
                float cm = cumm[mloc];
                unsigned short pv[4];
#pragma unroll
                for (int r = 0; r < 4; ++r) {
                    int lloc = wv * 16 + lg * 4 + r;
                    float val = (mabs >= l0 + lloc)
                                    ? s[r] * lrl[lloc] * __expf(cm - cuml[lloc])
                                    : 0.f;
                    pv[r] = f2bf(val);
                }
                *(uint2*)&Pm[mloc][wv * 16 + lg * 4] =
                    make_uint2((unsigned)pv[0] | ((unsigned)pv[1] << 16),
                               (unsigned)pv[2] | ((unsigned)pv[3] << 16));
            }
        }
        __syncthreads();
#pragma unroll
        for (int m16 = 0; m16 < 4; ++m16) {
            f32x4 p = (f32x4){0.f, 0.f, 0.f, 0.f};
#pragma unroll
            for (int ks = 0; ks < 2; ++ks) {
                short8v a = *(const short8v*)&Pm[m16 * 16 + lm][ks * 32 + lg * 8];
                short8v b = *(const short8v*)&GT2[wv * 16 + lm][ks * 32 + lg * 8];
                p = MFMA16(a, b, p);
            }
#pragma unroll
            for (int r = 0; r < 4; ++r) acc[m16][r] -= p[r];
        }
    }
    __syncthreads();
    {
        float(*Os)[68] = (float(*)[68])W2b;
#pragma unroll
        for (int m16 = 0; m16 < 4; ++m16)
#pragma unroll
            for (int r = 0; r < 4; ++r)
                Os[m16 * 16 + lg * 4 + r][wv * 16 + lm] = acc[m16][r];
        __syncthreads();
        float* zg = z2s + ((size_t)bn * CL + m0) * CHD;
        for (int i = t; i < 64 * 64 / 4; i += 256) {
            int r = i >> 4, c = (i & 15) << 2;
            *(float4*)(zg + (size_t)r * CHD + c) = *(const float4*)&Os[r][c];
        }
    }
}

// ---------------------------------------------------------------------------
// W1_next[h,d] = wdc_last*W1[h,d] - sum_l lr[l]*exp(cum_last-cum[l])*gz1[l,h]*k[l,d]
// ---------------------------------------------------------------------------
__global__ __launch_bounds__(256) void w1next_kernel(
    const float* __restrict__ gz1, const float* __restrict__ kh,
    const float* __restrict__ W1, const float* __restrict__ lrp,
    const float* __restrict__ cump, float* __restrict__ outw) {
    __shared__ float Gs[64][65];
    __shared__ float Ks[64][65];
    __shared__ float coefs[64];
    const int bn = blockIdx.y;
    const int h0 = blockIdx.x << 6;
    const int t = threadIdx.x;
    const float cum_last = cump[(size_t)bn * CL + CL - 1];
    const float wdcl = __expf(cum_last);
    const int hi = t >> 4, di = t & 15;
    float acc[4][4] = {};
    for (int l0 = 0; l0 < CL; l0 += 64) {
        for (int i = t; i < 64 * 64 / 4; i += 256) {
            int row = (i << 2) >> 6, col = (i << 2) & 63;
            float4 g = *(const float4*)(gz1 + ((size_t)bn * CL + l0 + row) * CHDH + h0 + col);
            Gs[row][col] = g.x; Gs[row][col + 1] = g.y;
            Gs[row][col + 2] = g.z; Gs[row][col + 3] = g.w;
            float4 k = *(const float4*)(kh + ((size_t)bn * CL + l0 + row) * CHD + col);
            Ks[row][col] = k.x; Ks[row][col + 1] = k.y;
            Ks[row][col + 2] = k.z; Ks[row][col + 3] = k.w;
        }
        if (t < 64)
            coefs[t] = lrp[(size_t)bn * CL + l0 + t] *
                       __expf(cum_last - cump[(size_t)bn * CL + l0 + t]);
        __syncthreads();
        for (int l = 0; l < 64; ++l) {
            float c = coefs[l];
            float g4[4], k4[4];
#pragma unroll
            for (int i = 0; i < 4; ++i) g4[i] = Gs[l][hi * 4 + i] * c;
#pragma unroll
            for (int j = 0; j < 4; ++j) k4[j] = Ks[l][di * 4 + j];
#pragma unroll
            for (int i = 0; i < 4; ++i)
#pragma unroll
                for (int j = 0; j < 4; ++j) acc[i][j] += g4[i] * k4[j];
        }
        __syncthreads();
    }
    const float* w1g = W1 + (size_t)bn * CHDH * CHD;
#pragma unroll
    for (int i = 0; i < 4; ++i) {
        int h = h0 + hi * 4 + i;
        int d = di * 4;
        float4 o;
        o.x = wdcl * w1g[h * CHD + d + 0] - acc[i][0];
        o.y = wdcl * w1g[h * CHD + d + 1] - acc[i][1];
        o.z = wdcl * w1g[h * CHD + d + 2] - acc[i][2];
        o.w = wdcl * w1g[h * CHD + d + 3] - acc[i][3];
        *(float4*)(outw + (size_t)bn * CHDH * CHD + h * CHD + d) = o;
    }
}

// ---------------------------------------------------------------------------
// W2_next[d,h] = wdc_last*W2[d,h] - sum_l lr[l]*exp(cum_last-cum[l])*gz2[l,d]*x2[l,h]
// ---------------------------------------------------------------------------
__global__ __launch_bounds__(256) void w2next_kernel(
    const float* __restrict__ gz2, const float* __restrict__ x2,
    const float* __restrict__ W2, const float* __restrict__ lrp,
    const float* __restrict__ cump, float* __restrict__ outw) {
    __shared__ float Gs[64][65];
    __shared__ float Xs[64][65];
    __shared__ float coefs[64];
    const int bn = blockIdx.y;
    const int h0 = blockIdx.x << 6;
    const int t = threadIdx.x;
    const float cum_last = cump[(size_t)bn * CL + CL - 1];
    const float wdcl = __expf(cum_last);
    const int di = t >> 4, hi = t & 15;
    float acc[4][4] = {};
    for (int l0 = 0; l0 < CL; l0 += 64) {
        for (int i = t; i < 64 * 64 / 4; i += 256) {
            int row = (i << 2) >> 6, col = (i << 2) & 63;
            float4 g = *(const float4*)(gz2 + ((size_t)bn * CL + l0 + row) * CHD + col);
            Gs[row][col] = g.x; Gs[row][col + 1] = g.y;
            Gs[row][col + 2] = g.z; Gs[row][col + 3] = g.w;
            float4 xv = *(const float4*)(x2 + ((size_t)bn * CL + l0 + row) * CHDH + h0 + col);
            Xs[row][col] = xv.x; Xs[row][col + 1] = xv.y;
            Xs[row][col + 2] = xv.z; Xs[row][col + 3] = xv.w;
        }
        if (t < 64)
            coefs[t] = lrp[(size_t)bn * CL + l0 + t] *
                       __expf(cum_last - cump[(size_t)bn * CL + l0 + t]);
        __syncthreads();
        for (int l = 0; l < 64; ++l) {
            float c = coefs[l];
            float g4[4], x4[4];
#pragma unroll
            for (int i = 0; i < 4; ++i) g4[i] = Gs[l][di * 4 + i] * c;
#pragma unroll
            for (int j = 0; j < 4; ++j) x4[j] = Xs[l][hi * 4 + j];
#pragma unroll
            for (int i = 0; i < 4; ++i)
#pragma unroll
                for (int j = 0; j < 4; ++j) acc[i][j] += g4[i] * x4[j];
        }
        __syncthreads();
    }
    const float* w2g = W2 + (size_t)bn * CHD * CHDH;
#pragma unroll
    for (int i = 0; i < 4; ++i) {
        int d = di * 4 + i;
        int h = h0 + hi * 4;
        float4 o;
        o.x = wdcl * w2g[d * CHDH + h + 0] - acc[i][0];
        o.y = wdcl * w2g[d * CHDH + h + 1] - acc[i][1];
        o.z = wdcl * w2g[d * CHDH + h + 2] - acc[i][2];
        o.w = wdcl * w2g[d * CHDH + h + 3] - acc[i][3];
        *(float4*)(outw + (size_t)bn * CHD * CHDH + d * CHDH + h) = o;
    }
}

// ---------------------------------------------------------------------------
extern "C" void kernel_launch(void* const* d_in, const int* in_sizes, int n_in,
                              void* d_out, int out_size, void* d_ws, size_t ws_size,
                              hipStream_t stream) {
    (void)in_sizes; (void)n_in; (void)out_size; (void)ws_size;
    const float* x      = (const float*)d_in[0];
    const float* W1     = (const float*)d_in[1];
    const float* W2     = (const float*)d_in[2];
    const float* lblr   = (const float*)d_in[3];
    const float* fclr_w = (const float*)d_in[4];
    const float* fclr_b = (const float*)d_in[5];
    const float* lbwd   = (const float*)d_in[6];
    const float* fcwd_w = (const float*)d_in[7];
    const float* fcwd_b = (const float*)d_in[8];
    const float* qw = (const float*)d_in[9];
    const float* qb = (const float*)d_in[10];
    const float* kw = (const float*)d_in[11];
    const float* kb = (const float*)d_in[12];
    const float* vw = (const float*)d_in[13];
    const float* vb = (const float*)d_in[14];
    const float* ow = (const float*)d_in[15];
    const float* ob = (const float*)d_in[16];

    float* ws = (float*)d_ws;
    const size_t SZ_HD = (size_t)CBN * CL * CHD;
    const size_t SZ_HDH = (size_t)CBN * CL * CHDH;
    float* qh   = ws;
    float* khb  = qh + SZ_HD;
    float* vhb  = khb + SZ_HD;
    float* gz2b = vhb + SZ_HD;
    float* z2sb = gz2b + SZ_HD;
    float* x2b  = z2sb + SZ_HD;
    float* gz1b = x2b + SZ_HDH;
    float* x2qb = gz1b + SZ_HDH;  // reinterpreted as bf16
    float* lrb  = x2qb + SZ_HDH;
    float* cumb = lrb + (size_t)CBN * CL;
    float* wdcb = cumb + (size_t)CBN * CL;

    float* outp = (float*)d_out;
    float* w1n = outp + (size_t)CB * CL * CD;
    float* w2n = w1n + (size_t)CBN * CHDH * CHD;

    dim3 gBig(CD / 64, (CB * CL) / 64);
    gemm_big<0, 1><<<gBig, 256, 0, stream>>>(x, qw, qb, qh);
    gemm_big<0, 1><<<gBig, 256, 0, stream>>>(x, kw, kb, khb);
    gemm_big<0, 1><<<gBig, 256, 0, stream>>>(x, vw, vb, vhb);
    lrwd_kernel<<<CB * CL, 64, 0, stream>>>(x, lblr, fclr_w, fclr_b, lbwd, fcwd_w,
                                            fcwd_b, lrb, cumb);
    scan_kernel<<<CBN, 64, 0, stream>>>(cumb, wdcb);
    mlp_kernel<<<dim3(CL / 32, CBN), 256, 0, stream>>>(khb, vhb, W1, W2, x2b, gz1b, gz2b);
    attn1_mfma<<<dim3(CL / 64, CBN), 256, 0, stream>>>(qh, khb, gz1b, W1, lrb, cumb,
                                                       wdcb, (unsigned short*)x2qb);
    attn2_mfma<<<dim3(CL / 64, CBN), 256, 0, stream>>>((const unsigned short*)x2qb, x2b,
                                                       gz2b, W2, lrb, cumb, wdcb, z2sb);
    w1next_kernel<<<dim3(2, CBN), 256, 0, stream>>>(gz1b, khb, W1, lrb, cumb, w1n);
    w2next_kernel<<<dim3(2, CBN), 256, 0, stream>>>(gz2b, x2b, W2, lrb, cumb, w2n);
    gemm_big<1, 0><<<gBig, 256, 0, stream>>>(z2sb, ow, ob, outp);
}

// Round 3
// 506.008 us; speedup vs baseline: 2.4513x; 1.4135x over previous
//
#include <hip/hip_runtime.h>

constexpr int CB = 2, CL = 1024, CD = 1024, CNH = 16, CHD = 64, CHDH = 128, CBN = CB * CNH;

__device__ __forceinline__ float sigf(float x) { return 1.0f / (1.0f + __expf(-x)); }

// round-to-nearest-even float -> bf16
__device__ __forceinline__ unsigned short f2bf(float x) {
    unsigned u = __float_as_uint(x);
    u += 0x7fffu + ((u >> 16) & 1u);
    return (unsigned short)(u >> 16);
}
__device__ __forceinline__ unsigned pk2(float a, float b) {
    return (unsigned)f2bf(a) | ((unsigned)f2bf(b) << 16);
}

typedef __attribute__((ext_vector_type(8))) short short8v;
typedef __attribute__((ext_vector_type(4))) float f32x4;
#define MFMA16(a, b, c) __builtin_amdgcn_mfma_f32_16x16x32_bf16(a, b, c, 0, 0, 0)

// ---------------------------------------------------------------------------
// Convert x, qw, kw, vw to bf16 in one pass.
// ---------------------------------------------------------------------------
__global__ __launch_bounds__(256) void tobf_kernel(
    const float* __restrict__ x, const float* __restrict__ qw,
    const float* __restrict__ kw, const float* __restrict__ vw,
    unsigned short* __restrict__ xb, unsigned short* __restrict__ qwb,
    unsigned short* __restrict__ kwb, unsigned short* __restrict__ vwb) {
    int i = blockIdx.x * 256 + threadIdx.x;  // 0 .. 1310719 (x4 floats)
    const float* s;
    unsigned short* d;
    int off;
    if (i < 524288) { s = x; d = xb; off = i; }
    else if (i < 786432) { s = qw; d = qwb; off = i - 524288; }
    else if (i < 1048576) { s = kw; d = kwb; off = i - 786432; }
    else { s = vw; d = vwb; off = i - 1048576; }
    float4 v = *(const float4*)(s + (size_t)off * 4);
    *(uint2*)(d + (size_t)off * 4) = make_uint2(pk2(v.x, v.y), pk2(v.z, v.w));
}

// ---------------------------------------------------------------------------
// MFMA bf16 GEMM: C[r][c] = sum_k A[r][k]*W[c][k] + bias[c]; 64x64 tile.
// Output scattered to per-head layout [b][n][l][64]. fp32 and/or bf16.
// ---------------------------------------------------------------------------
template <int STOREF, int BFOUT>
__global__ __launch_bounds__(256) void gemm_bf(const unsigned short* __restrict__ A,
                                               const unsigned short* __restrict__ Bw,
                                               const float* __restrict__ bias,
                                               float* __restrict__ Cf,
                                               unsigned short* __restrict__ Cb) {
    __shared__ __align__(16) unsigned short As[64][72];
    __shared__ __align__(16) unsigned short Bs[64][72];
    __shared__ float Os[64][68];
    const int t = threadIdx.x;
    const int r0 = blockIdx.y << 6, c0 = blockIdx.x << 6;
    const int wv = t >> 6, lane = t & 63;
    const int lm = lane & 15, lg = lane >> 4;
    f32x4 acc[4];
#pragma unroll
    for (int i = 0; i < 4; ++i) acc[i] = (f32x4){0.f, 0.f, 0.f, 0.f};
    for (int kc = 0; kc < CD; kc += 64) {
        for (int i = t; i < 512; i += 256) {
            int r = i >> 3, c = (i & 7) * 8;
            *(uint4*)&As[r][c] = *(const uint4*)(A + (size_t)(r0 + r) * CD + kc + c);
            *(uint4*)&Bs[r][c] = *(const uint4*)(Bw + (size_t)(c0 + r) * CD + kc + c);
        }
        __syncthreads();
#pragma unroll
        for (int n16 = 0; n16 < 4; ++n16)
#pragma unroll
            for (int ks = 0; ks < 2; ++ks) {
                short8v a = *(const short8v*)&As[wv * 16 + lm][ks * 32 + lg * 8];
                short8v b = *(const short8v*)&Bs[n16 * 16 + lm][ks * 32 + lg * 8];
                acc[n16] = MFMA16(a, b, acc[n16]);
            }
        __syncthreads();
    }
#pragma unroll
    for (int n16 = 0; n16 < 4; ++n16) {
        float bb = bias[c0 + n16 * 16 + lm];
#pragma unroll
        for (int r = 0; r < 4; ++r)
            Os[wv * 16 + lg * 4 + r][n16 * 16 + lm] = acc[n16][r] + bb;
    }
    __syncthreads();
    const int nh = c0 >> 6;
    for (int i = t; i < 1024; i += 256) {
        int r = i >> 4, c = (i & 15) * 4;
        float4 v = *(const float4*)&Os[r][c];
        int rr = r0 + r, b = rr >> 10, l = rr & 1023;
        size_t base = (((size_t)b * CNH + nh) * CL + l) * 64 + c;
        if (STOREF) *(float4*)(Cf + base) = v;
        if (BFOUT) *(uint2*)(Cb + base) = make_uint2(pk2(v.x, v.y), pk2(v.z, v.w));
    }
}

// ---------------------------------------------------------------------------
// Big fp32 GEMM (o-projection only): A gathered from per-head z2s.
// ---------------------------------------------------------------------------
__global__ __launch_bounds__(256) void gemm_big(const float* __restrict__ A,
                                                const float* __restrict__ Bw,
                                                const float* __restrict__ bias,
                                                float* __restrict__ C) {
    __shared__ float As[16][68];
    __shared__ float Bs[16][68];
    const int t = threadIdx.x;
    const int r0 = blockIdx.y << 6;
    const int c0 = blockIdx.x << 6;
    const int lrow = t >> 2;
    const int lk4 = (t & 3) << 2;
    const int tr = t >> 4, tc = t & 15;
    float acc[4][4] = {};
    for (int kc = 0; kc < CD; kc += 16) {
        const int ar = r0 + lrow;
        const int ak = kc + lk4;
        int b = ar >> 10, l = ar & 1023;
        int n = ak >> 6, d = ak & 63;
        float4 av = *(const float4*)(A + ((((size_t)b * CNH + n) * CL + l) << 6) + d);
        float4 bv = *(const float4*)(Bw + (size_t)(c0 + lrow) * CD + ak);
        As[lk4 + 0][lrow] = av.x; As[lk4 + 1][lrow] = av.y;
        As[lk4 + 2][lrow] = av.z; As[lk4 + 3][lrow] = av.w;
        Bs[lk4 + 0][lrow] = bv.x; Bs[lk4 + 1][lrow] = bv.y;
        Bs[lk4 + 2][lrow] = bv.z; Bs[lk4 + 3][lrow] = bv.w;
        __syncthreads();
#pragma unroll
        for (int kk = 0; kk < 16; ++kk) {
            float4 a4 = *(const float4*)(&As[kk][tr << 2]);
            float4 b4 = *(const float4*)(&Bs[kk][tc << 2]);
            float a[4] = {a4.x, a4.y, a4.z, a4.w};
            float b[4] = {b4.x, b4.y, b4.z, b4.w};
#pragma unroll
            for (int i = 0; i < 4; ++i)
#pragma unroll
                for (int j = 0; j < 4; ++j) acc[i][j] += a[i] * b[j];
        }
        __syncthreads();
    }
#pragma unroll
    for (int i = 0; i < 4; ++i) {
        const int r = r0 + tr * 4 + i;
        const int c = c0 + tc * 4;
        float4 o;
        o.x = acc[i][0] + bias[c + 0];
        o.y = acc[i][1] + bias[c + 1];
        o.z = acc[i][2] + bias[c + 2];
        o.w = acc[i][3] + bias[c + 3];
        *(float4*)(C + (size_t)r * CD + c) = o;
    }
}

// ---------------------------------------------------------------------------
// lr / log_wd projections: one wave per token row.
// ---------------------------------------------------------------------------
__global__ __launch_bounds__(64) void lrwd_kernel(
    const float* __restrict__ x, const float* __restrict__ lblr,
    const float* __restrict__ fclr_w, const float* __restrict__ fclr_b,
    const float* __restrict__ lbwd, const float* __restrict__ fcwd_w,
    const float* __restrict__ fcwd_b, float* __restrict__ lrp,
    float* __restrict__ logwd) {
    const int r = blockIdx.x;
    const int b = r >> 10, l = r & 1023;
    const int lane = threadIdx.x;
    float xv[16];
#pragma unroll
    for (int j = 0; j < 16; ++j) xv[j] = x[(size_t)r * CD + lane + 64 * j];
    for (int n = 0; n < CNH; ++n) {
        float d1 = 0.f, d2 = 0.f;
#pragma unroll
        for (int j = 0; j < 16; ++j) {
            d1 += xv[j] * fclr_w[(size_t)n * CD + lane + 64 * j];
            d2 += xv[j] * fcwd_w[(size_t)n * CD + lane + 64 * j];
        }
#pragma unroll
        for (int s = 32; s > 0; s >>= 1) {
            d1 += __shfl_down(d1, s);
            d2 += __shfl_down(d2, s);
        }
        if (lane == 0) {
            lrp[((size_t)b * CNH + n) * CL + l] = __expf(lblr[n]) * sigf(d1 + fclr_b[n]);
            logwd[((size_t)b * CNH + n) * CL + l] =
                log1pf(-__expf(lbwd[n]) * sigf(d2 + fcwd_b[n]));
        }
    }
}

// ---------------------------------------------------------------------------
// Inclusive prefix sum of log_wd -> cum, plus wdc = exp(cum).
// ---------------------------------------------------------------------------
__global__ __launch_bounds__(64) void scan_kernel(float* __restrict__ cum,
                                                  float* __restrict__ wdc) {
    const int bn = blockIdx.x;
    const int lane = threadIdx.x;
    float* p = cum + (size_t)bn * CL;
    float v[16];
#pragma unroll
    for (int j = 0; j < 16; ++j) v[j] = p[lane * 16 + j];
#pragma unroll
    for (int j = 1; j < 16; ++j) v[j] += v[j - 1];
    float tot = v[15];
    float inc = tot;
#pragma unroll
    for (int s = 1; s < 64; s <<= 1) {
        float tv = __shfl_up(inc, s);
        if (lane >= s) inc += tv;
    }
    const float pre = inc - tot;
#pragma unroll
    for (int j = 0; j < 16; ++j) {
        float c = pre + v[j];
        p[lane * 16 + j] = c;
        wdc[(size_t)bn * CL + lane * 16 + j] = __expf(c);
    }
}

// ---------------------------------------------------------------------------
// Fused per-head MLP fwd/bwd over a 32-token tile. Emits fp32 (for W-next)
// and bf16 copies (x2 row-major, gz1^T/gz2^T in [h][L]) for attn kernels.
// ---------------------------------------------------------------------------
__global__ __launch_bounds__(256) void mlp_kernel(
    const float* __restrict__ kh, const float* __restrict__ vh,
    const float* __restrict__ W1, const float* __restrict__ W2,
    float* __restrict__ x2, float* __restrict__ gz1, float* __restrict__ gz2,
    unsigned short* __restrict__ x2bf, unsigned short* __restrict__ gz1t,
    unsigned short* __restrict__ gz2t) {
    __shared__ float W1s[CHDH * CHD];
    __shared__ float W2s[CHD * CHDH];
    __shared__ float Ks[32][65];
    __shared__ float X2s[32][129];
    __shared__ float GZ2s[32][65];
    __shared__ float GZ1s[32][129];
    const int bn = blockIdx.y;
    const int l0 = blockIdx.x << 5;
    const int t = threadIdx.x;
    {
        const float4* w1g = (const float4*)(W1 + (size_t)bn * CHDH * CHD);
        const float4* w2g = (const float4*)(W2 + (size_t)bn * CHD * CHDH);
        float4* w1l = (float4*)W1s;
        float4* w2l = (float4*)W2s;
        for (int i = t; i < CHDH * CHD / 4; i += 256) {
            w1l[i] = w1g[i];
            w2l[i] = w2g[i];
        }
        const float4* kg = (const float4*)(kh + ((size_t)bn * CL + l0) * CHD);
        const float4* vg = (const float4*)(vh + ((size_t)bn * CL + l0) * CHD);
        for (int i = t; i < 32 * CHD / 4; i += 256) {
            int row = (i << 2) >> 6, col = (i << 2) & 63;
            float4 kv = kg[i];
            Ks[row][col] = kv.x; Ks[row][col + 1] = kv.y;
            Ks[row][col + 2] = kv.z; Ks[row][col + 3] = kv.w;
            float4 vv = vg[i];
            GZ2s[row][col] = vv.x; GZ2s[row][col + 1] = vv.y;
            GZ2s[row][col + 2] = vv.z; GZ2s[row][col + 3] = vv.w;
        }
    }
    __syncthreads();
    const int tt = t & 31;
    const int ss = t >> 5;
    float z1v[16] = {};
    for (int d = 0; d < CHD; ++d) {
        float kv = Ks[tt][d];
#pragma unroll
        for (int j = 0; j < 16; ++j) z1v[j] += W1s[(ss * 16 + j) * CHD + d] * kv;
    }
#pragma unroll
    for (int j = 0; j < 16; ++j) {
        float a = z1v[j];
        X2s[tt][ss * 16 + j] = a * sigf(a);
    }
    __syncthreads();
    {
        float z2v[8] = {};
        for (int h = 0; h < CHDH; ++h) {
            float xv = X2s[tt][h];
#pragma unroll
            for (int j = 0; j < 8; ++j) z2v[j] += W2s[(ss * 8 + j) * CHDH + h] * xv;
        }
#pragma unroll
        for (int j = 0; j < 8; ++j) {
            int d = ss * 8 + j;
            float g = z2v[j] - GZ2s[tt][d];
            GZ2s[tt][d] = g;
        }
    }
    __syncthreads();
    {
        float gx[16] = {};
        for (int d = 0; d < CHD; ++d) {
            float gv = GZ2s[tt][d];
#pragma unroll
            for (int j = 0; j < 16; ++j) gx[j] += W2s[d * CHDH + ss * 16 + j] * gv;
        }
#pragma unroll
        for (int j = 0; j < 16; ++j) {
            float zz = z1v[j];
            float s = sigf(zz);
            float sil = zz * s;
            GZ1s[tt][ss * 16 + j] = (sil + s * (1.f - sil)) * gx[j];
        }
    }
    __syncthreads();
    {
        float4* xg = (float4*)(x2 + ((size_t)bn * CL + l0) * CHDH);
        float4* gg = (float4*)(gz1 + ((size_t)bn * CL + l0) * CHDH);
        for (int i = t; i < 32 * CHDH / 4; i += 256) {
            int row = (i << 2) >> 7, col = (i << 2) & 127;
            float4 v;
            v.x = X2s[row][col]; v.y = X2s[row][col + 1];
            v.z = X2s[row][col + 2]; v.w = X2s[row][col + 3];
            xg[i] = v;
            float4 g;
            g.x = GZ1s[row][col]; g.y = GZ1s[row][col + 1];
            g.z = GZ1s[row][col + 2]; g.w = GZ1s[row][col + 3];
            gg[i] = g;
        }
        float4* zg = (float4*)(gz2 + ((size_t)bn * CL + l0) * CHD);
        for (int i = t; i < 32 * CHD / 4; i += 256) {
            int row = (i << 2) >> 6, col = (i << 2) & 63;
            float4 v;
            v.x = GZ2s[row][col]; v.y = GZ2s[row][col + 1];
            v.z = GZ2s[row][col + 2]; v.w = GZ2s[row][col + 3];
            zg[i] = v;
        }
        // bf16 copies for the attention kernels
        for (int i = t; i < 512; i += 256) {  // x2 bf16 [l][128]
            int r = i >> 4, c = (i & 15) * 8;
            uint4 u;
            u.x = pk2(X2s[r][c + 0], X2s[r][c + 1]);
            u.y = pk2(X2s[r][c + 2], X2s[r][c + 3]);
            u.z = pk2(X2s[r][c + 4], X2s[r][c + 5]);
            u.w = pk2(X2s[r][c + 6], X2s[r][c + 7]);
            *(uint4*)(x2bf + ((size_t)bn * CL + l0 + r) * CHDH + c) = u;
        }
        for (int i = t; i < 512; i += 256) {  // gz1^T bf16 [h][CL]
            int r = i >> 2, c = (i & 3) * 8;
            uint4 u;
            u.x = pk2(GZ1s[c + 0][r], GZ1s[c + 1][r]);
            u.y = pk2(GZ1s[c + 2][r], GZ1s[c + 3][r]);
            u.z = pk2(GZ1s[c + 4][r], GZ1s[c + 5][r]);
            u.w = pk2(GZ1s[c + 6][r], GZ1s[c + 7][r]);
            *(uint4*)(gz1t + ((size_t)bn * CHDH + r) * CL + l0 + c) = u;
        }
        for (int i = t; i < 256; i += 256) {  // gz2^T bf16 [d][CL]
            int r = i >> 2, c = (i & 3) * 8;
            uint4 u;
            u.x = pk2(GZ2s[c + 0][r], GZ2s[c + 1][r]);
            u.y = pk2(GZ2s[c + 2][r], GZ2s[c + 3][r]);
            u.z = pk2(GZ2s[c + 4][r], GZ2s[c + 5][r]);
            u.w = pk2(GZ2s[c + 6][r], GZ2s[c + 7][r]);
            *(uint4*)(gz2t + ((size_t)bn * CHD + r) * CL + l0 + c) = u;
        }
    }
}

// ---------------------------------------------------------------------------
// attn1 (MFMA bf16): X2_[m,h] = silu( wdc[m]*(W1 q_m)[h]
//                      - sum_{l<=m} (k_l.q_m)*lr[l]*exp(cum[m]-cum[l])*gz1[l,h] )
// All MFMA operands pre-staged bf16 in global. Output x2q bf16.
// ---------------------------------------------------------------------------
__global__ __launch_bounds__(256) void attn1_mfma(
    const unsigned short* __restrict__ qbf, const unsigned short* __restrict__ kbf,
    const unsigned short* __restrict__ gz1t, const float* __restrict__ W1,
    const float* __restrict__ lrp, const float* __restrict__ cump,
    const float* __restrict__ wdcp, unsigned short* __restrict__ x2q) {
    __shared__ __align__(16) unsigned short Qb[64][72];   // q  [m][d]
    __shared__ __align__(16) unsigned short Wb[128][72];  // W1 [h][d]; reused as out stage
    __shared__ __align__(16) unsigned short Kb[64][72];   // k  [l][d]
    __shared__ __align__(16) unsigned short GT[128][72];  // gz1^T [h][l]
    __shared__ __align__(16) unsigned short Pm[64][72];   // P [m][l]
    __shared__ float lrl[64], cuml[64], cumm[64], wdcm[64];
    const int bn = blockIdx.y, mt = blockIdx.x, m0 = mt << 6;
    const int t = threadIdx.x;
    const int wv = t >> 6, lane = t & 63;
    const int lm = lane & 15, lg = lane >> 4;
    {
        const unsigned short* qg = qbf + ((size_t)bn * CL + m0) * CHD;
        for (int i = t; i < 512; i += 256) {
            int r = i >> 3, c = (i & 7) * 8;
            *(uint4*)&Qb[r][c] = *(const uint4*)(qg + (size_t)r * CHD + c);
        }
        const float4* wg = (const float4*)(W1 + (size_t)bn * CHDH * CHD);
        for (int i = t; i < 2048; i += 256) {
            int r = i >> 4, c = (i & 15) << 2;
            float4 v = wg[i];
            *(uint2*)&Wb[r][c] = make_uint2(pk2(v.x, v.y), pk2(v.z, v.w));
        }
        if (t < 64) {
            cumm[t] = cump[(size_t)bn * CL + m0 + t];
            wdcm[t] = wdcp[(size_t)bn * CL + m0 + t];
        }
    }
    __syncthreads();
    f32x4 acc[4][2];
#pragma unroll
    for (int i = 0; i < 4; ++i)
#pragma unroll
        for (int j = 0; j < 2; ++j) acc[i][j] = (f32x4){0.f, 0.f, 0.f, 0.f};
#pragma unroll
    for (int m16 = 0; m16 < 4; ++m16)
#pragma unroll
        for (int hh = 0; hh < 2; ++hh) {
            int h16 = wv * 2 + hh;
#pragma unroll
            for (int ks = 0; ks < 2; ++ks) {
                short8v a = *(const short8v*)&Qb[m16 * 16 + lm][ks * 32 + lg * 8];
                short8v b = *(const short8v*)&Wb[h16 * 16 + lm][ks * 32 + lg * 8];
                acc[m16][hh] = MFMA16(a, b, acc[m16][hh]);
            }
        }
#pragma unroll
    for (int m16 = 0; m16 < 4; ++m16) {
#pragma unroll
        for (int r = 0; r < 4; ++r) {
            float w = wdcm[m16 * 16 + lg * 4 + r];
            acc[m16][0][r] *= w;
            acc[m16][1][r] *= w;
        }
    }
    for (int lt = 0; lt <= mt; ++lt) {
        const int l0 = lt << 6;
        __syncthreads();
        {
            const unsigned short* kg = kbf + ((size_t)bn * CL + l0) * CHD;
            for (int i = t; i < 512; i += 256) {
                int r = i >> 3, c = (i & 7) * 8;
                *(uint4*)&Kb[r][c] = *(const uint4*)(kg + (size_t)r * CHD + c);
            }
            const unsigned short* gg = gz1t + (size_t)bn * CHDH * CL + l0;
            for (int i = t; i < 1024; i += 256) {
                int r = i >> 3, c = (i & 7) * 8;
                *(uint4*)&GT[r][c] = *(const uint4*)(gg + (size_t)r * CL + c);
            }
            if (t < 64) {
                lrl[t] = lrp[(size_t)bn * CL + l0 + t];
                cuml[t] = cump[(size_t)bn * CL + l0 + t];
            }
        }
        __syncthreads();
        {
            const int mabsb = m0 + lm;
#pragma unroll
            for (int m16 = 0; m16 < 4; ++m16) {
                f32x4 s = (f32x4){0.f, 0.f, 0.f, 0.f};
#pragma unroll
                for (int ks = 0; ks < 2; ++ks) {
                    short8v a = *(const short8v*)&Kb[wv * 16 + lm][ks * 32 + lg * 8];
                    short8v b = *(const short8v*)&Qb[m16 * 16 + lm][ks * 32 + lg * 8];
                    s = MFMA16(a, b, s);
                }
                int mloc = m16 * 16 + lm;
                int mabs = mabsb + m16 * 16;
                float cm = cumm[mloc];
                unsigned short pv[4];
#pragma unroll
                for (int r = 0; r < 4; ++r) {
                    int lloc = wv * 16 + lg * 4 + r;
                    float val = (mabs >= l0 + lloc)
                                    ? s[r] * lrl[lloc] * __expf(cm - cuml[lloc])
                                    : 0.f;
                    pv[r] = f2bf(val);
                }
                *(uint2*)&Pm[mloc][wv * 16 + lg * 4] =
                    make_uint2((unsigned)pv[0] | ((unsigned)pv[1] << 16),
                               (unsigned)pv[2] | ((unsigned)pv[3] << 16));
            }
        }
        __syncthreads();
#pragma unroll
        for (int m16 = 0; m16 < 4; ++m16)
#pragma unroll
            for (int hh = 0; hh < 2; ++hh) {
                int h16 = wv * 2 + hh;
                f32x4 p = (f32x4){0.f, 0.f, 0.f, 0.f};
#pragma unroll
                for (int ks = 0; ks < 2; ++ks) {
                    short8v a = *(const short8v*)&Pm[m16 * 16 + lm][ks * 32 + lg * 8];
                    short8v b = *(const short8v*)&GT[h16 * 16 + lm][ks * 32 + lg * 8];
                    p = MFMA16(a, b, p);
                }
#pragma unroll
                for (int r = 0; r < 4; ++r) acc[m16][hh][r] -= p[r];
            }
    }
    __syncthreads();
    {
        unsigned short(*Ob)[136] = (unsigned short(*)[136])Wb;
#pragma unroll
        for (int m16 = 0; m16 < 4; ++m16)
#pragma unroll
            for (int hh = 0; hh < 2; ++hh) {
                int h = (wv * 2 + hh) * 16 + lm;
#pragma unroll
                for (int r = 0; r < 4; ++r) {
                    int mloc = m16 * 16 + lg * 4 + r;
                    float a = acc[m16][hh][r];
                    Ob[mloc][h] = f2bf(a * sigf(a));
                }
            }
        __syncthreads();
        unsigned short* og = x2q + ((size_t)bn * CL + m0) * CHDH;
        for (int i = t; i < 1024; i += 256) {
            int r = i >> 4, c = (i & 15) * 8;
            *(uint4*)(og + (size_t)r * CHDH + c) = *(const uint4*)&Ob[r][c];
        }
    }
}

// ---------------------------------------------------------------------------
// attn2 (MFMA bf16): Z2_[m,d] = wdc[m]*(W2 x2_[m])[d]
//          - sum_{l<=m} (x2[l].x2_[m])*lr[l]*exp(cum[m]-cum[l])*gz2[l,d]
// ---------------------------------------------------------------------------
__global__ __launch_bounds__(256) void attn2_mfma(
    const unsigned short* __restrict__ x2q, const unsigned short* __restrict__ x2bf,
    const unsigned short* __restrict__ gz2t, const float* __restrict__ W2,
    const float* __restrict__ lrp, const float* __restrict__ cump,
    const float* __restrict__ wdcp, float* __restrict__ z2s) {
    __shared__ __align__(16) unsigned short X2qb[64][136];  // x2_ [m][h]
    __shared__ __align__(16) unsigned short W2b[64][136];   // W2 [d][h]; reused out stage
    __shared__ __align__(16) unsigned short X2l[64][136];   // x2 [l][h]
    __shared__ __align__(16) unsigned short GT2[64][72];    // gz2^T [d][l]
    __shared__ __align__(16) unsigned short Pm[64][72];     // P [m][l]
    __shared__ float lrl[64], cuml[64], cumm[64], wdcm[64];
    const int bn = blockIdx.y, mt = blockIdx.x, m0 = mt << 6;
    const int t = threadIdx.x;
    const int wv = t >> 6, lane = t & 63;
    const int lm = lane & 15, lg = lane >> 4;
    {
        const uint4* qg = (const uint4*)(x2q + ((size_t)bn * CL + m0) * CHDH);
        for (int i = t; i < 1024; i += 256) {
            int r = i >> 4, c = (i & 15) * 8;
            *(uint4*)&X2qb[r][c] = qg[i];
        }
        const float4* wg = (const float4*)(W2 + (size_t)bn * CHD * CHDH);
        for (int i = t; i < 2048; i += 256) {
            int r = i >> 5, c = (i & 31) << 2;
            float4 v = wg[i];
            *(uint2*)&W2b[r][c] = make_uint2(pk2(v.x, v.y), pk2(v.z, v.w));
        }
        if (t < 64) {
            cumm[t] = cump[(size_t)bn * CL + m0 + t];
            wdcm[t] = wdcp[(size_t)bn * CL + m0 + t];
        }
    }
    __syncthreads();
    f32x4 acc[4];
#pragma unroll
    for (int i = 0; i < 4; ++i) acc[i] = (f32x4){0.f, 0.f, 0.f, 0.f};
#pragma unroll
    for (int m16 = 0; m16 < 4; ++m16)
#pragma unroll
        for (int ks = 0; ks < 4; ++ks) {
            short8v a = *(const short8v*)&X2qb[m16 * 16 + lm][ks * 32 + lg * 8];
            short8v b = *(const short8v*)&W2b[wv * 16 + lm][ks * 32 + lg * 8];
            acc[m16] = MFMA16(a, b, acc[m16]);
        }
#pragma unroll
    for (int m16 = 0; m16 < 4; ++m16)
#pragma unroll
        for (int r = 0; r < 4; ++r) acc[m16][r] *= wdcm[m16 * 16 + lg * 4 + r];
    for (int lt = 0; lt <= mt; ++lt) {
        const int l0 = lt << 6;
        __syncthreads();
        {
            const unsigned short* kg = x2bf + ((size_t)bn * CL + l0) * CHDH;
            for (int i = t; i < 1024; i += 256) {
                int r = i >> 4, c = (i & 15) * 8;
                *(uint4*)&X2l[r][c] = *(const uint4*)(kg + (size_t)r * CHDH + c);
            }
            const unsigned short* gg = gz2t + (size_t)bn * CHD * CL + l0;
            for (int i = t; i < 512; i += 256) {
                int r = i >> 3, c = (i & 7) * 8;
                *(uint4*)&GT2[r][c] = *(const uint4*)(gg + (size_t)r * CL + c);
            }
            if (t < 64) {
                lrl[t] = lrp[(size_t)bn * CL + l0 + t];
                cuml[t] = cump[(size_t)bn * CL + l0 + t];
            }
        }
        __syncthreads();
        {
            const int mabsb = m0 + lm;
#pragma unroll
            for (int m16 = 0; m16 < 4; ++m16) {
                f32x4 s = (f32x4){0.f, 0.f, 0.f, 0.f};
#pragma unroll
                for (int ks = 0; ks < 4; ++ks) {
                    short8v a = *(const short8v*)&X2l[wv * 16 + lm][ks * 32 + lg * 8];
                    short8v b = *(const short8v*)&X2qb[m16 * 16 + lm][ks * 32 + lg * 8];
                    s = MFMA16(a, b, s);
                }
                int mloc = m16 * 16 + lm;
                int mabs = mabsb + m16 * 16;
                float cm = cumm[mloc];
                unsigned short pv[4];
#pragma unroll
                for (int r = 0; r < 4; ++r) {
                    int lloc = wv * 16 + lg * 4 + r;
                    float val = (mabs >= l0 + lloc)
                                    ? s[r] * lrl[lloc] * __expf(cm - cuml[lloc])
                                    : 0.f;
                    pv[r] = f2bf(val);
                }
                *(uint2*)&Pm[mloc][wv * 16 + lg * 4] =
                    make_uint2((unsigned)pv[0] | ((unsigned)pv[1] << 16),
                               (unsigned)pv[2] | ((unsigned)pv[3] << 16));
            }
        }
        __syncthreads();
#pragma unroll
        for (int m16 = 0; m16 < 4; ++m16) {
            f32x4 p = (f32x4){0.f, 0.f, 0.f, 0.f};
#pragma unroll
            for (int ks = 0; ks < 2; ++ks) {
                short8v a = *(const short8v*)&Pm[m16 * 16 + lm][ks * 32 + lg * 8];
                short8v b = *(const short8v*)&GT2[wv * 16 + lm][ks * 32 + lg * 8];
                p = MFMA16(a, b, p);
            }
#pragma unroll
            for (int r = 0; r < 4; ++r) acc[m16][r] -= p[r];
        }
    }
    __syncthreads();
    {
        float(*Os)[68] = (float(*)[68])W2b;
#pragma unroll
        for (int m16 = 0; m16 < 4; ++m16)
#pragma unroll
            for (int r = 0; r < 4; ++r)
                Os[m16 * 16 + lg * 4 + r][wv * 16 + lm] = acc[m16][r];
        __syncthreads();
        float* zg = z2s + ((size_t)bn * CL + m0) * CHD;
        for (int i = t; i < 1024; i += 256) {
            int r = i >> 4, c = (i & 15) << 2;
            *(float4*)(zg + (size_t)r * CHD + c) = *(const float4*)&Os[r][c];
        }
    }
}

// ---------------------------------------------------------------------------
// W1_next[h,d] = wdc_last*W1[h,d] - sum_l lr[l]*exp(cum_last-cum[l])*gz1[l,h]*k[l,d]
// ---------------------------------------------------------------------------
__global__ __launch_bounds__(256) void w1next_kernel(
    const float* __restrict__ gz1, const float* __restrict__ kh,
    const float* __restrict__ W1, const float* __restrict__ lrp,
    const float* __restrict__ cump, float* __restrict__ outw) {
    __shared__ float Gs[64][65];
    __shared__ float Ks[64][65];
    __shared__ float coefs[64];
    const int bn = blockIdx.y;
    const int h0 = blockIdx.x << 6;
    const int t = threadIdx.x;
    const float cum_last = cump[(size_t)bn * CL + CL - 1];
    const float wdcl = __expf(cum_last);
    const int hi = t >> 4, di = t & 15;
    float acc[4][4] = {};
    for (int l0 = 0; l0 < CL; l0 += 64) {
        for (int i = t; i < 64 * 64 / 4; i += 256) {
            int row = (i << 2) >> 6, col = (i << 2) & 63;
            float4 g = *(const float4*)(gz1 + ((size_t)bn * CL + l0 + row) * CHDH + h0 + col);
            Gs[row][col] = g.x; Gs[row][col + 1] = g.y;
            Gs[row][col + 2] = g.z; Gs[row][col + 3] = g.w;
            float4 k = *(const float4*)(kh + ((size_t)bn * CL + l0 + row) * CHD + col);
            Ks[row][col] = k.x; Ks[row][col + 1] = k.y;
            Ks[row][col + 2] = k.z; Ks[row][col + 3] = k.w;
        }
        if (t < 64)
            coefs[t] = lrp[(size_t)bn * CL + l0 + t] *
                       __expf(cum_last - cump[(size_t)bn * CL + l0 + t]);
        __syncthreads();
        for (int l = 0; l < 64; ++l) {
            float c = coefs[l];
            float g4[4], k4[4];
#pragma unroll
            for (int i = 0; i < 4; ++i) g4[i] = Gs[l][hi * 4 + i] * c;
#pragma unroll
            for (int j = 0; j < 4; ++j) k4[j] = Ks[l][di * 4 + j];
#pragma unroll
            for (int i = 0; i < 4; ++i)
#pragma unroll
                for (int j = 0; j < 4; ++j) acc[i][j] += g4[i] * k4[j];
        }
        __syncthreads();
    }
    const float* w1g = W1 + (size_t)bn * CHDH * CHD;
#pragma unroll
    for (int i = 0; i < 4; ++i) {
        int h = h0 + hi * 4 + i;
        int d = di * 4;
        float4 o;
        o.x = wdcl * w1g[h * CHD + d + 0] - acc[i][0];
        o.y = wdcl * w1g[h * CHD + d + 1] - acc[i][1];
        o.z = wdcl * w1g[h * CHD + d + 2] - acc[i][2];
        o.w = wdcl * w1g[h * CHD + d + 3] - acc[i][3];
        *(float4*)(outw + (size_t)bn * CHDH * CHD + h * CHD + d) = o;
    }
}

// ---------------------------------------------------------------------------
// W2_next[d,h] = wdc_last*W2[d,h] - sum_l lr[l]*exp(cum_last-cum[l])*gz2[l,d]*x2[l,h]
// ---------------------------------------------------------------------------
__global__ __launch_bounds__(256) void w2next_kernel(
    const float* __restrict__ gz2, const float* __restrict__ x2,
    const float* __restrict__ W2, const float* __restrict__ lrp,
    const float* __restrict__ cump, float* __restrict__ outw) {
    __shared__ float Gs[64][65];
    __shared__ float Xs[64][65];
    __shared__ float coefs[64];
    const int bn = blockIdx.y;
    const int h0 = blockIdx.x << 6;
    const int t = threadIdx.x;
    const float cum_last = cump[(size_t)bn * CL + CL - 1];
    const float wdcl = __expf(cum_last);
    const int di = t >> 4, hi = t & 15;
    float acc[4][4] = {};
    for (int l0 = 0; l0 < CL; l0 += 64) {
        for (int i = t; i < 64 * 64 / 4; i += 256) {
            int row = (i << 2) >> 6, col = (i << 2) & 63;
            float4 g = *(const float4*)(gz2 + ((size_t)bn * CL + l0 + row) * CHD + col);
            Gs[row][col] = g.x; Gs[row][col + 1] = g.y;
            Gs[row][col + 2] = g.z; Gs[row][col + 3] = g.w;
            float4 xv = *(const float4*)(x2 + ((size_t)bn * CL + l0 + row) * CHDH + h0 + col);
            Xs[row][col] = xv.x; Xs[row][col + 1] = xv.y;
            Xs[row][col + 2] = xv.z; Xs[row][col + 3] = xv.w;
        }
        if (t < 64)
            coefs[t] = lrp[(size_t)bn * CL + l0 + t] *
                       __expf(cum_last - cump[(size_t)bn * CL + l0 + t]);
        __syncthreads();
        for (int l = 0; l < 64; ++l) {
            float c = coefs[l];
            float g4[4], x4[4];
#pragma unroll
            for (int i = 0; i < 4; ++i) g4[i] = Gs[l][di * 4 + i] * c;
#pragma unroll
            for (int j = 0; j < 4; ++j) x4[j] = Xs[l][hi * 4 + j];
#pragma unroll
            for (int i = 0; i < 4; ++i)
#pragma unroll
                for (int j = 0; j < 4; ++j) acc[i][j] += g4[i] * x4[j];
        }
        __syncthreads();
    }
    const float* w2g = W2 + (size_t)bn * CHD * CHDH;
#pragma unroll
    for (int i = 0; i < 4; ++i) {
        int d = di * 4 + i;
        int h = h0 + hi * 4;
        float4 o;
        o.x = wdcl * w2g[d * CHDH + h + 0] - acc[i][0];
        o.y = wdcl * w2g[d * CHDH + h + 1] - acc[i][1];
        o.z = wdcl * w2g[d * CHDH + h + 2] - acc[i][2];
        o.w = wdcl * w2g[d * CHDH + h + 3] - acc[i][3];
        *(float4*)(outw + (size_t)bn * CHD * CHDH + d * CHDH + h) = o;
    }
}

// ---------------------------------------------------------------------------
extern "C" void kernel_launch(void* const* d_in, const int* in_sizes, int n_in,
                              void* d_out, int out_size, void* d_ws, size_t ws_size,
                              hipStream_t stream) {
    (void)in_sizes; (void)n_in; (void)out_size; (void)ws_size;
    const float* x      = (const float*)d_in[0];
    const float* W1     = (const float*)d_in[1];
    const float* W2     = (const float*)d_in[2];
    const float* lblr   = (const float*)d_in[3];
    const float* fclr_w = (const float*)d_in[4];
    const float* fclr_b = (const float*)d_in[5];
    const float* lbwd   = (const float*)d_in[6];
    const float* fcwd_w = (const float*)d_in[7];
    const float* fcwd_b = (const float*)d_in[8];
    const float* qw = (const float*)d_in[9];
    const float* qb = (const float*)d_in[10];
    const float* kw = (const float*)d_in[11];
    const float* kb = (const float*)d_in[12];
    const float* vw = (const float*)d_in[13];
    const float* vb = (const float*)d_in[14];
    const float* ow = (const float*)d_in[15];
    const float* ob = (const float*)d_in[16];

    float* ws = (float*)d_ws;
    const size_t SZ_HD = (size_t)CBN * CL * CHD;    // 2,097,152
    const size_t SZ_HDH = (size_t)CBN * CL * CHDH;  // 4,194,304
    float* qh   = ws;            // dead fp32 slot; reused for q/k bf16
    float* khb  = qh + SZ_HD;
    float* vhb  = khb + SZ_HD;
    float* gz2b = vhb + SZ_HD;
    float* z2sb = gz2b + SZ_HD;  // gz1t bf16 overlays here until attn2 writes
    float* x2b  = z2sb + SZ_HD;
    float* gz1b = x2b + SZ_HDH;
    float* x2qb = gz1b + SZ_HDH; // half: x2q bf16; half: x2bf
    float* lrb  = x2qb + SZ_HDH;
    float* cumb = lrb + (size_t)CBN * CL;
    float* wdcb = cumb + (size_t)CBN * CL;
    unsigned short* xbf  = (unsigned short*)(wdcb + (size_t)CBN * CL);
    unsigned short* qwbf = xbf + (size_t)CB * CL * CD;
    unsigned short* kwbf = qwbf + (size_t)CD * CD;
    unsigned short* vwbf = kwbf + (size_t)CD * CD;
    unsigned short* gz2t = vwbf + (size_t)CD * CD;  // [bn][64][CL]
    unsigned short* qbf = (unsigned short*)qh;      // [bn][l][64]
    unsigned short* kbf = qbf + SZ_HD;
    unsigned short* x2q = (unsigned short*)x2qb;    // [bn][l][128]
    unsigned short* x2bf = x2q + SZ_HDH;
    unsigned short* gz1t = (unsigned short*)z2sb;   // [bn][128][CL]

    float* outp = (float*)d_out;
    float* w1n = outp + (size_t)CB * CL * CD;
    float* w2n = w1n + (size_t)CBN * CHDH * CHD;

    tobf_kernel<<<5120, 256, 0, stream>>>(x, qw, kw, vw, xbf, qwbf, kwbf, vwbf);
    dim3 gBig(CD / 64, (CB * CL) / 64);
    gemm_bf<0, 1><<<gBig, 256, 0, stream>>>(xbf, qwbf, qb, nullptr, qbf);
    gemm_bf<1, 1><<<gBig, 256, 0, stream>>>(xbf, kwbf, kb, khb, kbf);
    gemm_bf<1, 0><<<gBig, 256, 0, stream>>>(xbf, vwbf, vb, vhb, nullptr);
    lrwd_kernel<<<CB * CL, 64, 0, stream>>>(x, lblr, fclr_w, fclr_b, lbwd, fcwd_w,
                                            fcwd_b, lrb, cumb);
    scan_kernel<<<CBN, 64, 0, stream>>>(cumb, wdcb);
    mlp_kernel<<<dim3(CL / 32, CBN), 256, 0, stream>>>(khb, vhb, W1, W2, x2b, gz1b,
                                                       gz2b, x2bf, gz1t, gz2t);
    attn1_mfma<<<dim3(CL / 64, CBN), 256, 0, stream>>>(qbf, kbf, gz1t, W1, lrb, cumb,
                                                       wdcb, x2q);
    attn2_mfma<<<dim3(CL / 64, CBN), 256, 0, stream>>>(x2q, x2bf, gz2t, W2, lrb, cumb,
                                                       wdcb, z2sb);
    w1next_kernel<<<dim3(2, CBN), 256, 0, stream>>>(gz1b, khb, W1, lrb, cumb, w1n);
    w2next_kernel<<<dim3(2, CBN), 256, 0, stream>>>(gz2b, x2b, W2, lrb, cumb, w2n);
    gemm_big<<<gBig, 256, 0, stream>>>(z2sb, ow, ob, outp);
}

// Round 4
// 411.144 us; speedup vs baseline: 3.0169x; 1.2307x over previous
//
#include <hip/hip_runtime.h>

constexpr int CB = 2, CL = 1024, CD = 1024, CNH = 16, CHD = 64, CHDH = 128, CBN = CB * CNH;

__device__ __forceinline__ float sigf(float x) { return 1.0f / (1.0f + __expf(-x)); }

__device__ __forceinline__ unsigned short f2bf(float x) {
    unsigned u = __float_as_uint(x);
    u += 0x7fffu + ((u >> 16) & 1u);
    return (unsigned short)(u >> 16);
}
__device__ __forceinline__ unsigned pk2(float a, float b) {
    return (unsigned)f2bf(a) | ((unsigned)f2bf(b) << 16);
}
__device__ __forceinline__ unsigned pkus(unsigned short a, unsigned short b) {
    return (unsigned)a | ((unsigned)b << 16);
}
__device__ __forceinline__ float bf2f(unsigned short u) {
    return __uint_as_float(((unsigned)u) << 16);
}

typedef __attribute__((ext_vector_type(8))) short short8v;
typedef __attribute__((ext_vector_type(4))) float f32x4;
#define MFMA16(a, b, c) __builtin_amdgcn_mfma_f32_16x16x32_bf16(a, b, c, 0, 0, 0)

// ---------------------------------------------------------------------------
// Convert x, qw, kw, vw to bf16.
// ---------------------------------------------------------------------------
__global__ __launch_bounds__(256) void tobf_kernel(
    const float* __restrict__ x, const float* __restrict__ qw,
    const float* __restrict__ kw, const float* __restrict__ vw,
    unsigned short* __restrict__ xb, unsigned short* __restrict__ qwb,
    unsigned short* __restrict__ kwb, unsigned short* __restrict__ vwb) {
    int i = blockIdx.x * 256 + threadIdx.x;
    const float* s;
    unsigned short* d;
    int off;
    if (i < 524288) { s = x; d = xb; off = i; }
    else if (i < 786432) { s = qw; d = qwb; off = i - 524288; }
    else if (i < 1048576) { s = kw; d = kwb; off = i - 786432; }
    else { s = vw; d = vwb; off = i - 1048576; }
    float4 v = *(const float4*)(s + (size_t)off * 4);
    *(uint2*)(d + (size_t)off * 4) = make_uint2(pk2(v.x, v.y), pk2(v.z, v.w));
}

// ---------------------------------------------------------------------------
// Convert W1 -> w1bf, W2 -> w2bf, W2^T -> w2tbf (bf16).
// ---------------------------------------------------------------------------
__global__ __launch_bounds__(256) void tobf2_kernel(
    const float* __restrict__ W1, const float* __restrict__ W2,
    unsigned short* __restrict__ w1b, unsigned short* __restrict__ w2b,
    unsigned short* __restrict__ w2t) {
    int i = blockIdx.x * 256 + threadIdx.x;  // 0..196607
    if (i < 65536) {
        size_t e = (size_t)i * 4;
        float4 v = *(const float4*)(W1 + e);
        *(uint2*)(w1b + e) = make_uint2(pk2(v.x, v.y), pk2(v.z, v.w));
    } else if (i < 131072) {
        size_t e = (size_t)(i - 65536) * 4;
        float4 v = *(const float4*)(W2 + e);
        *(uint2*)(w2b + e) = make_uint2(pk2(v.x, v.y), pk2(v.z, v.w));
    } else {
        size_t e = (size_t)(i - 131072) * 4;
        int bn = (int)(e >> 13), rem = (int)(e & 8191);
        int h = rem >> 6, d0 = rem & 63;
        const float* src = W2 + (size_t)bn * CHD * CHDH;
        float a = src[(d0 + 0) * CHDH + h], b = src[(d0 + 1) * CHDH + h];
        float c = src[(d0 + 2) * CHDH + h], dd = src[(d0 + 3) * CHDH + h];
        *(uint2*)(w2t + e) = make_uint2(pk2(a, b), pk2(c, dd));
    }
}

// ---------------------------------------------------------------------------
// MFMA bf16 GEMM: 64x64 tile, K=1024. Out per-head [b][n][l][64].
// STOREF: fp32 out. BFOUT: bf16 out. KTOUT: bf16 transposed out [bn][d][L].
// ---------------------------------------------------------------------------
template <int STOREF, int BFOUT, int KTOUT>
__global__ __launch_bounds__(256) void gemm_bf(const unsigned short* __restrict__ A,
                                               const unsigned short* __restrict__ Bw,
                                               const float* __restrict__ bias,
                                               float* __restrict__ Cf,
                                               unsigned short* __restrict__ Cb,
                                               unsigned short* __restrict__ Ct) {
    __shared__ __align__(16) unsigned short As[64][72];
    __shared__ __align__(16) unsigned short Bs[64][72];
    __shared__ float Os[64][68];
    const int t = threadIdx.x;
    const int r0 = blockIdx.y << 6, c0 = blockIdx.x << 6;
    const int wv = t >> 6, lane = t & 63;
    const int lm = lane & 15, lg = lane >> 4;
    f32x4 acc[4];
#pragma unroll
    for (int i = 0; i < 4; ++i) acc[i] = (f32x4){0.f, 0.f, 0.f, 0.f};
    for (int kc = 0; kc < CD; kc += 64) {
        for (int i = t; i < 512; i += 256) {
            int r = i >> 3, c = (i & 7) * 8;
            *(uint4*)&As[r][c] = *(const uint4*)(A + (size_t)(r0 + r) * CD + kc + c);
            *(uint4*)&Bs[r][c] = *(const uint4*)(Bw + (size_t)(c0 + r) * CD + kc + c);
        }
        __syncthreads();
#pragma unroll
        for (int n16 = 0; n16 < 4; ++n16)
#pragma unroll
            for (int ks = 0; ks < 2; ++ks) {
                short8v a = *(const short8v*)&As[wv * 16 + lm][ks * 32 + lg * 8];
                short8v b = *(const short8v*)&Bs[n16 * 16 + lm][ks * 32 + lg * 8];
                acc[n16] = MFMA16(a, b, acc[n16]);
            }
        __syncthreads();
    }
#pragma unroll
    for (int n16 = 0; n16 < 4; ++n16) {
        float bb = bias[c0 + n16 * 16 + lm];
#pragma unroll
        for (int r = 0; r < 4; ++r)
            Os[wv * 16 + lg * 4 + r][n16 * 16 + lm] = acc[n16][r] + bb;
    }
    __syncthreads();
    const int nh = c0 >> 6;
    const int b = r0 >> 10, lb0 = r0 & 1023;
    for (int i = t; i < 1024; i += 256) {
        int r = i >> 4, c = (i & 15) * 4;
        float4 v = *(const float4*)&Os[r][c];
        size_t base = (((size_t)b * CNH + nh) * CL + lb0 + r) * 64 + c;
        if (STOREF) *(float4*)(Cf + base) = v;
        if (BFOUT) *(uint2*)(Cb + base) = make_uint2(pk2(v.x, v.y), pk2(v.z, v.w));
    }
    if (KTOUT) {
        for (int i = t; i < 512; i += 256) {
            int d = i >> 3, lb = (i & 7) * 8;
            uint4 u;
            u.x = pk2(Os[lb + 0][d], Os[lb + 1][d]);
            u.y = pk2(Os[lb + 2][d], Os[lb + 3][d]);
            u.z = pk2(Os[lb + 4][d], Os[lb + 5][d]);
            u.w = pk2(Os[lb + 6][d], Os[lb + 7][d]);
            *(uint4*)(Ct + (((size_t)b * CNH + nh) * 64 + d) * CL + lb0 + lb) = u;
        }
    }
}

// ---------------------------------------------------------------------------
// Big fp32 GEMM (o-projection): A gathered from per-head z2s.
// ---------------------------------------------------------------------------
__global__ __launch_bounds__(256) void gemm_big(const float* __restrict__ A,
                                                const float* __restrict__ Bw,
                                                const float* __restrict__ bias,
                                                float* __restrict__ C) {
    __shared__ float As[16][68];
    __shared__ float Bs[16][68];
    const int t = threadIdx.x;
    const int r0 = blockIdx.y << 6;
    const int c0 = blockIdx.x << 6;
    const int lrow = t >> 2;
    const int lk4 = (t & 3) << 2;
    const int tr = t >> 4, tc = t & 15;
    float acc[4][4] = {};
    for (int kc = 0; kc < CD; kc += 16) {
        const int ar = r0 + lrow;
        const int ak = kc + lk4;
        int b = ar >> 10, l = ar & 1023;
        int n = ak >> 6, d = ak & 63;
        float4 av = *(const float4*)(A + ((((size_t)b * CNH + n) * CL + l) << 6) + d);
        float4 bv = *(const float4*)(Bw + (size_t)(c0 + lrow) * CD + ak);
        As[lk4 + 0][lrow] = av.x; As[lk4 + 1][lrow] = av.y;
        As[lk4 + 2][lrow] = av.z; As[lk4 + 3][lrow] = av.w;
        Bs[lk4 + 0][lrow] = bv.x; Bs[lk4 + 1][lrow] = bv.y;
        Bs[lk4 + 2][lrow] = bv.z; Bs[lk4 + 3][lrow] = bv.w;
        __syncthreads();
#pragma unroll
        for (int kk = 0; kk < 16; ++kk) {
            float4 a4 = *(const float4*)(&As[kk][tr << 2]);
            float4 b4 = *(const float4*)(&Bs[kk][tc << 2]);
            float a[4] = {a4.x, a4.y, a4.z, a4.w};
            float b[4] = {b4.x, b4.y, b4.z, b4.w};
#pragma unroll
            for (int i = 0; i < 4; ++i)
#pragma unroll
                for (int j = 0; j < 4; ++j) acc[i][j] += a[i] * b[j];
        }
        __syncthreads();
    }
#pragma unroll
    for (int i = 0; i < 4; ++i) {
        const int r = r0 + tr * 4 + i;
        const int c = c0 + tc * 4;
        float4 o;
        o.x = acc[i][0] + bias[c + 0];
        o.y = acc[i][1] + bias[c + 1];
        o.z = acc[i][2] + bias[c + 2];
        o.w = acc[i][3] + bias[c + 3];
        *(float4*)(C + (size_t)r * CD + c) = o;
    }
}

// ---------------------------------------------------------------------------
// lr / log_wd projections.
// ---------------------------------------------------------------------------
__global__ __launch_bounds__(64) void lrwd_kernel(
    const float* __restrict__ x, const float* __restrict__ lblr,
    const float* __restrict__ fclr_w, const float* __restrict__ fclr_b,
    const float* __restrict__ lbwd, const float* __restrict__ fcwd_w,
    const float* __restrict__ fcwd_b, float* __restrict__ lrp,
    float* __restrict__ logwd) {
    const int r = blockIdx.x;
    const int b = r >> 10, l = r & 1023;
    const int lane = threadIdx.x;
    float xv[16];
#pragma unroll
    for (int j = 0; j < 16; ++j) xv[j] = x[(size_t)r * CD + lane + 64 * j];
    for (int n = 0; n < CNH; ++n) {
        float d1 = 0.f, d2 = 0.f;
#pragma unroll
        for (int j = 0; j < 16; ++j) {
            d1 += xv[j] * fclr_w[(size_t)n * CD + lane + 64 * j];
            d2 += xv[j] * fcwd_w[(size_t)n * CD + lane + 64 * j];
        }
#pragma unroll
        for (int s = 32; s > 0; s >>= 1) {
            d1 += __shfl_down(d1, s);
            d2 += __shfl_down(d2, s);
        }
        if (lane == 0) {
            lrp[((size_t)b * CNH + n) * CL + l] = __expf(lblr[n]) * sigf(d1 + fclr_b[n]);
            logwd[((size_t)b * CNH + n) * CL + l] =
                log1pf(-__expf(lbwd[n]) * sigf(d2 + fcwd_b[n]));
        }
    }
}

// ---------------------------------------------------------------------------
// Inclusive prefix sum of log_wd -> cum, plus wdc = exp(cum).
// ---------------------------------------------------------------------------
__global__ __launch_bounds__(64) void scan_kernel(float* __restrict__ cum,
                                                  float* __restrict__ wdc) {
    const int bn = blockIdx.x;
    const int lane = threadIdx.x;
    float* p = cum + (size_t)bn * CL;
    float v[16];
#pragma unroll
    for (int j = 0; j < 16; ++j) v[j] = p[lane * 16 + j];
#pragma unroll
    for (int j = 1; j < 16; ++j) v[j] += v[j - 1];
    float tot = v[15];
    float inc = tot;
#pragma unroll
    for (int s = 1; s < 64; s <<= 1) {
        float tv = __shfl_up(inc, s);
        if (lane >= s) inc += tv;
    }
    const float pre = inc - tot;
#pragma unroll
    for (int j = 0; j < 16; ++j) {
        float c = pre + v[j];
        p[lane * 16 + j] = c;
        wdc[(size_t)bn * CL + lane * 16 + j] = __expf(c);
    }
}

// ---------------------------------------------------------------------------
// MFMA MLP fwd/bwd over 64 tokens. Three chained MFMA stages with LDS reuse:
//   RA: W1b -> W2t ; RB: Kb -> GZ2s ; RC: W2b -> GZ1s ; X2s persistent.
// Emits x2bf (rows), x2t/gz1t/gz2t (transposed bf16).
// ---------------------------------------------------------------------------
__global__ __launch_bounds__(256) void mlp_mfma(
    const unsigned short* __restrict__ kbf, const float* __restrict__ vh,
    const unsigned short* __restrict__ w1bf, const unsigned short* __restrict__ w2bf,
    const unsigned short* __restrict__ w2tbf, unsigned short* __restrict__ x2bf,
    unsigned short* __restrict__ x2t, unsigned short* __restrict__ gz1t,
    unsigned short* __restrict__ gz2t) {
    __shared__ __align__(16) unsigned short RA[128][72];
    __shared__ __align__(16) unsigned short RB[64][72];
    __shared__ __align__(16) unsigned short RC[64][136];
    __shared__ __align__(16) unsigned short X2s[64][136];
    const int bn = blockIdx.y, l0 = blockIdx.x << 6;
    const int t = threadIdx.x;
    const int wv = t >> 6, lane = t & 63;
    const int lm = lane & 15, lg = lane >> 4;
    {
        const unsigned short* kg = kbf + ((size_t)bn * CL + l0) * CHD;
        for (int i = t; i < 512; i += 256) {
            int r = i >> 3, c = (i & 7) * 8;
            *(uint4*)&RB[r][c] = *(const uint4*)(kg + (size_t)r * CHD + c);
        }
        const unsigned short* w1g = w1bf + (size_t)bn * CHDH * CHD;
        for (int i = t; i < 1024; i += 256) {
            int r = i >> 3, c = (i & 7) * 8;
            *(uint4*)&RA[r][c] = *(const uint4*)(w1g + (size_t)r * CHD + c);
        }
        const unsigned short* w2g = w2bf + (size_t)bn * CHD * CHDH;
        for (int i = t; i < 1024; i += 256) {
            int r = i >> 4, c = (i & 15) * 8;
            *(uint4*)&RC[r][c] = *(const uint4*)(w2g + (size_t)r * CHDH + c);
        }
    }
    __syncthreads();
    // MFMA1: Z1[l][h]
    f32x4 acc1[4][2];
#pragma unroll
    for (int i = 0; i < 4; ++i)
#pragma unroll
        for (int j = 0; j < 2; ++j) acc1[i][j] = (f32x4){0.f, 0.f, 0.f, 0.f};
#pragma unroll
    for (int m16 = 0; m16 < 4; ++m16)
#pragma unroll
        for (int hh = 0; hh < 2; ++hh) {
            int h16 = wv * 2 + hh;
#pragma unroll
            for (int ks = 0; ks < 2; ++ks) {
                short8v a = *(const short8v*)&RB[m16 * 16 + lm][ks * 32 + lg * 8];
                short8v b = *(const short8v*)&RA[h16 * 16 + lm][ks * 32 + lg * 8];
                acc1[m16][hh] = MFMA16(a, b, acc1[m16][hh]);
            }
        }
#pragma unroll
    for (int m16 = 0; m16 < 4; ++m16)
#pragma unroll
        for (int hh = 0; hh < 2; ++hh)
#pragma unroll
            for (int r = 0; r < 4; ++r) {
                float a = acc1[m16][hh][r];
                X2s[m16 * 16 + lg * 4 + r][(wv * 2 + hh) * 16 + lm] = f2bf(a * sigf(a));
            }
    __syncthreads();  // X2s ready; RA/RB free
    {
        const unsigned short* w2tg = w2tbf + (size_t)bn * CHDH * CHD;
        for (int i = t; i < 1024; i += 256) {
            int r = i >> 3, c = (i & 7) * 8;
            *(uint4*)&RA[r][c] = *(const uint4*)(w2tg + (size_t)r * CHD + c);
        }
    }
    // MFMA2: Z2[l][d], d16 = wv
    {
        f32x4 acc2[4];
#pragma unroll
        for (int i = 0; i < 4; ++i) acc2[i] = (f32x4){0.f, 0.f, 0.f, 0.f};
#pragma unroll
        for (int m16 = 0; m16 < 4; ++m16)
#pragma unroll
            for (int ks = 0; ks < 4; ++ks) {
                short8v a = *(const short8v*)&X2s[m16 * 16 + lm][ks * 32 + lg * 8];
                short8v b = *(const short8v*)&RC[wv * 16 + lm][ks * 32 + lg * 8];
                acc2[m16] = MFMA16(a, b, acc2[m16]);
            }
#pragma unroll
        for (int m16 = 0; m16 < 4; ++m16)
#pragma unroll
            for (int r = 0; r < 4; ++r) {
                int l = l0 + m16 * 16 + lg * 4 + r;
                float v = vh[((size_t)bn * CL + l) * 64 + wv * 16 + lm];
                RB[m16 * 16 + lg * 4 + r][wv * 16 + lm] = f2bf(acc2[m16][r] - v);
            }
    }
    __syncthreads();  // GZ2s + W2t ready
    // MFMA3: gX2[l][h]; gz1 = silu'(Z1) * gX2
#pragma unroll
    for (int m16 = 0; m16 < 4; ++m16)
#pragma unroll
        for (int hh = 0; hh < 2; ++hh) {
            int h16 = wv * 2 + hh;
            f32x4 p = (f32x4){0.f, 0.f, 0.f, 0.f};
#pragma unroll
            for (int ks = 0; ks < 2; ++ks) {
                short8v a = *(const short8v*)&RB[m16 * 16 + lm][ks * 32 + lg * 8];
                short8v b = *(const short8v*)&RA[h16 * 16 + lm][ks * 32 + lg * 8];
                p = MFMA16(a, b, p);
            }
#pragma unroll
            for (int r = 0; r < 4; ++r) {
                float zz = acc1[m16][hh][r];
                float s = sigf(zz);
                float sil = zz * s;
                RC[m16 * 16 + lg * 4 + r][h16 * 16 + lm] =
                    f2bf((sil + s * (1.f - sil)) * p[r]);
            }
        }
    __syncthreads();
    // epilogue global writes
    for (int i = t; i < 1024; i += 256) {  // x2bf rows
        int r = i >> 4, c = (i & 15) * 8;
        *(uint4*)(x2bf + ((size_t)bn * CL + l0 + r) * CHDH + c) = *(const uint4*)&X2s[r][c];
    }
    for (int i = t; i < 1024; i += 256) {  // x2t [bn][128][CL]
        int h = i >> 3, lb = (i & 7) * 8;
        uint4 u;
        u.x = pkus(X2s[lb + 0][h], X2s[lb + 1][h]);
        u.y = pkus(X2s[lb + 2][h], X2s[lb + 3][h]);
        u.z = pkus(X2s[lb + 4][h], X2s[lb + 5][h]);
        u.w = pkus(X2s[lb + 6][h], X2s[lb + 7][h]);
        *(uint4*)(x2t + ((size_t)bn * CHDH + h) * CL + l0 + lb) = u;
    }
    for (int i = t; i < 1024; i += 256) {  // gz1t [bn][128][CL]
        int h = i >> 3, lb = (i & 7) * 8;
        uint4 u;
        u.x = pkus(RC[lb + 0][h], RC[lb + 1][h]);
        u.y = pkus(RC[lb + 2][h], RC[lb + 3][h]);
        u.z = pkus(RC[lb + 4][h], RC[lb + 5][h]);
        u.w = pkus(RC[lb + 6][h], RC[lb + 7][h]);
        *(uint4*)(gz1t + ((size_t)bn * CHDH + h) * CL + l0 + lb) = u;
    }
    for (int i = t; i < 512; i += 256) {  // gz2t [bn][64][CL]
        int d = i >> 3, lb = (i & 7) * 8;
        uint4 u;
        u.x = pkus(RB[lb + 0][d], RB[lb + 1][d]);
        u.y = pkus(RB[lb + 2][d], RB[lb + 3][d]);
        u.z = pkus(RB[lb + 4][d], RB[lb + 5][d]);
        u.w = pkus(RB[lb + 6][d], RB[lb + 7][d]);
        *(uint4*)(gz2t + ((size_t)bn * CHD + d) * CL + l0 + lb) = u;
    }
}

// ---------------------------------------------------------------------------
// attn1 (MFMA bf16).
// ---------------------------------------------------------------------------
__global__ __launch_bounds__(256) void attn1_mfma(
    const unsigned short* __restrict__ qbf, const unsigned short* __restrict__ kbf,
    const unsigned short* __restrict__ gz1t, const unsigned short* __restrict__ w1bf,
    const float* __restrict__ lrp, const float* __restrict__ cump,
    const float* __restrict__ wdcp, unsigned short* __restrict__ x2q) {
    __shared__ __align__(16) unsigned short Qb[64][72];
    __shared__ __align__(16) unsigned short Wb[128][72];
    __shared__ __align__(16) unsigned short Kb[64][72];
    __shared__ __align__(16) unsigned short GT[128][72];
    __shared__ __align__(16) unsigned short Pm[64][72];
    __shared__ float lrl[64], cuml[64], cumm[64], wdcm[64];
    const int bn = blockIdx.y, mt = blockIdx.x, m0 = mt << 6;
    const int t = threadIdx.x;
    const int wv = t >> 6, lane = t & 63;
    const int lm = lane & 15, lg = lane >> 4;
    {
        const unsigned short* qg = qbf + ((size_t)bn * CL + m0) * CHD;
        for (int i = t; i < 512; i += 256) {
            int r = i >> 3, c = (i & 7) * 8;
            *(uint4*)&Qb[r][c] = *(const uint4*)(qg + (size_t)r * CHD + c);
        }
        const unsigned short* wg = w1bf + (size_t)bn * CHDH * CHD;
        for (int i = t; i < 1024; i += 256) {
            int r = i >> 3, c = (i & 7) * 8;
            *(uint4*)&Wb[r][c] = *(const uint4*)(wg + (size_t)r * CHD + c);
        }
        if (t < 64) {
            cumm[t] = cump[(size_t)bn * CL + m0 + t];
            wdcm[t] = wdcp[(size_t)bn * CL + m0 + t];
        }
    }
    __syncthreads();
    f32x4 acc[4][2];
#pragma unroll
    for (int i = 0; i < 4; ++i)
#pragma unroll
        for (int j = 0; j < 2; ++j) acc[i][j] = (f32x4){0.f, 0.f, 0.f, 0.f};
#pragma unroll
    for (int m16 = 0; m16 < 4; ++m16)
#pragma unroll
        for (int hh = 0; hh < 2; ++hh) {
            int h16 = wv * 2 + hh;
#pragma unroll
            for (int ks = 0; ks < 2; ++ks) {
                short8v a = *(const short8v*)&Qb[m16 * 16 + lm][ks * 32 + lg * 8];
                short8v b = *(const short8v*)&Wb[h16 * 16 + lm][ks * 32 + lg * 8];
                acc[m16][hh] = MFMA16(a, b, acc[m16][hh]);
            }
        }
#pragma unroll
    for (int m16 = 0; m16 < 4; ++m16) {
#pragma unroll
        for (int r = 0; r < 4; ++r) {
            float w = wdcm[m16 * 16 + lg * 4 + r];
            acc[m16][0][r] *= w;
            acc[m16][1][r] *= w;
        }
    }
    for (int lt = 0; lt <= mt; ++lt) {
        const int l0 = lt << 6;
        __syncthreads();
        {
            const unsigned short* kg = kbf + ((size_t)bn * CL + l0) * CHD;
            for (int i = t; i < 512; i += 256) {
                int r = i >> 3, c = (i & 7) * 8;
                *(uint4*)&Kb[r][c] = *(const uint4*)(kg + (size_t)r * CHD + c);
            }
            const unsigned short* gg = gz1t + (size_t)bn * CHDH * CL + l0;
            for (int i = t; i < 1024; i += 256) {
                int r = i >> 3, c = (i & 7) * 8;
                *(uint4*)&GT[r][c] = *(const uint4*)(gg + (size_t)r * CL + c);
            }
            if (t < 64) {
                lrl[t] = lrp[(size_t)bn * CL + l0 + t];
                cuml[t] = cump[(size_t)bn * CL + l0 + t];
            }
        }
        __syncthreads();
        {
            const int mabsb = m0 + lm;
#pragma unroll
            for (int m16 = 0; m16 < 4; ++m16) {
                f32x4 s = (f32x4){0.f, 0.f, 0.f, 0.f};
#pragma unroll
                for (int ks = 0; ks < 2; ++ks) {
                    short8v a = *(const short8v*)&Kb[wv * 16 + lm][ks * 32 + lg * 8];
                    short8v b = *(const short8v*)&Qb[m16 * 16 + lm][ks * 32 + lg * 8];
                    s = MFMA16(a, b, s);
                }
                int mloc = m16 * 16 + lm;
                int mabs = mabsb + m16 * 16;
                float cm = cumm[mloc];
                unsigned short pv[4];
#pragma unroll
                for (int r = 0; r < 4; ++r) {
                    int lloc = wv * 16 + lg * 4 + r;
                    float val = (mabs >= l0 + lloc)
                                    ? s[r] * lrl[lloc] * __expf(cm - cuml[lloc])
                                    : 0.f;
                    pv[r] = f2bf(val);
                }
                *(uint2*)&Pm[mloc][wv * 16 + lg * 4] =
                    make_uint2(pkus(pv[0], pv[1]), pkus(pv[2], pv[3]));
            }
        }
        __syncthreads();
#pragma unroll
        for (int m16 = 0; m16 < 4; ++m16)
#pragma unroll
            for (int hh = 0; hh < 2; ++hh) {
                int h16 = wv * 2 + hh;
                f32x4 p = (f32x4){0.f, 0.f, 0.f, 0.f};
#pragma unroll
                for (int ks = 0; ks < 2; ++ks) {
                    short8v a = *(const short8v*)&Pm[m16 * 16 + lm][ks * 32 + lg * 8];
                    short8v b = *(const short8v*)&GT[h16 * 16 + lm][ks * 32 + lg * 8];
                    p = MFMA16(a, b, p);
                }
#pragma unroll
                for (int r = 0; r < 4; ++r) acc[m16][hh][r] -= p[r];
            }
    }
    __syncthreads();
    {
        unsigned short(*Ob)[136] = (unsigned short(*)[136])Wb;
#pragma unroll
        for (int m16 = 0; m16 < 4; ++m16)
#pragma unroll
            for (int hh = 0; hh < 2; ++hh) {
                int h = (wv * 2 + hh) * 16 + lm;
#pragma unroll
                for (int r = 0; r < 4; ++r) {
                    int mloc = m16 * 16 + lg * 4 + r;
                    float a = acc[m16][hh][r];
                    Ob[mloc][h] = f2bf(a * sigf(a));
                }
            }
        __syncthreads();
        unsigned short* og = x2q + ((size_t)bn * CL + m0) * CHDH;
        for (int i = t; i < 1024; i += 256) {
            int r = i >> 4, c = (i & 15) * 8;
            *(uint4*)(og + (size_t)r * CHDH + c) = *(const uint4*)&Ob[r][c];
        }
    }
}

// ---------------------------------------------------------------------------
// attn2 (MFMA bf16).
// ---------------------------------------------------------------------------
__global__ __launch_bounds__(256) void attn2_mfma(
    const unsigned short* __restrict__ x2q, const unsigned short* __restrict__ x2bf,
    const unsigned short* __restrict__ gz2t, const unsigned short* __restrict__ w2bf,
    const float* __restrict__ lrp, const float* __restrict__ cump,
    const float* __restrict__ wdcp, float* __restrict__ z2s) {
    __shared__ __align__(16) unsigned short X2qb[64][136];
    __shared__ __align__(16) unsigned short W2b[64][136];
    __shared__ __align__(16) unsigned short X2l[64][136];
    __shared__ __align__(16) unsigned short GT2[64][72];
    __shared__ __align__(16) unsigned short Pm[64][72];
    __shared__ float lrl[64], cuml[64], cumm[64], wdcm[64];
    const int bn = blockIdx.y, mt = blockIdx.x, m0 = mt << 6;
    const int t = threadIdx.x;
    const int wv = t >> 6, lane = t & 63;
    const int lm = lane & 15, lg = lane >> 4;
    {
        const uint4* qg = (const uint4*)(x2q + ((size_t)bn * CL + m0) * CHDH);
        for (int i = t; i < 1024; i += 256) {
            int r = i >> 4, c = (i & 15) * 8;
            *(uint4*)&X2qb[r][c] = qg[i];
        }
        const unsigned short* wg = w2bf + (size_t)bn * CHD * CHDH;
        for (int i = t; i < 1024; i += 256) {
            int r = i >> 4, c = (i & 15) * 8;
            *(uint4*)&W2b[r][c] = *(const uint4*)(wg + (size_t)r * CHDH + c);
        }
        if (t < 64) {
            cumm[t] = cump[(size_t)bn * CL + m0 + t];
            wdcm[t] = wdcp[(size_t)bn * CL + m0 + t];
        }
    }
    __syncthreads();
    f32x4 acc[4];
#pragma unroll
    for (int i = 0; i < 4; ++i) acc[i] = (f32x4){0.f, 0.f, 0.f, 0.f};
#pragma unroll
    for (int m16 = 0; m16 < 4; ++m16)
#pragma unroll
        for (int ks = 0; ks < 4; ++ks) {
            short8v a = *(const short8v*)&X2qb[m16 * 16 + lm][ks * 32 + lg * 8];
            short8v b = *(const short8v*)&W2b[wv * 16 + lm][ks * 32 + lg * 8];
            acc[m16] = MFMA16(a, b, acc[m16]);
        }
#pragma unroll
    for (int m16 = 0; m16 < 4; ++m16)
#pragma unroll
        for (int r = 0; r < 4; ++r) acc[m16][r] *= wdcm[m16 * 16 + lg * 4 + r];
    for (int lt = 0; lt <= mt; ++lt) {
        const int l0 = lt << 6;
        __syncthreads();
        {
            const unsigned short* kg = x2bf + ((size_t)bn * CL + l0) * CHDH;
            for (int i = t; i < 1024; i += 256) {
                int r = i >> 4, c = (i & 15) * 8;
                *(uint4*)&X2l[r][c] = *(const uint4*)(kg + (size_t)r * CHDH + c);
            }
            const unsigned short* gg = gz2t + (size_t)bn * CHD * CL + l0;
            for (int i = t; i < 512; i += 256) {
                int r = i >> 3, c = (i & 7) * 8;
                *(uint4*)&GT2[r][c] = *(const uint4*)(gg + (size_t)r * CL + c);
            }
            if (t < 64) {
                lrl[t] = lrp[(size_t)bn * CL + l0 + t];
                cuml[t] = cump[(size_t)bn * CL + l0 + t];
            }
        }
        __syncthreads();
        {
            const int mabsb = m0 + lm;
#pragma unroll
            for (int m16 = 0; m16 < 4; ++m16) {
                f32x4 s = (f32x4){0.f, 0.f, 0.f, 0.f};
#pragma unroll
                for (int ks = 0; ks < 4; ++ks) {
                    short8v a = *(const short8v*)&X2l[wv * 16 + lm][ks * 32 + lg * 8];
                    short8v b = *(const short8v*)&X2qb[m16 * 16 + lm][ks * 32 + lg * 8];
                    s = MFMA16(a, b, s);
                }
                int mloc = m16 * 16 + lm;
                int mabs = mabsb + m16 * 16;
                float cm = cumm[mloc];
                unsigned short pv[4];
#pragma unroll
                for (int r = 0; r < 4; ++r) {
                    int lloc = wv * 16 + lg * 4 + r;
                    float val = (mabs >= l0 + lloc)
                                    ? s[r] * lrl[lloc] * __expf(cm - cuml[lloc])
                                    : 0.f;
                    pv[r] = f2bf(val);
                }
                *(uint2*)&Pm[mloc][wv * 16 + lg * 4] =
                    make_uint2(pkus(pv[0], pv[1]), pkus(pv[2], pv[3]));
            }
        }
        __syncthreads();
#pragma unroll
        for (int m16 = 0; m16 < 4; ++m16) {
            f32x4 p = (f32x4){0.f, 0.f, 0.f, 0.f};
#pragma unroll
            for (int ks = 0; ks < 2; ++ks) {
                short8v a = *(const short8v*)&Pm[m16 * 16 + lm][ks * 32 + lg * 8];
                short8v b = *(const short8v*)&GT2[wv * 16 + lm][ks * 32 + lg * 8];
                p = MFMA16(a, b, p);
            }
#pragma unroll
            for (int r = 0; r < 4; ++r) acc[m16][r] -= p[r];
        }
    }
    __syncthreads();
    {
        float(*Os)[68] = (float(*)[68])W2b;
#pragma unroll
        for (int m16 = 0; m16 < 4; ++m16)
#pragma unroll
            for (int r = 0; r < 4; ++r)
                Os[m16 * 16 + lg * 4 + r][wv * 16 + lm] = acc[m16][r];
        __syncthreads();
        float* zg = z2s + ((size_t)bn * CL + m0) * CHD;
        for (int i = t; i < 1024; i += 256) {
            int r = i >> 4, c = (i & 15) << 2;
            *(float4*)(zg + (size_t)r * CHD + c) = *(const float4*)&Os[r][c];
        }
    }
}

// ---------------------------------------------------------------------------
// W1_next via MFMA: out[h][d] = wdcl*W1[h][d] - sum_l coef[l]*gz1[l,h]*k[l,d]
// A = gz1t * coef (rows h), B = ktbf (rows d). One block per bn.
// ---------------------------------------------------------------------------
__global__ __launch_bounds__(256) void w1n_mfma(
    const unsigned short* __restrict__ gz1t, const unsigned short* __restrict__ ktbf,
    const float* __restrict__ W1, const float* __restrict__ lrp,
    const float* __restrict__ cump, float* __restrict__ outw) {
    __shared__ __align__(16) unsigned short Ab[128][72];
    __shared__ __align__(16) unsigned short Bb[64][72];
    __shared__ float coefA[1024];
    const int bn = blockIdx.x, t = threadIdx.x;
    const int wv = t >> 6, lane = t & 63;
    const int lm = lane & 15, lg = lane >> 4;
    const float cum_last = cump[(size_t)bn * CL + CL - 1];
    const float wdcl = __expf(cum_last);
    for (int i = t; i < 1024; i += 256)
        coefA[i] = lrp[(size_t)bn * CL + i] * __expf(cum_last - cump[(size_t)bn * CL + i]);
    f32x4 acc[2][4];
#pragma unroll
    for (int i = 0; i < 2; ++i)
#pragma unroll
        for (int j = 0; j < 4; ++j) acc[i][j] = (f32x4){0.f, 0.f, 0.f, 0.f};
    for (int lc = 0; lc < CL; lc += 64) {
        __syncthreads();
        for (int i = t; i < 1024; i += 256) {
            int h = i >> 3, cc = (i & 7) * 8;
            uint4 g = *(const uint4*)(gz1t + ((size_t)bn * CHDH + h) * CL + lc + cc);
            unsigned short* gp = (unsigned short*)&g;
            uint4 o;
            o.x = pk2(bf2f(gp[0]) * coefA[lc + cc + 0], bf2f(gp[1]) * coefA[lc + cc + 1]);
            o.y = pk2(bf2f(gp[2]) * coefA[lc + cc + 2], bf2f(gp[3]) * coefA[lc + cc + 3]);
            o.z = pk2(bf2f(gp[4]) * coefA[lc + cc + 4], bf2f(gp[5]) * coefA[lc + cc + 5]);
            o.w = pk2(bf2f(gp[6]) * coefA[lc + cc + 6], bf2f(gp[7]) * coefA[lc + cc + 7]);
            *(uint4*)&Ab[h][cc] = o;
        }
        for (int i = t; i < 512; i += 256) {
            int d = i >> 3, cc = (i & 7) * 8;
            *(uint4*)&Bb[d][cc] = *(const uint4*)(ktbf + ((size_t)bn * CHD + d) * CL + lc + cc);
        }
        __syncthreads();
#pragma unroll
        for (int mm = 0; mm < 2; ++mm) {
            int m16 = wv * 2 + mm;
#pragma unroll
            for (int n16 = 0; n16 < 4; ++n16)
#pragma unroll
                for (int ks = 0; ks < 2; ++ks) {
                    short8v a = *(const short8v*)&Ab[m16 * 16 + lm][ks * 32 + lg * 8];
                    short8v b = *(const short8v*)&Bb[n16 * 16 + lm][ks * 32 + lg * 8];
                    acc[mm][n16] = MFMA16(a, b, acc[mm][n16]);
                }
        }
    }
    const float* w1g = W1 + (size_t)bn * CHDH * CHD;
    float* og = outw + (size_t)bn * CHDH * CHD;
#pragma unroll
    for (int mm = 0; mm < 2; ++mm)
#pragma unroll
        for (int n16 = 0; n16 < 4; ++n16)
#pragma unroll
            for (int r = 0; r < 4; ++r) {
                int h = (wv * 2 + mm) * 16 + lg * 4 + r;
                int d = n16 * 16 + lm;
                og[h * CHD + d] = wdcl * w1g[h * CHD + d] - acc[mm][n16][r];
            }
}

// ---------------------------------------------------------------------------
// W2_next via MFMA: out[d][h] = wdcl*W2[d][h] - sum_l coef[l]*gz2[l,d]*x2[l,h]
// ---------------------------------------------------------------------------
__global__ __launch_bounds__(256) void w2n_mfma(
    const unsigned short* __restrict__ gz2t, const unsigned short* __restrict__ x2t,
    const float* __restrict__ W2, const float* __restrict__ lrp,
    const float* __restrict__ cump, float* __restrict__ outw) {
    __shared__ __align__(16) unsigned short Ab[64][72];
    __shared__ __align__(16) unsigned short Bb[128][72];
    __shared__ float coefA[1024];
    const int bn = blockIdx.x, t = threadIdx.x;
    const int wv = t >> 6, lane = t & 63;
    const int lm = lane & 15, lg = lane >> 4;
    const float cum_last = cump[(size_t)bn * CL + CL - 1];
    const float wdcl = __expf(cum_last);
    for (int i = t; i < 1024; i += 256)
        coefA[i] = lrp[(size_t)bn * CL + i] * __expf(cum_last - cump[(size_t)bn * CL + i]);
    f32x4 acc[8];
#pragma unroll
    for (int i = 0; i < 8; ++i) acc[i] = (f32x4){0.f, 0.f, 0.f, 0.f};
    for (int lc = 0; lc < CL; lc += 64) {
        __syncthreads();
        for (int i = t; i < 512; i += 256) {
            int d = i >> 3, cc = (i & 7) * 8;
            uint4 g = *(const uint4*)(gz2t + ((size_t)bn * CHD + d) * CL + lc + cc);
            unsigned short* gp = (unsigned short*)&g;
            uint4 o;
            o.x = pk2(bf2f(gp[0]) * coefA[lc + cc + 0], bf2f(gp[1]) * coefA[lc + cc + 1]);
            o.y = pk2(bf2f(gp[2]) * coefA[lc + cc + 2], bf2f(gp[3]) * coefA[lc + cc + 3]);
            o.z = pk2(bf2f(gp[4]) * coefA[lc + cc + 4], bf2f(gp[5]) * coefA[lc + cc + 5]);
            o.w = pk2(bf2f(gp[6]) * coefA[lc + cc + 6], bf2f(gp[7]) * coefA[lc + cc + 7]);
            *(uint4*)&Ab[d][cc] = o;
        }
        for (int i = t; i < 1024; i += 256) {
            int h = i >> 3, cc = (i & 7) * 8;
            *(uint4*)&Bb[h][cc] = *(const uint4*)(x2t + ((size_t)bn * CHDH + h) * CL + lc + cc);
        }
        __syncthreads();
#pragma unroll
        for (int n16 = 0; n16 < 8; ++n16)
#pragma unroll
            for (int ks = 0; ks < 2; ++ks) {
                short8v a = *(const short8v*)&Ab[wv * 16 + lm][ks * 32 + lg * 8];
                short8v b = *(const short8v*)&Bb[n16 * 16 + lm][ks * 32 + lg * 8];
                acc[n16] = MFMA16(a, b, acc[n16]);
            }
    }
    const float* w2g = W2 + (size_t)bn * CHD * CHDH;
    float* og = outw + (size_t)bn * CHD * CHDH;
#pragma unroll
    for (int n16 = 0; n16 < 8; ++n16)
#pragma unroll
        for (int r = 0; r < 4; ++r) {
            int d = wv * 16 + lg * 4 + r;
            int h = n16 * 16 + lm;
            og[d * CHDH + h] = wdcl * w2g[d * CHDH + h] - acc[n16][r];
        }
}

// ---------------------------------------------------------------------------
extern "C" void kernel_launch(void* const* d_in, const int* in_sizes, int n_in,
                              void* d_out, int out_size, void* d_ws, size_t ws_size,
                              hipStream_t stream) {
    (void)in_sizes; (void)n_in; (void)out_size; (void)ws_size;
    const float* x      = (const float*)d_in[0];
    const float* W1     = (const float*)d_in[1];
    const float* W2     = (const float*)d_in[2];
    const float* lblr   = (const float*)d_in[3];
    const float* fclr_w = (const float*)d_in[4];
    const float* fclr_b = (const float*)d_in[5];
    const float* lbwd   = (const float*)d_in[6];
    const float* fcwd_w = (const float*)d_in[7];
    const float* fcwd_b = (const float*)d_in[8];
    const float* qw = (const float*)d_in[9];
    const float* qb = (const float*)d_in[10];
    const float* kw = (const float*)d_in[11];
    const float* kb = (const float*)d_in[12];
    const float* vw = (const float*)d_in[13];
    const float* vb = (const float*)d_in[14];
    const float* ow = (const float*)d_in[15];
    const float* ob = (const float*)d_in[16];

    float* ws = (float*)d_ws;
    const size_t SZ_HD = (size_t)CBN * CL * CHD;    // 2,097,152
    const size_t SZ_HDH = (size_t)CBN * CL * CHDH;  // 4,194,304
    float* qh   = ws;            // region: qbf + kbf (bf16)
    float* khb  = qh + SZ_HD;    // region: ktbf + w1bf + w2bf + w2tbf (bf16)
    float* vhb  = khb + SZ_HD;   // fp32 v (live)
    float* gz2b = vhb + SZ_HD;   // region: gz2t (bf16)
    float* z2sb = gz2b + SZ_HD;  // fp32 z2s (live)
    float* x2b  = z2sb + SZ_HD;  // region: x2t (bf16)
    float* gz1b = x2b + SZ_HDH;  // region: gz1t (bf16)
    float* x2qb = gz1b + SZ_HDH; // region: x2q + x2bf (bf16)
    float* lrb  = x2qb + SZ_HDH;
    float* cumb = lrb + (size_t)CBN * CL;
    float* wdcb = cumb + (size_t)CBN * CL;
    unsigned short* xbf  = (unsigned short*)(wdcb + (size_t)CBN * CL);
    unsigned short* qwbf = xbf + (size_t)CB * CL * CD;
    unsigned short* kwbf = qwbf + (size_t)CD * CD;
    unsigned short* vwbf = kwbf + (size_t)CD * CD;

    unsigned short* qbf   = (unsigned short*)qh;
    unsigned short* kbf   = qbf + SZ_HD;
    unsigned short* ktbf  = (unsigned short*)khb;                // [bn][64][CL]
    unsigned short* w1bf  = ktbf + SZ_HD;
    unsigned short* w2bf  = w1bf + (size_t)CBN * CHDH * CHD;
    unsigned short* w2tbf = w2bf + (size_t)CBN * CHDH * CHD;
    unsigned short* gz2t  = (unsigned short*)gz2b;               // [bn][64][CL]
    unsigned short* x2t   = (unsigned short*)x2b;                // [bn][128][CL]
    unsigned short* gz1t  = (unsigned short*)gz1b;               // [bn][128][CL]
    unsigned short* x2q   = (unsigned short*)x2qb;               // [bn][l][128]
    unsigned short* x2bf  = x2q + SZ_HDH;                        // [bn][l][128]

    float* outp = (float*)d_out;
    float* w1n = outp + (size_t)CB * CL * CD;
    float* w2n = w1n + (size_t)CBN * CHDH * CHD;

    tobf_kernel<<<5120, 256, 0, stream>>>(x, qw, kw, vw, xbf, qwbf, kwbf, vwbf);
    tobf2_kernel<<<768, 256, 0, stream>>>(W1, W2, w1bf, w2bf, w2tbf);
    dim3 gBig(CD / 64, (CB * CL) / 64);
    gemm_bf<0, 1, 0><<<gBig, 256, 0, stream>>>(xbf, qwbf, qb, nullptr, qbf, nullptr);
    gemm_bf<0, 1, 1><<<gBig, 256, 0, stream>>>(xbf, kwbf, kb, nullptr, kbf, ktbf);
    gemm_bf<1, 0, 0><<<gBig, 256, 0, stream>>>(xbf, vwbf, vb, vhb, nullptr, nullptr);
    lrwd_kernel<<<CB * CL, 64, 0, stream>>>(x, lblr, fclr_w, fclr_b, lbwd, fcwd_w,
                                            fcwd_b, lrb, cumb);
    scan_kernel<<<CBN, 64, 0, stream>>>(cumb, wdcb);
    mlp_mfma<<<dim3(CL / 64, CBN), 256, 0, stream>>>(kbf, vhb, w1bf, w2bf, w2tbf,
                                                     x2bf, x2t, gz1t, gz2t);
    attn1_mfma<<<dim3(CL / 64, CBN), 256, 0, stream>>>(qbf, kbf, gz1t, w1bf, lrb, cumb,
                                                       wdcb, x2q);
    attn2_mfma<<<dim3(CL / 64, CBN), 256, 0, stream>>>(x2q, x2bf, gz2t, w2bf, lrb, cumb,
                                                       wdcb, z2sb);
    w1n_mfma<<<CBN, 256, 0, stream>>>(gz1t, ktbf, W1, lrb, cumb, w1n);
    w2n_mfma<<<CBN, 256, 0, stream>>>(gz2t, x2t, W2, lrb, cumb, w2n);
    gemm_big<<<gBig, 256, 0, stream>>>(z2sb, ow, ob, outp);
}

// Round 5
// 391.043 us; speedup vs baseline: 3.1720x; 1.0514x over previous
//
#include <hip/hip_runtime.h>

constexpr int CB = 2, CL = 1024, CD = 1024, CNH = 16, CHD = 64, CHDH = 128, CBN = CB * CNH;

__device__ __forceinline__ float sigf(float x) { return 1.0f / (1.0f + __expf(-x)); }

__device__ __forceinline__ unsigned short f2bf(float x) {
    unsigned u = __float_as_uint(x);
    u += 0x7fffu + ((u >> 16) & 1u);
    return (unsigned short)(u >> 16);
}
__device__ __forceinline__ unsigned pk2(float a, float b) {
    return (unsigned)f2bf(a) | ((unsigned)f2bf(b) << 16);
}
__device__ __forceinline__ unsigned pkus(unsigned short a, unsigned short b) {
    return (unsigned)a | ((unsigned)b << 16);
}
__device__ __forceinline__ float bf2f(unsigned short u) {
    return __uint_as_float(((unsigned)u) << 16);
}

typedef __attribute__((ext_vector_type(8))) short short8v;
typedef __attribute__((ext_vector_type(4))) float f32x4;
#define MFMA16(a, b, c) __builtin_amdgcn_mfma_f32_16x16x32_bf16(a, b, c, 0, 0, 0)

// ---------------------------------------------------------------------------
// Convert x, qw, kw, vw to bf16.
// ---------------------------------------------------------------------------
__global__ __launch_bounds__(256) void tobf_kernel(
    const float* __restrict__ x, const float* __restrict__ qw,
    const float* __restrict__ kw, const float* __restrict__ vw,
    unsigned short* __restrict__ xb, unsigned short* __restrict__ qwb,
    unsigned short* __restrict__ kwb, unsigned short* __restrict__ vwb) {
    int i = blockIdx.x * 256 + threadIdx.x;
    const float* s;
    unsigned short* d;
    int off;
    if (i < 524288) { s = x; d = xb; off = i; }
    else if (i < 786432) { s = qw; d = qwb; off = i - 524288; }
    else if (i < 1048576) { s = kw; d = kwb; off = i - 786432; }
    else { s = vw; d = vwb; off = i - 1048576; }
    float4 v = *(const float4*)(s + (size_t)off * 4);
    *(uint2*)(d + (size_t)off * 4) = make_uint2(pk2(v.x, v.y), pk2(v.z, v.w));
}

// ---------------------------------------------------------------------------
// Convert W1 -> w1bf, W2 -> w2bf, W2^T -> w2tbf (bf16).
// ---------------------------------------------------------------------------
__global__ __launch_bounds__(256) void tobf2_kernel(
    const float* __restrict__ W1, const float* __restrict__ W2,
    unsigned short* __restrict__ w1b, unsigned short* __restrict__ w2b,
    unsigned short* __restrict__ w2t) {
    int i = blockIdx.x * 256 + threadIdx.x;  // 0..196607
    if (i < 65536) {
        size_t e = (size_t)i * 4;
        float4 v = *(const float4*)(W1 + e);
        *(uint2*)(w1b + e) = make_uint2(pk2(v.x, v.y), pk2(v.z, v.w));
    } else if (i < 131072) {
        size_t e = (size_t)(i - 65536) * 4;
        float4 v = *(const float4*)(W2 + e);
        *(uint2*)(w2b + e) = make_uint2(pk2(v.x, v.y), pk2(v.z, v.w));
    } else {
        size_t e = (size_t)(i - 131072) * 4;
        int bn = (int)(e >> 13), rem = (int)(e & 8191);
        int h = rem >> 6, d0 = rem & 63;
        const float* src = W2 + (size_t)bn * CHD * CHDH;
        float a = src[(d0 + 0) * CHDH + h], b = src[(d0 + 1) * CHDH + h];
        float c = src[(d0 + 2) * CHDH + h], dd = src[(d0 + 3) * CHDH + h];
        *(uint2*)(w2t + e) = make_uint2(pk2(a, b), pk2(c, dd));
    }
}

// ---------------------------------------------------------------------------
// Split ow into hi/lo bf16 (hi = bf16(v), lo = bf16(v - hi)).
// ---------------------------------------------------------------------------
__global__ __launch_bounds__(256) void tobf3_kernel(
    const float* __restrict__ ow, unsigned short* __restrict__ owh,
    unsigned short* __restrict__ owl) {
    size_t e = ((size_t)blockIdx.x * 256 + threadIdx.x) * 4;  // 1024 blocks
    float4 v = *(const float4*)(ow + e);
    unsigned short h0 = f2bf(v.x), h1 = f2bf(v.y), h2 = f2bf(v.z), h3 = f2bf(v.w);
    *(uint2*)(owh + e) = make_uint2(pkus(h0, h1), pkus(h2, h3));
    *(uint2*)(owl + e) = make_uint2(
        pk2(v.x - bf2f(h0), v.y - bf2f(h1)), pk2(v.z - bf2f(h2), v.w - bf2f(h3)));
}

// ---------------------------------------------------------------------------
// MFMA bf16 GEMM: 64x64 tile, K=1024. Out per-head [b][n][l][64].
// ---------------------------------------------------------------------------
template <int STOREF, int BFOUT, int KTOUT>
__global__ __launch_bounds__(256) void gemm_bf(const unsigned short* __restrict__ A,
                                               const unsigned short* __restrict__ Bw,
                                               const float* __restrict__ bias,
                                               float* __restrict__ Cf,
                                               unsigned short* __restrict__ Cb,
                                               unsigned short* __restrict__ Ct) {
    __shared__ __align__(16) unsigned short As[64][72];
    __shared__ __align__(16) unsigned short Bs[64][72];
    __shared__ float Os[64][68];
    const int t = threadIdx.x;
    const int r0 = blockIdx.y << 6, c0 = blockIdx.x << 6;
    const int wv = t >> 6, lane = t & 63;
    const int lm = lane & 15, lg = lane >> 4;
    f32x4 acc[4];
#pragma unroll
    for (int i = 0; i < 4; ++i) acc[i] = (f32x4){0.f, 0.f, 0.f, 0.f};
    for (int kc = 0; kc < CD; kc += 64) {
        for (int i = t; i < 512; i += 256) {
            int r = i >> 3, c = (i & 7) * 8;
            *(uint4*)&As[r][c] = *(const uint4*)(A + (size_t)(r0 + r) * CD + kc + c);
            *(uint4*)&Bs[r][c] = *(const uint4*)(Bw + (size_t)(c0 + r) * CD + kc + c);
        }
        __syncthreads();
#pragma unroll
        for (int n16 = 0; n16 < 4; ++n16)
#pragma unroll
            for (int ks = 0; ks < 2; ++ks) {
                short8v a = *(const short8v*)&As[wv * 16 + lm][ks * 32 + lg * 8];
                short8v b = *(const short8v*)&Bs[n16 * 16 + lm][ks * 32 + lg * 8];
                acc[n16] = MFMA16(a, b, acc[n16]);
            }
        __syncthreads();
    }
#pragma unroll
    for (int n16 = 0; n16 < 4; ++n16) {
        float bb = bias[c0 + n16 * 16 + lm];
#pragma unroll
        for (int r = 0; r < 4; ++r)
            Os[wv * 16 + lg * 4 + r][n16 * 16 + lm] = acc[n16][r] + bb;
    }
    __syncthreads();
    const int nh = c0 >> 6;
    const int b = r0 >> 10, lb0 = r0 & 1023;
    for (int i = t; i < 1024; i += 256) {
        int r = i >> 4, c = (i & 15) * 4;
        float4 v = *(const float4*)&Os[r][c];
        size_t base = (((size_t)b * CNH + nh) * CL + lb0 + r) * 64 + c;
        if (STOREF) *(float4*)(Cf + base) = v;
        if (BFOUT) *(uint2*)(Cb + base) = make_uint2(pk2(v.x, v.y), pk2(v.z, v.w));
    }
    if (KTOUT) {
        for (int i = t; i < 512; i += 256) {
            int d = i >> 3, lb = (i & 7) * 8;
            uint4 u;
            u.x = pk2(Os[lb + 0][d], Os[lb + 1][d]);
            u.y = pk2(Os[lb + 2][d], Os[lb + 3][d]);
            u.z = pk2(Os[lb + 4][d], Os[lb + 5][d]);
            u.w = pk2(Os[lb + 6][d], Os[lb + 7][d]);
            *(uint4*)(Ct + (((size_t)b * CNH + nh) * 64 + d) * CL + lb0 + lb) = u;
        }
    }
}

// ---------------------------------------------------------------------------
// Split-precision MFMA o-projection:
//   out = z2s @ ow^T + ob, with z2s,ow each split hi+lo bf16;
//   out ≈ zh@wh + zh@wl + zl@wh (fp32 MFMA accum -> ~fp32 accuracy).
// A gathered from per-head z2s. Out row-major [B*L][D].
// ---------------------------------------------------------------------------
__global__ __launch_bounds__(256) void gemm_obf(const float* __restrict__ A,
                                                const unsigned short* __restrict__ Bh,
                                                const unsigned short* __restrict__ Bl,
                                                const float* __restrict__ bias,
                                                float* __restrict__ C) {
    __shared__ __align__(16) unsigned short SM[4][64][72];  // Ah, Al, Bhs, Bls
    const int t = threadIdx.x;
    const int r0 = blockIdx.y << 6, c0 = blockIdx.x << 6;
    const int wv = t >> 6, lane = t & 63;
    const int lm = lane & 15, lg = lane >> 4;
    const int b = r0 >> 10, lb0 = r0 & 1023;
    f32x4 acc[4];
#pragma unroll
    for (int i = 0; i < 4; ++i) acc[i] = (f32x4){0.f, 0.f, 0.f, 0.f};
    for (int kc = 0; kc < CD; kc += 64) {
        for (int i = t; i < 1024; i += 256) {
            int r = i >> 4, c4 = (i & 15) * 4;
            int ak = kc + c4, n = ak >> 6, d = ak & 63;
            float4 v = *(const float4*)(A + ((((size_t)b * CNH + n) * CL + lb0 + r) << 6) + d);
            unsigned short h0 = f2bf(v.x), h1 = f2bf(v.y), h2 = f2bf(v.z), h3 = f2bf(v.w);
            *(uint2*)&SM[0][r][c4] = make_uint2(pkus(h0, h1), pkus(h2, h3));
            *(uint2*)&SM[1][r][c4] = make_uint2(
                pk2(v.x - bf2f(h0), v.y - bf2f(h1)), pk2(v.z - bf2f(h2), v.w - bf2f(h3)));
        }
        for (int i = t; i < 512; i += 256) {
            int r = i >> 3, c = (i & 7) * 8;
            *(uint4*)&SM[2][r][c] = *(const uint4*)(Bh + (size_t)(c0 + r) * CD + kc + c);
            *(uint4*)&SM[3][r][c] = *(const uint4*)(Bl + (size_t)(c0 + r) * CD + kc + c);
        }
        __syncthreads();
#pragma unroll
        for (int n16 = 0; n16 < 4; ++n16)
#pragma unroll
            for (int ks = 0; ks < 2; ++ks) {
                short8v ah = *(const short8v*)&SM[0][wv * 16 + lm][ks * 32 + lg * 8];
                short8v al = *(const short8v*)&SM[1][wv * 16 + lm][ks * 32 + lg * 8];
                short8v bh = *(const short8v*)&SM[2][n16 * 16 + lm][ks * 32 + lg * 8];
                short8v bl = *(const short8v*)&SM[3][n16 * 16 + lm][ks * 32 + lg * 8];
                acc[n16] = MFMA16(ah, bh, acc[n16]);
                acc[n16] = MFMA16(ah, bl, acc[n16]);
                acc[n16] = MFMA16(al, bh, acc[n16]);
            }
        __syncthreads();
    }
    float(*Os)[68] = (float(*)[68])SM;  // overlay (36KB >= 17KB)
#pragma unroll
    for (int n16 = 0; n16 < 4; ++n16) {
        float bb = bias[c0 + n16 * 16 + lm];
#pragma unroll
        for (int r = 0; r < 4; ++r)
            Os[wv * 16 + lg * 4 + r][n16 * 16 + lm] = acc[n16][r] + bb;
    }
    __syncthreads();
    for (int i = t; i < 1024; i += 256) {
        int r = i >> 4, c = (i & 15) * 4;
        *(float4*)(C + (size_t)(r0 + r) * CD + c0 + c) = *(const float4*)&Os[r][c];
    }
}

// ---------------------------------------------------------------------------
// lr / log_wd projections.
// ---------------------------------------------------------------------------
__global__ __launch_bounds__(64) void lrwd_kernel(
    const float* __restrict__ x, const float* __restrict__ lblr,
    const float* __restrict__ fclr_w, const float* __restrict__ fclr_b,
    const float* __restrict__ lbwd, const float* __restrict__ fcwd_w,
    const float* __restrict__ fcwd_b, float* __restrict__ lrp,
    float* __restrict__ logwd) {
    const int r = blockIdx.x;
    const int b = r >> 10, l = r & 1023;
    const int lane = threadIdx.x;
    float xv[16];
#pragma unroll
    for (int j = 0; j < 16; ++j) xv[j] = x[(size_t)r * CD + lane + 64 * j];
    for (int n = 0; n < CNH; ++n) {
        float d1 = 0.f, d2 = 0.f;
#pragma unroll
        for (int j = 0; j < 16; ++j) {
            d1 += xv[j] * fclr_w[(size_t)n * CD + lane + 64 * j];
            d2 += xv[j] * fcwd_w[(size_t)n * CD + lane + 64 * j];
        }
#pragma unroll
        for (int s = 32; s > 0; s >>= 1) {
            d1 += __shfl_down(d1, s);
            d2 += __shfl_down(d2, s);
        }
        if (lane == 0) {
            lrp[((size_t)b * CNH + n) * CL + l] = __expf(lblr[n]) * sigf(d1 + fclr_b[n]);
            logwd[((size_t)b * CNH + n) * CL + l] =
                log1pf(-__expf(lbwd[n]) * sigf(d2 + fcwd_b[n]));
        }
    }
}

// ---------------------------------------------------------------------------
// Inclusive prefix sum of log_wd -> cum, plus wdc = exp(cum).
// ---------------------------------------------------------------------------
__global__ __launch_bounds__(64) void scan_kernel(float* __restrict__ cum,
                                                  float* __restrict__ wdc) {
    const int bn = blockIdx.x;
    const int lane = threadIdx.x;
    float* p = cum + (size_t)bn * CL;
    float v[16];
#pragma unroll
    for (int j = 0; j < 16; ++j) v[j] = p[lane * 16 + j];
#pragma unroll
    for (int j = 1; j < 16; ++j) v[j] += v[j - 1];
    float tot = v[15];
    float inc = tot;
#pragma unroll
    for (int s = 1; s < 64; s <<= 1) {
        float tv = __shfl_up(inc, s);
        if (lane >= s) inc += tv;
    }
    const float pre = inc - tot;
#pragma unroll
    for (int j = 0; j < 16; ++j) {
        float c = pre + v[j];
        p[lane * 16 + j] = c;
        wdc[(size_t)bn * CL + lane * 16 + j] = __expf(c);
    }
}

// ---------------------------------------------------------------------------
// MFMA MLP fwd/bwd over 64 tokens.
// ---------------------------------------------------------------------------
__global__ __launch_bounds__(256) void mlp_mfma(
    const unsigned short* __restrict__ kbf, const float* __restrict__ vh,
    const unsigned short* __restrict__ w1bf, const unsigned short* __restrict__ w2bf,
    const unsigned short* __restrict__ w2tbf, unsigned short* __restrict__ x2bf,
    unsigned short* __restrict__ x2t, unsigned short* __restrict__ gz1t,
    unsigned short* __restrict__ gz2t) {
    __shared__ __align__(16) unsigned short RA[128][72];
    __shared__ __align__(16) unsigned short RB[64][72];
    __shared__ __align__(16) unsigned short RC[64][136];
    __shared__ __align__(16) unsigned short X2s[64][136];
    const int bn = blockIdx.y, l0 = blockIdx.x << 6;
    const int t = threadIdx.x;
    const int wv = t >> 6, lane = t & 63;
    const int lm = lane & 15, lg = lane >> 4;
    {
        const unsigned short* kg = kbf + ((size_t)bn * CL + l0) * CHD;
        for (int i = t; i < 512; i += 256) {
            int r = i >> 3, c = (i & 7) * 8;
            *(uint4*)&RB[r][c] = *(const uint4*)(kg + (size_t)r * CHD + c);
        }
        const unsigned short* w1g = w1bf + (size_t)bn * CHDH * CHD;
        for (int i = t; i < 1024; i += 256) {
            int r = i >> 3, c = (i & 7) * 8;
            *(uint4*)&RA[r][c] = *(const uint4*)(w1g + (size_t)r * CHD + c);
        }
        const unsigned short* w2g = w2bf + (size_t)bn * CHD * CHDH;
        for (int i = t; i < 1024; i += 256) {
            int r = i >> 4, c = (i & 15) * 8;
            *(uint4*)&RC[r][c] = *(const uint4*)(w2g + (size_t)r * CHDH + c);
        }
    }
    __syncthreads();
    f32x4 acc1[4][2];
#pragma unroll
    for (int i = 0; i < 4; ++i)
#pragma unroll
        for (int j = 0; j < 2; ++j) acc1[i][j] = (f32x4){0.f, 0.f, 0.f, 0.f};
#pragma unroll
    for (int m16 = 0; m16 < 4; ++m16)
#pragma unroll
        for (int hh = 0; hh < 2; ++hh) {
            int h16 = wv * 2 + hh;
#pragma unroll
            for (int ks = 0; ks < 2; ++ks) {
                short8v a = *(const short8v*)&RB[m16 * 16 + lm][ks * 32 + lg * 8];
                short8v b = *(const short8v*)&RA[h16 * 16 + lm][ks * 32 + lg * 8];
                acc1[m16][hh] = MFMA16(a, b, acc1[m16][hh]);
            }
        }
#pragma unroll
    for (int m16 = 0; m16 < 4; ++m16)
#pragma unroll
        for (int hh = 0; hh < 2; ++hh)
#pragma unroll
            for (int r = 0; r < 4; ++r) {
                float a = acc1[m16][hh][r];
                X2s[m16 * 16 + lg * 4 + r][(wv * 2 + hh) * 16 + lm] = f2bf(a * sigf(a));
            }
    __syncthreads();
    {
        const unsigned short* w2tg = w2tbf + (size_t)bn * CHDH * CHD;
        for (int i = t; i < 1024; i += 256) {
            int r = i >> 3, c = (i & 7) * 8;
            *(uint4*)&RA[r][c] = *(const uint4*)(w2tg + (size_t)r * CHD + c);
        }
    }
    {
        f32x4 acc2[4];
#pragma unroll
        for (int i = 0; i < 4; ++i) acc2[i] = (f32x4){0.f, 0.f, 0.f, 0.f};
#pragma unroll
        for (int m16 = 0; m16 < 4; ++m16)
#pragma unroll
            for (int ks = 0; ks < 4; ++ks) {
                short8v a = *(const short8v*)&X2s[m16 * 16 + lm][ks * 32 + lg * 8];
                short8v b = *(const short8v*)&RC[wv * 16 + lm][ks * 32 + lg * 8];
                acc2[m16] = MFMA16(a, b, acc2[m16]);
            }
#pragma unroll
        for (int m16 = 0; m16 < 4; ++m16)
#pragma unroll
            for (int r = 0; r < 4; ++r) {
                int l = l0 + m16 * 16 + lg * 4 + r;
                float v = vh[((size_t)bn * CL + l) * 64 + wv * 16 + lm];
                RB[m16 * 16 + lg * 4 + r][wv * 16 + lm] = f2bf(acc2[m16][r] - v);
            }
    }
    __syncthreads();
#pragma unroll
    for (int m16 = 0; m16 < 4; ++m16)
#pragma unroll
        for (int hh = 0; hh < 2; ++hh) {
            int h16 = wv * 2 + hh;
            f32x4 p = (f32x4){0.f, 0.f, 0.f, 0.f};
#pragma unroll
            for (int ks = 0; ks < 2; ++ks) {
                short8v a = *(const short8v*)&RB[m16 * 16 + lm][ks * 32 + lg * 8];
                short8v b = *(const short8v*)&RA[h16 * 16 + lm][ks * 32 + lg * 8];
                p = MFMA16(a, b, p);
            }
#pragma unroll
            for (int r = 0; r < 4; ++r) {
                float zz = acc1[m16][hh][r];
                float s = sigf(zz);
                float sil = zz * s;
                RC[m16 * 16 + lg * 4 + r][h16 * 16 + lm] =
                    f2bf((sil + s * (1.f - sil)) * p[r]);
            }
        }
    __syncthreads();
    for (int i = t; i < 1024; i += 256) {
        int r = i >> 4, c = (i & 15) * 8;
        *(uint4*)(x2bf + ((size_t)bn * CL + l0 + r) * CHDH + c) = *(const uint4*)&X2s[r][c];
    }
    for (int i = t; i < 1024; i += 256) {
        int h = i >> 3, lb = (i & 7) * 8;
        uint4 u;
        u.x = pkus(X2s[lb + 0][h], X2s[lb + 1][h]);
        u.y = pkus(X2s[lb + 2][h], X2s[lb + 3][h]);
        u.z = pkus(X2s[lb + 4][h], X2s[lb + 5][h]);
        u.w = pkus(X2s[lb + 6][h], X2s[lb + 7][h]);
        *(uint4*)(x2t + ((size_t)bn * CHDH + h) * CL + l0 + lb) = u;
    }
    for (int i = t; i < 1024; i += 256) {
        int h = i >> 3, lb = (i & 7) * 8;
        uint4 u;
        u.x = pkus(RC[lb + 0][h], RC[lb + 1][h]);
        u.y = pkus(RC[lb + 2][h], RC[lb + 3][h]);
        u.z = pkus(RC[lb + 4][h], RC[lb + 5][h]);
        u.w = pkus(RC[lb + 6][h], RC[lb + 7][h]);
        *(uint4*)(gz1t + ((size_t)bn * CHDH + h) * CL + l0 + lb) = u;
    }
    for (int i = t; i < 512; i += 256) {
        int d = i >> 3, lb = (i & 7) * 8;
        uint4 u;
        u.x = pkus(RB[lb + 0][d], RB[lb + 1][d]);
        u.y = pkus(RB[lb + 2][d], RB[lb + 3][d]);
        u.z = pkus(RB[lb + 4][d], RB[lb + 5][d]);
        u.w = pkus(RB[lb + 6][d], RB[lb + 7][d]);
        *(uint4*)(gz2t + ((size_t)bn * CHD + d) * CL + l0 + lb) = u;
    }
}

// ---------------------------------------------------------------------------
// attn1 (MFMA bf16).
// ---------------------------------------------------------------------------
__global__ __launch_bounds__(256) void attn1_mfma(
    const unsigned short* __restrict__ qbf, const unsigned short* __restrict__ kbf,
    const unsigned short* __restrict__ gz1t, const unsigned short* __restrict__ w1bf,
    const float* __restrict__ lrp, const float* __restrict__ cump,
    const float* __restrict__ wdcp, unsigned short* __restrict__ x2q) {
    __shared__ __align__(16) unsigned short Qb[64][72];
    __shared__ __align__(16) unsigned short Wb[128][72];
    __shared__ __align__(16) unsigned short Kb[64][72];
    __shared__ __align__(16) unsigned short GT[128][72];
    __shared__ __align__(16) unsigned short Pm[64][72];
    __shared__ float lrl[64], cuml[64], cumm[64], wdcm[64];
    const int bn = blockIdx.y, mt = blockIdx.x, m0 = mt << 6;
    const int t = threadIdx.x;
    const int wv = t >> 6, lane = t & 63;
    const int lm = lane & 15, lg = lane >> 4;
    {
        const unsigned short* qg = qbf + ((size_t)bn * CL + m0) * CHD;
        for (int i = t; i < 512; i += 256) {
            int r = i >> 3, c = (i & 7) * 8;
            *(uint4*)&Qb[r][c] = *(const uint4*)(qg + (size_t)r * CHD + c);
        }
        const unsigned short* wg = w1bf + (size_t)bn * CHDH * CHD;
        for (int i = t; i < 1024; i += 256) {
            int r = i >> 3, c = (i & 7) * 8;
            *(uint4*)&Wb[r][c] = *(const uint4*)(wg + (size_t)r * CHD + c);
        }
        if (t < 64) {
            cumm[t] = cump[(size_t)bn * CL + m0 + t];
            wdcm[t] = wdcp[(size_t)bn * CL + m0 + t];
        }
    }
    __syncthreads();
    f32x4 acc[4][2];
#pragma unroll
    for (int i = 0; i < 4; ++i)
#pragma unroll
        for (int j = 0; j < 2; ++j) acc[i][j] = (f32x4){0.f, 0.f, 0.f, 0.f};
#pragma unroll
    for (int m16 = 0; m16 < 4; ++m16)
#pragma unroll
        for (int hh = 0; hh < 2; ++hh) {
            int h16 = wv * 2 + hh;
#pragma unroll
            for (int ks = 0; ks < 2; ++ks) {
                short8v a = *(const short8v*)&Qb[m16 * 16 + lm][ks * 32 + lg * 8];
                short8v b = *(const short8v*)&Wb[h16 * 16 + lm][ks * 32 + lg * 8];
                acc[m16][hh] = MFMA16(a, b, acc[m16][hh]);
            }
        }
#pragma unroll
    for (int m16 = 0; m16 < 4; ++m16) {
#pragma unroll
        for (int r = 0; r < 4; ++r) {
            float w = wdcm[m16 * 16 + lg * 4 + r];
            acc[m16][0][r] *= w;
            acc[m16][1][r] *= w;
        }
    }
    for (int lt = 0; lt <= mt; ++lt) {
        const int l0 = lt << 6;
        __syncthreads();
        {
            const unsigned short* kg = kbf + ((size_t)bn * CL + l0) * CHD;
            for (int i = t; i < 512; i += 256) {
                int r = i >> 3, c = (i & 7) * 8;
                *(uint4*)&Kb[r][c] = *(const uint4*)(kg + (size_t)r * CHD + c);
            }
            const unsigned short* gg = gz1t + (size_t)bn * CHDH * CL + l0;
            for (int i = t; i < 1024; i += 256) {
                int r = i >> 3, c = (i & 7) * 8;
                *(uint4*)&GT[r][c] = *(const uint4*)(gg + (size_t)r * CL + c);
            }
            if (t < 64) {
                lrl[t] = lrp[(size_t)bn * CL + l0 + t];
                cuml[t] = cump[(size_t)bn * CL + l0 + t];
            }
        }
        __syncthreads();
        {
            const int mabsb = m0 + lm;
#pragma unroll
            for (int m16 = 0; m16 < 4; ++m16) {
                f32x4 s = (f32x4){0.f, 0.f, 0.f, 0.f};
#pragma unroll
                for (int ks = 0; ks < 2; ++ks) {
                    short8v a = *(const short8v*)&Kb[wv * 16 + lm][ks * 32 + lg * 8];
                    short8v b = *(const short8v*)&Qb[m16 * 16 + lm][ks * 32 + lg * 8];
                    s = MFMA16(a, b, s);
                }
                int mloc = m16 * 16 + lm;
                int mabs = mabsb + m16 * 16;
                float cm = cumm[mloc];
                unsigned short pv[4];
#pragma unroll
                for (int r = 0; r < 4; ++r) {
                    int lloc = wv * 16 + lg * 4 + r;
                    float val = (mabs >= l0 + lloc)
                                    ? s[r] * lrl[lloc] * __expf(cm - cuml[lloc])
                                    : 0.f;
                    pv[r] = f2bf(val);
                }
                *(uint2*)&Pm[mloc][wv * 16 + lg * 4] =
                    make_uint2(pkus(pv[0], pv[1]), pkus(pv[2], pv[3]));
            }
        }
        __syncthreads();
#pragma unroll
        for (int m16 = 0; m16 < 4; ++m16)
#pragma unroll
            for (int hh = 0; hh < 2; ++hh) {
                int h16 = wv * 2 + hh;
                f32x4 p = (f32x4){0.f, 0.f, 0.f, 0.f};
#pragma unroll
                for (int ks = 0; ks < 2; ++ks) {
                    short8v a = *(const short8v*)&Pm[m16 * 16 + lm][ks * 32 + lg * 8];
                    short8v b = *(const short8v*)&GT[h16 * 16 + lm][ks * 32 + lg * 8];
                    p = MFMA16(a, b, p);
                }
#pragma unroll
                for (int r = 0; r < 4; ++r) acc[m16][hh][r] -= p[r];
            }
    }
    __syncthreads();
    {
        unsigned short(*Ob)[136] = (unsigned short(*)[136])Wb;
#pragma unroll
        for (int m16 = 0; m16 < 4; ++m16)
#pragma unroll
            for (int hh = 0; hh < 2; ++hh) {
                int h = (wv * 2 + hh) * 16 + lm;
#pragma unroll
                for (int r = 0; r < 4; ++r) {
                    int mloc = m16 * 16 + lg * 4 + r;
                    float a = acc[m16][hh][r];
                    Ob[mloc][h] = f2bf(a * sigf(a));
                }
            }
        __syncthreads();
        unsigned short* og = x2q + ((size_t)bn * CL + m0) * CHDH;
        for (int i = t; i < 1024; i += 256) {
            int r = i >> 4, c = (i & 15) * 8;
            *(uint4*)(og + (size_t)r * CHDH + c) = *(const uint4*)&Ob[r][c];
        }
    }
}

// ---------------------------------------------------------------------------
// attn2 (MFMA bf16).
// ---------------------------------------------------------------------------
__global__ __launch_bounds__(256) void attn2_mfma(
    const unsigned short* __restrict__ x2q, const unsigned short* __restrict__ x2bf,
    const unsigned short* __restrict__ gz2t, const unsigned short* __restrict__ w2bf,
    const float* __restrict__ lrp, const float* __restrict__ cump,
    const float* __restrict__ wdcp, float* __restrict__ z2s) {
    __shared__ __align__(16) unsigned short X2qb[64][136];
    __shared__ __align__(16) unsigned short W2b[64][136];
    __shared__ __align__(16) unsigned short X2l[64][136];
    __shared__ __align__(16) unsigned short GT2[64][72];
    __shared__ __align__(16) unsigned short Pm[64][72];
    __shared__ float lrl[64], cuml[64], cumm[64], wdcm[64];
    const int bn = blockIdx.y, mt = blockIdx.x, m0 = mt << 6;
    const int t = threadIdx.x;
    const int wv = t >> 6, lane = t & 63;
    const int lm = lane & 15, lg = lane >> 4;
    {
        const uint4* qg = (const uint4*)(x2q + ((size_t)bn * CL + m0) * CHDH);
        for (int i = t; i < 1024; i += 256) {
            int r = i >> 4, c = (i & 15) * 8;
            *(uint4*)&X2qb[r][c] = qg[i];
        }
        const unsigned short* wg = w2bf + (size_t)bn * CHD * CHDH;
        for (int i = t; i < 1024; i += 256) {
            int r = i >> 4, c = (i & 15) * 8;
            *(uint4*)&W2b[r][c] = *(const uint4*)(wg + (size_t)r * CHDH + c);
        }
        if (t < 64) {
            cumm[t] = cump[(size_t)bn * CL + m0 + t];
            wdcm[t] = wdcp[(size_t)bn * CL + m0 + t];
        }
    }
    __syncthreads();
    f32x4 acc[4];
#pragma unroll
    for (int i = 0; i < 4; ++i) acc[i] = (f32x4){0.f, 0.f, 0.f, 0.f};
#pragma unroll
    for (int m16 = 0; m16 < 4; ++m16)
#pragma unroll
        for (int ks = 0; ks < 4; ++ks) {
            short8v a = *(const short8v*)&X2qb[m16 * 16 + lm][ks * 32 + lg * 8];
            short8v b = *(const short8v*)&W2b[wv * 16 + lm][ks * 32 + lg * 8];
            acc[m16] = MFMA16(a, b, acc[m16]);
        }
#pragma unroll
    for (int m16 = 0; m16 < 4; ++m16)
#pragma unroll
        for (int r = 0; r < 4; ++r) acc[m16][r] *= wdcm[m16 * 16 + lg * 4 + r];
    for (int lt = 0; lt <= mt; ++lt) {
        const int l0 = lt << 6;
        __syncthreads();
        {
            const unsigned short* kg = x2bf + ((size_t)bn * CL + l0) * CHDH;
            for (int i = t; i < 1024; i += 256) {
                int r = i >> 4, c = (i & 15) * 8;
                *(uint4*)&X2l[r][c] = *(const uint4*)(kg + (size_t)r * CHDH + c);
            }
            const unsigned short* gg = gz2t + (size_t)bn * CHD * CL + l0;
            for (int i = t; i < 512; i += 256) {
                int r = i >> 3, c = (i & 7) * 8;
                *(uint4*)&GT2[r][c] = *(const uint4*)(gg + (size_t)r * CL + c);
            }
            if (t < 64) {
                lrl[t] = lrp[(size_t)bn * CL + l0 + t];
                cuml[t] = cump[(size_t)bn * CL + l0 + t];
            }
        }
        __syncthreads();
        {
            const int mabsb = m0 + lm;
#pragma unroll
            for (int m16 = 0; m16 < 4; ++m16) {
                f32x4 s = (f32x4){0.f, 0.f, 0.f, 0.f};
#pragma unroll
                for (int ks = 0; ks < 4; ++ks) {
                    short8v a = *(const short8v*)&X2l[wv * 16 + lm][ks * 32 + lg * 8];
                    short8v b = *(const short8v*)&X2qb[m16 * 16 + lm][ks * 32 + lg * 8];
                    s = MFMA16(a, b, s);
                }
                int mloc = m16 * 16 + lm;
                int mabs = mabsb + m16 * 16;
                float cm = cumm[mloc];
                unsigned short pv[4];
#pragma unroll
                for (int r = 0; r < 4; ++r) {
                    int lloc = wv * 16 + lg * 4 + r;
                    float val = (mabs >= l0 + lloc)
                                    ? s[r] * lrl[lloc] * __expf(cm - cuml[lloc])
                                    : 0.f;
                    pv[r] = f2bf(val);
                }
                *(uint2*)&Pm[mloc][wv * 16 + lg * 4] =
                    make_uint2(pkus(pv[0], pv[1]), pkus(pv[2], pv[3]));
            }
        }
        __syncthreads();
#pragma unroll
        for (int m16 = 0; m16 < 4; ++m16) {
            f32x4 p = (f32x4){0.f, 0.f, 0.f, 0.f};
#pragma unroll
            for (int ks = 0; ks < 2; ++ks) {
                short8v a = *(const short8v*)&Pm[m16 * 16 + lm][ks * 32 + lg * 8];
                short8v b = *(const short8v*)&GT2[wv * 16 + lm][ks * 32 + lg * 8];
                p = MFMA16(a, b, p);
            }
#pragma unroll
            for (int r = 0; r < 4; ++r) acc[m16][r] -= p[r];
        }
    }
    __syncthreads();
    {
        float(*Os)[68] = (float(*)[68])W2b;
#pragma unroll
        for (int m16 = 0; m16 < 4; ++m16)
#pragma unroll
            for (int r = 0; r < 4; ++r)
                Os[m16 * 16 + lg * 4 + r][wv * 16 + lm] = acc[m16][r];
        __syncthreads();
        float* zg = z2s + ((size_t)bn * CL + m0) * CHD;
        for (int i = t; i < 1024; i += 256) {
            int r = i >> 4, c = (i & 15) << 2;
            *(float4*)(zg + (size_t)r * CHD + c) = *(const float4*)&Os[r][c];
        }
    }
}

// ---------------------------------------------------------------------------
// W1_next via MFMA.
// ---------------------------------------------------------------------------
__global__ __launch_bounds__(256) void w1n_mfma(
    const unsigned short* __restrict__ gz1t, const unsigned short* __restrict__ ktbf,
    const float* __restrict__ W1, const float* __restrict__ lrp,
    const float* __restrict__ cump, float* __restrict__ outw) {
    __shared__ __align__(16) unsigned short Ab[128][72];
    __shared__ __align__(16) unsigned short Bb[64][72];
    __shared__ float coefA[1024];
    const int bn = blockIdx.x, t = threadIdx.x;
    const int wv = t >> 6, lane = t & 63;
    const int lm = lane & 15, lg = lane >> 4;
    const float cum_last = cump[(size_t)bn * CL + CL - 1];
    const float wdcl = __expf(cum_last);
    for (int i = t; i < 1024; i += 256)
        coefA[i] = lrp[(size_t)bn * CL + i] * __expf(cum_last - cump[(size_t)bn * CL + i]);
    f32x4 acc[2][4];
#pragma unroll
    for (int i = 0; i < 2; ++i)
#pragma unroll
        for (int j = 0; j < 4; ++j) acc[i][j] = (f32x4){0.f, 0.f, 0.f, 0.f};
    for (int lc = 0; lc < CL; lc += 64) {
        __syncthreads();
        for (int i = t; i < 1024; i += 256) {
            int h = i >> 3, cc = (i & 7) * 8;
            uint4 g = *(const uint4*)(gz1t + ((size_t)bn * CHDH + h) * CL + lc + cc);
            unsigned short* gp = (unsigned short*)&g;
            uint4 o;
            o.x = pk2(bf2f(gp[0]) * coefA[lc + cc + 0], bf2f(gp[1]) * coefA[lc + cc + 1]);
            o.y = pk2(bf2f(gp[2]) * coefA[lc + cc + 2], bf2f(gp[3]) * coefA[lc + cc + 3]);
            o.z = pk2(bf2f(gp[4]) * coefA[lc + cc + 4], bf2f(gp[5]) * coefA[lc + cc + 5]);
            o.w = pk2(bf2f(gp[6]) * coefA[lc + cc + 6], bf2f(gp[7]) * coefA[lc + cc + 7]);
            *(uint4*)&Ab[h][cc] = o;
        }
        for (int i = t; i < 512; i += 256) {
            int d = i >> 3, cc = (i & 7) * 8;
            *(uint4*)&Bb[d][cc] = *(const uint4*)(ktbf + ((size_t)bn * CHD + d) * CL + lc + cc);
        }
        __syncthreads();
#pragma unroll
        for (int mm = 0; mm < 2; ++mm) {
            int m16 = wv * 2 + mm;
#pragma unroll
            for (int n16 = 0; n16 < 4; ++n16)
#pragma unroll
                for (int ks = 0; ks < 2; ++ks) {
                    short8v a = *(const short8v*)&Ab[m16 * 16 + lm][ks * 32 + lg * 8];
                    short8v b = *(const short8v*)&Bb[n16 * 16 + lm][ks * 32 + lg * 8];
                    acc[mm][n16] = MFMA16(a, b, acc[mm][n16]);
                }
        }
    }
    const float* w1g = W1 + (size_t)bn * CHDH * CHD;
    float* og = outw + (size_t)bn * CHDH * CHD;
#pragma unroll
    for (int mm = 0; mm < 2; ++mm)
#pragma unroll
        for (int n16 = 0; n16 < 4; ++n16)
#pragma unroll
            for (int r = 0; r < 4; ++r) {
                int h = (wv * 2 + mm) * 16 + lg * 4 + r;
                int d = n16 * 16 + lm;
                og[h * CHD + d] = wdcl * w1g[h * CHD + d] - acc[mm][n16][r];
            }
}

// ---------------------------------------------------------------------------
// W2_next via MFMA.
// ---------------------------------------------------------------------------
__global__ __launch_bounds__(256) void w2n_mfma(
    const unsigned short* __restrict__ gz2t, const unsigned short* __restrict__ x2t,
    const float* __restrict__ W2, const float* __restrict__ lrp,
    const float* __restrict__ cump, float* __restrict__ outw) {
    __shared__ __align__(16) unsigned short Ab[64][72];
    __shared__ __align__(16) unsigned short Bb[128][72];
    __shared__ float coefA[1024];
    const int bn = blockIdx.x, t = threadIdx.x;
    const int wv = t >> 6, lane = t & 63;
    const int lm = lane & 15, lg = lane >> 4;
    const float cum_last = cump[(size_t)bn * CL + CL - 1];
    const float wdcl = __expf(cum_last);
    for (int i = t; i < 1024; i += 256)
        coefA[i] = lrp[(size_t)bn * CL + i] * __expf(cum_last - cump[(size_t)bn * CL + i]);
    f32x4 acc[8];
#pragma unroll
    for (int i = 0; i < 8; ++i) acc[i] = (f32x4){0.f, 0.f, 0.f, 0.f};
    for (int lc = 0; lc < CL; lc += 64) {
        __syncthreads();
        for (int i = t; i < 512; i += 256) {
            int d = i >> 3, cc = (i & 7) * 8;
            uint4 g = *(const uint4*)(gz2t + ((size_t)bn * CHD + d) * CL + lc + cc);
            unsigned short* gp = (unsigned short*)&g;
            uint4 o;
            o.x = pk2(bf2f(gp[0]) * coefA[lc + cc + 0], bf2f(gp[1]) * coefA[lc + cc + 1]);
            o.y = pk2(bf2f(gp[2]) * coefA[lc + cc + 2], bf2f(gp[3]) * coefA[lc + cc + 3]);
            o.z = pk2(bf2f(gp[4]) * coefA[lc + cc + 4], bf2f(gp[5]) * coefA[lc + cc + 5]);
            o.w = pk2(bf2f(gp[6]) * coefA[lc + cc + 6], bf2f(gp[7]) * coefA[lc + cc + 7]);
            *(uint4*)&Ab[d][cc] = o;
        }
        for (int i = t; i < 1024; i += 256) {
            int h = i >> 3, cc = (i & 7) * 8;
            *(uint4*)&Bb[h][cc] = *(const uint4*)(x2t + ((size_t)bn * CHDH + h) * CL + lc + cc);
        }
        __syncthreads();
#pragma unroll
        for (int n16 = 0; n16 < 8; ++n16)
#pragma unroll
            for (int ks = 0; ks < 2; ++ks) {
                short8v a = *(const short8v*)&Ab[wv * 16 + lm][ks * 32 + lg * 8];
                short8v b = *(const short8v*)&Bb[n16 * 16 + lm][ks * 32 + lg * 8];
                acc[n16] = MFMA16(a, b, acc[n16]);
            }
    }
    const float* w2g = W2 + (size_t)bn * CHD * CHDH;
    float* og = outw + (size_t)bn * CHD * CHDH;
#pragma unroll
    for (int n16 = 0; n16 < 8; ++n16)
#pragma unroll
        for (int r = 0; r < 4; ++r) {
            int d = wv * 16 + lg * 4 + r;
            int h = n16 * 16 + lm;
            og[d * CHDH + h] = wdcl * w2g[d * CHDH + h] - acc[n16][r];
        }
}

// ---------------------------------------------------------------------------
extern "C" void kernel_launch(void* const* d_in, const int* in_sizes, int n_in,
                              void* d_out, int out_size, void* d_ws, size_t ws_size,
                              hipStream_t stream) {
    (void)in_sizes; (void)n_in; (void)out_size; (void)ws_size;
    const float* x      = (const float*)d_in[0];
    const float* W1     = (const float*)d_in[1];
    const float* W2     = (const float*)d_in[2];
    const float* lblr   = (const float*)d_in[3];
    const float* fclr_w = (const float*)d_in[4];
    const float* fclr_b = (const float*)d_in[5];
    const float* lbwd   = (const float*)d_in[6];
    const float* fcwd_w = (const float*)d_in[7];
    const float* fcwd_b = (const float*)d_in[8];
    const float* qw = (const float*)d_in[9];
    const float* qb = (const float*)d_in[10];
    const float* kw = (const float*)d_in[11];
    const float* kb = (const float*)d_in[12];
    const float* vw = (const float*)d_in[13];
    const float* vb = (const float*)d_in[14];
    const float* ow = (const float*)d_in[15];
    const float* ob = (const float*)d_in[16];

    float* ws = (float*)d_ws;
    const size_t SZ_HD = (size_t)CBN * CL * CHD;
    const size_t SZ_HDH = (size_t)CBN * CL * CHDH;
    float* qh   = ws;
    float* khb  = qh + SZ_HD;
    float* vhb  = khb + SZ_HD;
    float* gz2b = vhb + SZ_HD;
    float* z2sb = gz2b + SZ_HD;
    float* x2b  = z2sb + SZ_HD;
    float* gz1b = x2b + SZ_HDH;
    float* x2qb = gz1b + SZ_HDH;
    float* lrb  = x2qb + SZ_HDH;
    float* cumb = lrb + (size_t)CBN * CL;
    float* wdcb = cumb + (size_t)CBN * CL;
    unsigned short* xbf  = (unsigned short*)(wdcb + (size_t)CBN * CL);
    unsigned short* qwbf = xbf + (size_t)CB * CL * CD;
    unsigned short* kwbf = qwbf + (size_t)CD * CD;
    unsigned short* vwbf = kwbf + (size_t)CD * CD;
    unsigned short* owh  = vwbf + (size_t)CD * CD;
    unsigned short* owl  = owh + (size_t)CD * CD;

    unsigned short* qbf   = (unsigned short*)qh;
    unsigned short* kbf   = qbf + SZ_HD;
    unsigned short* ktbf  = (unsigned short*)khb;
    unsigned short* w1bf  = ktbf + SZ_HD;
    unsigned short* w2bf  = w1bf + (size_t)CBN * CHDH * CHD;
    unsigned short* w2tbf = w2bf + (size_t)CBN * CHDH * CHD;
    unsigned short* gz2t  = (unsigned short*)gz2b;
    unsigned short* x2t   = (unsigned short*)x2b;
    unsigned short* gz1t  = (unsigned short*)gz1b;
    unsigned short* x2q   = (unsigned short*)x2qb;
    unsigned short* x2bf  = x2q + SZ_HDH;

    float* outp = (float*)d_out;
    float* w1n = outp + (size_t)CB * CL * CD;
    float* w2n = w1n + (size_t)CBN * CHDH * CHD;

    tobf_kernel<<<5120, 256, 0, stream>>>(x, qw, kw, vw, xbf, qwbf, kwbf, vwbf);
    tobf2_kernel<<<768, 256, 0, stream>>>(W1, W2, w1bf, w2bf, w2tbf);
    tobf3_kernel<<<1024, 256, 0, stream>>>(ow, owh, owl);
    dim3 gBig(CD / 64, (CB * CL) / 64);
    gemm_bf<0, 1, 0><<<gBig, 256, 0, stream>>>(xbf, qwbf, qb, nullptr, qbf, nullptr);
    gemm_bf<0, 1, 1><<<gBig, 256, 0, stream>>>(xbf, kwbf, kb, nullptr, kbf, ktbf);
    gemm_bf<1, 0, 0><<<gBig, 256, 0, stream>>>(xbf, vwbf, vb, vhb, nullptr, nullptr);
    lrwd_kernel<<<CB * CL, 64, 0, stream>>>(x, lblr, fclr_w, fclr_b, lbwd, fcwd_w,
                                            fcwd_b, lrb, cumb);
    scan_kernel<<<CBN, 64, 0, stream>>>(cumb, wdcb);
    mlp_mfma<<<dim3(CL / 64, CBN), 256, 0, stream>>>(kbf, vhb, w1bf, w2bf, w2tbf,
                                                     x2bf, x2t, gz1t, gz2t);
    attn1_mfma<<<dim3(CL / 64, CBN), 256, 0, stream>>>(qbf, kbf, gz1t, w1bf, lrb, cumb,
                                                       wdcb, x2q);
    attn2_mfma<<<dim3(CL / 64, CBN), 256, 0, stream>>>(x2q, x2bf, gz2t, w2bf, lrb, cumb,
                                                       wdcb, z2sb);
    w1n_mfma<<<CBN, 256, 0, stream>>>(gz1t, ktbf, W1, lrb, cumb, w1n);
    w2n_mfma<<<CBN, 256, 0, stream>>>(gz2t, x2t, W2, lrb, cumb, w2n);
    gemm_obf<<<gBig, 256, 0, stream>>>(z2sb, owh, owl, ob, outp);
}